// Round 1
// baseline (1251.859 us; speedup 1.0000x reference)
//
#include <hip/hip_runtime.h>

#define N_NODES 100000
#define N_EDGES 1600000
#define D0 128
#define D1 256
#define D2 64

// ---------------- CSR build ----------------

__global__ void zero_int_kernel(int* __restrict__ p, int n) {
  int i = blockIdx.x * blockDim.x + threadIdx.x;
  if (i < n) p[i] = 0;
}

__global__ void count_deg_kernel(const int* __restrict__ dst, int* __restrict__ deg) {
  int e = blockIdx.x * blockDim.x + threadIdx.x;
  if (e < N_EDGES) atomicAdd(&deg[dst[e]], 1);
}

// Single-block exclusive scan over deg -> rowptr; also leaves the same
// exclusive prefix in deg (making it the scatter cursor). deg==cursor buffer.
__global__ void scan_deg_kernel(int* deg_cursor, int* __restrict__ rowptr) {
  __shared__ int s[1024];
  __shared__ int carry_s;
  int tid = threadIdx.x;
  if (tid == 0) carry_s = 0;
  __syncthreads();
  for (int base = 0; base < N_NODES; base += 1024) {
    int i = base + tid;
    int v = (i < N_NODES) ? deg_cursor[i] : 0;
    s[tid] = v;
    __syncthreads();
    // Hillis-Steele inclusive scan
    for (int off = 1; off < 1024; off <<= 1) {
      int t = (tid >= off) ? s[tid - off] : 0;
      __syncthreads();
      s[tid] += t;
      __syncthreads();
    }
    int incl = s[tid];
    int total = s[1023];
    int rbase = carry_s;
    if (i < N_NODES) {
      int r = rbase + incl - v;   // exclusive
      rowptr[i] = r;
      deg_cursor[i] = r;          // cursor for scatter
    }
    __syncthreads();
    if (tid == 0) carry_s = rbase + total;
    __syncthreads();
  }
  if (tid == 0) rowptr[N_NODES] = carry_s;
}

__global__ void scatter_edges_kernel(const int* __restrict__ src, const int* __restrict__ dst,
                                     int* cursor, int* __restrict__ ebuf) {
  int e = blockIdx.x * blockDim.x + threadIdx.x;
  if (e < N_EDGES) {
    int p = atomicAdd(&cursor[dst[e]], 1);
    ebuf[p] = src[e];
  }
}

// ---------------- Layer-1 aggregation: mean over neighbors of x ----------------
// one block (128 threads) per node; thread t owns feature t
__global__ void agg_mean1_kernel(const int* __restrict__ rowptr, const int* __restrict__ ebuf,
                                 const float* __restrict__ x, float* __restrict__ mean1) {
  int node = blockIdx.x;
  int t = threadIdx.x;  // 0..127
  int beg = rowptr[node], end = rowptr[node + 1];
  float acc = 0.f;
  for (int e = beg; e < end; ++e) {
    int s = ebuf[e];
    acc += x[(size_t)s * D0 + t];
  }
  float inv = (end > beg) ? 1.0f / (float)(end - beg) : 0.0f;
  mean1[(size_t)node * D0 + t] = acc * inv;
}

// ---------------- GEMM layer 1 ----------------
// h = relu([mean1 | x] @ [W1_l ; W1_r] + b1)   M=100000, N=256, K=256(concat)
__launch_bounds__(256)
__global__ void gemm_layer1_kernel(const float* __restrict__ mean1, const float* __restrict__ x,
                                   const float* __restrict__ W1l, const float* __restrict__ W1r,
                                   const float* __restrict__ b1, float* __restrict__ h) {
  __shared__ float As[64][33];
  __shared__ float Bs[32][65];
  int tid = threadIdx.x;
  int tx = tid & 15, ty = tid >> 4;
  int rowBase = blockIdx.x * 64;
  int colBase = blockIdx.y * 64;
  float c[4][4] = {};
  for (int k0 = 0; k0 < 256; k0 += 32) {
#pragma unroll
    for (int r = 0; r < 8; ++r) {
      int elem = tid + r * 256;
      int row = elem >> 5;
      int kk = elem & 31;
      int grow = rowBase + row;
      int gk = k0 + kk;
      float v = 0.f;
      if (grow < N_NODES)
        v = (gk < 128) ? mean1[(size_t)grow * 128 + gk]
                       : x[(size_t)grow * 128 + (gk - 128)];
      As[row][kk] = v;
    }
#pragma unroll
    for (int r = 0; r < 8; ++r) {
      int elem = tid + r * 256;
      int kk = elem >> 6;
      int col = elem & 63;
      int gk = k0 + kk;
      int gcol = colBase + col;
      Bs[kk][col] = (gk < 128) ? W1l[(size_t)gk * 256 + gcol]
                               : W1r[(size_t)(gk - 128) * 256 + gcol];
    }
    __syncthreads();
#pragma unroll
    for (int kk = 0; kk < 32; ++kk) {
      float a[4], b[4];
#pragma unroll
      for (int m = 0; m < 4; ++m) a[m] = As[ty * 4 + m][kk];
#pragma unroll
      for (int n = 0; n < 4; ++n) b[n] = Bs[kk][tx * 4 + n];
#pragma unroll
      for (int m = 0; m < 4; ++m)
#pragma unroll
        for (int n = 0; n < 4; ++n) c[m][n] += a[m] * b[n];
    }
    __syncthreads();
  }
#pragma unroll
  for (int m = 0; m < 4; ++m) {
    int grow = rowBase + ty * 4 + m;
    if (grow >= N_NODES) continue;
#pragma unroll
    for (int n = 0; n < 4; ++n) {
      int gcol = colBase + tx * 4 + n;
      float v = c[m][n] + b1[gcol];
      h[(size_t)grow * 256 + gcol] = fmaxf(v, 0.f);
    }
  }
}

// ---------------- GEMM layer 2 ----------------
// pq[:, 0:64] = h @ W2_l ; pq[:, 64:128] = h @ W2_r   (blockIdx.y selects)
__launch_bounds__(256)
__global__ void gemm_layer2_kernel(const float* __restrict__ h, const float* __restrict__ W2l,
                                   const float* __restrict__ W2r, float* __restrict__ pq) {
  __shared__ float As[64][33];
  __shared__ float Bs[32][65];
  int tid = threadIdx.x;
  int tx = tid & 15, ty = tid >> 4;
  int rowBase = blockIdx.x * 64;
  const float* W = (blockIdx.y == 0) ? W2l : W2r;
  float c[4][4] = {};
  for (int k0 = 0; k0 < 256; k0 += 32) {
#pragma unroll
    for (int r = 0; r < 8; ++r) {
      int elem = tid + r * 256;
      int row = elem >> 5;
      int kk = elem & 31;
      int grow = rowBase + row;
      As[row][kk] = (grow < N_NODES) ? h[(size_t)grow * 256 + k0 + kk] : 0.f;
    }
#pragma unroll
    for (int r = 0; r < 8; ++r) {
      int elem = tid + r * 256;
      int kk = elem >> 6;
      int col = elem & 63;
      Bs[kk][col] = W[(size_t)(k0 + kk) * 64 + col];
    }
    __syncthreads();
#pragma unroll
    for (int kk = 0; kk < 32; ++kk) {
      float a[4], b[4];
#pragma unroll
      for (int m = 0; m < 4; ++m) a[m] = As[ty * 4 + m][kk];
#pragma unroll
      for (int n = 0; n < 4; ++n) b[n] = Bs[kk][tx * 4 + n];
#pragma unroll
      for (int m = 0; m < 4; ++m)
#pragma unroll
        for (int n = 0; n < 4; ++n) c[m][n] += a[m] * b[n];
    }
    __syncthreads();
  }
#pragma unroll
  for (int m = 0; m < 4; ++m) {
    int grow = rowBase + ty * 4 + m;
    if (grow >= N_NODES) continue;
#pragma unroll
    for (int n = 0; n < 4; ++n) {
      pq[(size_t)grow * 128 + blockIdx.y * 64 + tx * 4 + n] = c[m][n];
    }
  }
}

// ---------------- Final: aggregate P, + b2 + Q, log_softmax ----------------
// one block = one wave (64 threads) per node; thread t owns class t
__global__ void final_kernel(const int* __restrict__ rowptr, const int* __restrict__ ebuf,
                             const float* __restrict__ pq, const float* __restrict__ b2,
                             float* __restrict__ out) {
  int node = blockIdx.x;
  int t = threadIdx.x;  // 0..63
  int beg = rowptr[node], end = rowptr[node + 1];
  float acc = 0.f;
  for (int e = beg; e < end; ++e) {
    int s = ebuf[e];
    acc += pq[(size_t)s * 128 + t];  // P part
  }
  float inv = (end > beg) ? 1.0f / (float)(end - beg) : 0.0f;
  float v = acc * inv + b2[t] + pq[(size_t)node * 128 + 64 + t];  // + Q part
  // wave-wide (64-lane) log_softmax
  float m = v;
  for (int o = 32; o > 0; o >>= 1) m = fmaxf(m, __shfl_xor(m, o));
  float ex = expf(v - m);
  float ssum = ex;
  for (int o = 32; o > 0; o >>= 1) ssum += __shfl_xor(ssum, o);
  out[(size_t)node * 64 + t] = v - m - logf(ssum);
}

// ---------------- launch ----------------

extern "C" void kernel_launch(void* const* d_in, const int* in_sizes, int n_in,
                              void* d_out, int out_size, void* d_ws, size_t ws_size,
                              hipStream_t stream) {
  const float* x   = (const float*)d_in[0];
  const int*   ei  = (const int*)d_in[1];
  const float* W1l = (const float*)d_in[2];
  const float* b1  = (const float*)d_in[3];
  const float* W1r = (const float*)d_in[4];
  const float* W2l = (const float*)d_in[5];
  const float* b2  = (const float*)d_in[6];
  const float* W2r = (const float*)d_in[7];
  float* out = (float*)d_out;
  const int* src = ei;
  const int* dst = ei + N_EDGES;

  char* w = (char*)d_ws;
  int*   cursor = (int*)(w);                                   // N ints (deg, then cursor)
  int*   rowptr = (int*)(w + 512 * 1024);                      // N+1 ints
  int*   ebuf   = (int*)(w + 1024 * 1024);                     // E ints (6.4 MB)
  float* mean1  = (float*)(w + 8ull * 1024 * 1024);            // N*128 f32 (51.2 MB)
  float* h      = (float*)(w + 60ull * 1024 * 1024);           // N*256 f32 (102.4 MB)
  float* pq     = mean1;  // mean1 dead after gemm1; reuse for P|Q (N*128)

  zero_int_kernel<<<(N_NODES + 255) / 256, 256, 0, stream>>>(cursor, N_NODES);
  count_deg_kernel<<<(N_EDGES + 255) / 256, 256, 0, stream>>>(dst, cursor);
  scan_deg_kernel<<<1, 1024, 0, stream>>>(cursor, rowptr);
  scatter_edges_kernel<<<(N_EDGES + 255) / 256, 256, 0, stream>>>(src, dst, cursor, ebuf);

  agg_mean1_kernel<<<N_NODES, 128, 0, stream>>>(rowptr, ebuf, x, mean1);

  gemm_layer1_kernel<<<dim3((N_NODES + 63) / 64, 4), 256, 0, stream>>>(mean1, x, W1l, W1r, b1, h);
  gemm_layer2_kernel<<<dim3((N_NODES + 63) / 64, 2), 256, 0, stream>>>(h, W2l, W2r, pq);

  final_kernel<<<N_NODES, 64, 0, stream>>>(rowptr, ebuf, pq, b2, out);
}

// Round 2
// 576.557 us; speedup vs baseline: 2.1713x; 2.1713x over previous
//
#include <hip/hip_runtime.h>

#define N_NODES 100000
#define N_EDGES 1600000
#define GK 256   // K dim of both GEMMs (concat for layer 1, D1 for layer 2)

typedef __attribute__((ext_vector_type(8))) short bf16x8;
typedef __attribute__((ext_vector_type(4))) float f32x4;
typedef unsigned short ushort_t;

__device__ __forceinline__ float bf2f(unsigned int bits16) {
  union { unsigned int i; float f; } v; v.i = bits16 << 16; return v.f;
}
__device__ __forceinline__ unsigned short f2bf(float f) {
  union { float f; unsigned int i; } v; v.f = f;
  unsigned int u = v.i;
  unsigned int r = (u + 0x7fffu + ((u >> 16) & 1u)) >> 16;  // RNE
  return (unsigned short)r;
}
__device__ __forceinline__ void gload16(const void* g, void* l) {
  __builtin_amdgcn_global_load_lds(
      (const __attribute__((address_space(1))) void*)g,
      (__attribute__((address_space(3))) void*)l, 16, 0, 0);
}

// ---------------- CSR build ----------------

__global__ void zero_int_kernel(int* __restrict__ p, int n) {
  int i = blockIdx.x * blockDim.x + threadIdx.x;
  if (i < n) p[i] = 0;
}

__global__ void count_deg_kernel(const int* __restrict__ dst, int* __restrict__ deg) {
  int e = blockIdx.x * blockDim.x + threadIdx.x;
  if (e < N_EDGES) atomicAdd(&deg[dst[e]], 1);
}

__global__ void scan_deg_kernel(int* deg_cursor, int* __restrict__ rowptr) {
  __shared__ int s[1024];
  __shared__ int carry_s;
  int tid = threadIdx.x;
  if (tid == 0) carry_s = 0;
  __syncthreads();
  for (int base = 0; base < N_NODES; base += 1024) {
    int i = base + tid;
    int v = (i < N_NODES) ? deg_cursor[i] : 0;
    s[tid] = v;
    __syncthreads();
    for (int off = 1; off < 1024; off <<= 1) {
      int t = (tid >= off) ? s[tid - off] : 0;
      __syncthreads();
      s[tid] += t;
      __syncthreads();
    }
    int incl = s[tid];
    int total = s[1023];
    int rbase = carry_s;
    if (i < N_NODES) {
      int r = rbase + incl - v;
      rowptr[i] = r;
      deg_cursor[i] = r;
    }
    __syncthreads();
    if (tid == 0) carry_s = rbase + total;
    __syncthreads();
  }
  if (tid == 0) rowptr[N_NODES] = carry_s;
}

__global__ void scatter_edges_kernel(const int* __restrict__ src, const int* __restrict__ dst,
                                     int* cursor, int* __restrict__ ebuf) {
  int e = blockIdx.x * blockDim.x + threadIdx.x;
  if (e < N_EDGES) {
    int p = atomicAdd(&cursor[dst[e]], 1);
    ebuf[p] = src[e];
  }
}

// ---------------- conversions ----------------
// axb layout: [N][256] bf16, cols 0..127 = mean1 (filled by agg), 128..255 = x
__global__ void cvt_x_kernel(const float* __restrict__ x, ushort_t* __restrict__ axb) {
  int idx = blockIdx.x * blockDim.x + threadIdx.x;  // one thread per 4 elems
  if (idx >= N_NODES * 32) return;
  int n = idx >> 5, j = (idx & 31) << 2;
  float4 v = *(const float4*)(x + (size_t)n * 128 + j);
  ushort4 o;
  o.x = f2bf(v.x); o.y = f2bf(v.y); o.z = f2bf(v.z); o.w = f2bf(v.w);
  *(ushort4*)(axb + (size_t)n * 256 + 128 + j) = o;
}

// W1bt [256 cols][256 k] = transpose of [W1l;W1r]; W2bt [128 cols][256 k] = transpose of [W2l|W2r]
__global__ void cvt_w_kernel(const float* __restrict__ W1l, const float* __restrict__ W1r,
                             const float* __restrict__ W2l, const float* __restrict__ W2r,
                             ushort_t* __restrict__ W1bt, ushort_t* __restrict__ W2bt) {
  int idx = blockIdx.x * blockDim.x + threadIdx.x;
  if (idx < 65536) {
    int n = idx >> 8, k = idx & 255;
    float v = (k < 128) ? W1l[(size_t)k * 256 + n] : W1r[(size_t)(k - 128) * 256 + n];
    W1bt[idx] = f2bf(v);
  } else if (idx < 65536 + 32768) {
    int t = idx - 65536;
    int n = t >> 8, k = t & 255;
    float v = (n < 64) ? W2l[(size_t)k * 64 + n] : W2r[(size_t)k * 64 + (n - 64)];
    W2bt[t] = f2bf(v);
  }
}

// ---------------- layer-1 mean aggregation (bf16 gather, f32 acc) ----------------
// one wave per node; lane l owns features 2l, 2l+1
__global__ void agg_mean1_kernel(const int* __restrict__ rowptr, const int* __restrict__ ebuf,
                                 ushort_t* __restrict__ axb) {
  int node = blockIdx.x * 4 + (threadIdx.x >> 6);
  int lane = threadIdx.x & 63;
  int beg = rowptr[node], end = rowptr[node + 1];
  const ushort_t* xb = axb + 128;  // x part of rows
  float a0 = 0.f, a1 = 0.f;
  int e = beg;
  for (; e + 4 <= end; e += 4) {
    int s0 = ebuf[e], s1 = ebuf[e + 1], s2 = ebuf[e + 2], s3 = ebuf[e + 3];
    unsigned int v0 = *(const unsigned int*)(xb + (size_t)s0 * 256 + lane * 2);
    unsigned int v1 = *(const unsigned int*)(xb + (size_t)s1 * 256 + lane * 2);
    unsigned int v2 = *(const unsigned int*)(xb + (size_t)s2 * 256 + lane * 2);
    unsigned int v3 = *(const unsigned int*)(xb + (size_t)s3 * 256 + lane * 2);
    a0 += bf2f(v0 & 0xffff) + bf2f(v1 & 0xffff) + bf2f(v2 & 0xffff) + bf2f(v3 & 0xffff);
    a1 += bf2f(v0 >> 16) + bf2f(v1 >> 16) + bf2f(v2 >> 16) + bf2f(v3 >> 16);
  }
  for (; e < end; ++e) {
    int s = ebuf[e];
    unsigned int v = *(const unsigned int*)(xb + (size_t)s * 256 + lane * 2);
    a0 += bf2f(v & 0xffff);
    a1 += bf2f(v >> 16);
  }
  float inv = (end > beg) ? 1.0f / (float)(end - beg) : 0.0f;
  unsigned int o = (unsigned int)f2bf(a0 * inv) | ((unsigned int)f2bf(a1 * inv) << 16);
  *(unsigned int*)(axb + (size_t)node * 256 + lane * 2) = o;
}

// ---------------- bf16 MFMA GEMM (K=256 fixed) ----------------
// C[M][NC] (bf16) = A[M][256] (bf16, row-major) @ Bt[NC][256]^T (bf16)
// tile 128x128, BK=64, 4 waves (2x2), wave = 64x64 = 4x4 fragments of 16x16x32
// LDS XOR-swizzle: 16B slot index within row ^= (row&7)  (involution; staged pre-swizzled)
template<bool RELU>
__launch_bounds__(256)
__global__ void gemm_bf16_kernel(const ushort_t* __restrict__ A, const ushort_t* __restrict__ Bt,
                                 const float* __restrict__ bias, ushort_t* __restrict__ C,
                                 int M, int NC) {
  __shared__ ushort_t ldsA[128 * 64];  // 16 KB
  __shared__ ushort_t ldsB[128 * 64];  // 16 KB
  const int tid = threadIdx.x;
  const int lane = tid & 63;
  const int wm = (tid >> 6) & 1, wn = tid >> 7;
  const int rowBase = blockIdx.x * 128;
  const int colBase = blockIdx.y * 128;
  f32x4 acc[4][4];
#pragma unroll
  for (int i = 0; i < 4; ++i)
#pragma unroll
    for (int j = 0; j < 4; ++j) acc[i][j] = (f32x4){0.f, 0.f, 0.f, 0.f};

  for (int k0 = 0; k0 < GK; k0 += 64) {
#pragma unroll
    for (int i = 0; i < 4; ++i) {
      int s = tid + i * 256;          // 16B slot id; lane-contiguous per wave
      int row = s >> 3, off16 = s & 7;
      int k16 = off16 ^ (row & 7);    // inverse-swizzled global source
      int ga = rowBase + row; if (ga > M - 1) ga = M - 1;
      gload16(A + (size_t)ga * GK + k0 + k16 * 8, &ldsA[s * 8]);
      gload16(Bt + (size_t)(colBase + row) * GK + k0 + k16 * 8, &ldsB[s * 8]);
    }
    __syncthreads();
#pragma unroll
    for (int kc = 0; kc < 2; ++kc) {
      bf16x8 af[4], bfr[4];
#pragma unroll
      for (int i = 0; i < 4; ++i) {
        int rA = wm * 64 + i * 16 + (lane & 15);
        int oA = (kc * 4 + (lane >> 4)) ^ (rA & 7);   // swizzled read
        af[i] = *(const bf16x8*)&ldsA[rA * 64 + oA * 8];
        int rB = wn * 64 + i * 16 + (lane & 15);
        int oB = (kc * 4 + (lane >> 4)) ^ (rB & 7);
        bfr[i] = *(const bf16x8*)&ldsB[rB * 64 + oB * 8];
      }
#pragma unroll
      for (int mi = 0; mi < 4; ++mi)
#pragma unroll
        for (int ni = 0; ni < 4; ++ni)
          acc[mi][ni] = __builtin_amdgcn_mfma_f32_16x16x32_bf16(af[mi], bfr[ni], acc[mi][ni], 0, 0, 0);
    }
    __syncthreads();
  }
  // epilogue: C/D layout col=lane&15, row=(lane>>4)*4+r  [m89-verified]
#pragma unroll
  for (int mi = 0; mi < 4; ++mi) {
#pragma unroll
    for (int r = 0; r < 4; ++r) {
      int grow = rowBase + wm * 64 + mi * 16 + (lane >> 4) * 4 + r;
      if (grow >= M) continue;
#pragma unroll
      for (int ni = 0; ni < 4; ++ni) {
        int gcol = colBase + wn * 64 + ni * 16 + (lane & 15);
        float v = acc[mi][ni][r];
        if (RELU) v = fmaxf(v + bias[gcol], 0.f);
        C[(size_t)grow * NC + gcol] = f2bf(v);
      }
    }
  }
}

// ---------------- final: aggregate P (bf16), + b2 + Q, log_softmax ----------------
// one wave per node; lane t owns class t
__global__ void final_kernel(const int* __restrict__ rowptr, const int* __restrict__ ebuf,
                             const ushort_t* __restrict__ pq, const float* __restrict__ b2,
                             float* __restrict__ out) {
  int node = blockIdx.x * 4 + (threadIdx.x >> 6);
  int t = threadIdx.x & 63;
  int beg = rowptr[node], end = rowptr[node + 1];
  float acc = 0.f;
  int e = beg;
  for (; e + 4 <= end; e += 4) {
    int s0 = ebuf[e], s1 = ebuf[e + 1], s2 = ebuf[e + 2], s3 = ebuf[e + 3];
    acc += bf2f(pq[(size_t)s0 * 128 + t]) + bf2f(pq[(size_t)s1 * 128 + t]) +
           bf2f(pq[(size_t)s2 * 128 + t]) + bf2f(pq[(size_t)s3 * 128 + t]);
  }
  for (; e < end; ++e) acc += bf2f(pq[(size_t)ebuf[e] * 128 + t]);
  float inv = (end > beg) ? 1.0f / (float)(end - beg) : 0.0f;
  float v = acc * inv + b2[t] + bf2f(pq[(size_t)node * 128 + 64 + t]);
  float m = v;
  for (int o = 32; o > 0; o >>= 1) m = fmaxf(m, __shfl_xor(m, o));
  float ex = expf(v - m);
  float ssum = ex;
  for (int o = 32; o > 0; o >>= 1) ssum += __shfl_xor(ssum, o);
  out[(size_t)node * 64 + t] = v - m - logf(ssum);
}

// ---------------- launch ----------------

extern "C" void kernel_launch(void* const* d_in, const int* in_sizes, int n_in,
                              void* d_out, int out_size, void* d_ws, size_t ws_size,
                              hipStream_t stream) {
  const float* x   = (const float*)d_in[0];
  const int*   ei  = (const int*)d_in[1];
  const float* W1l = (const float*)d_in[2];
  const float* b1  = (const float*)d_in[3];
  const float* W1r = (const float*)d_in[4];
  const float* W2l = (const float*)d_in[5];
  const float* b2  = (const float*)d_in[6];
  const float* W2r = (const float*)d_in[7];
  float* out = (float*)d_out;
  const int* src = ei;
  const int* dst = ei + N_EDGES;

  char* w = (char*)d_ws;
  int*      cursor = (int*)(w);                              // 400 KB
  int*      rowptr = (int*)(w + 512 * 1024);                 // 400 KB
  int*      ebuf   = (int*)(w + 1024 * 1024);                // 6.4 MB
  ushort_t* W1bt   = (ushort_t*)(w + 8ull * 1024 * 1024);    // 128 KB
  ushort_t* W2bt   = (ushort_t*)(w + 8ull * 1024 * 1024 + 256 * 1024);  // 64 KB
  ushort_t* axb    = (ushort_t*)(w + 9ull * 1024 * 1024);    // 51.2 MB  [N][256] bf16
  ushort_t* h      = (ushort_t*)(w + 61ull * 1024 * 1024);   // 51.2 MB  [N][256] bf16
  ushort_t* pq     = (ushort_t*)(w + 113ull * 1024 * 1024);  // 25.6 MB  [N][128] bf16

  zero_int_kernel<<<(N_NODES + 255) / 256, 256, 0, stream>>>(cursor, N_NODES);
  count_deg_kernel<<<(N_EDGES + 255) / 256, 256, 0, stream>>>(dst, cursor);
  scan_deg_kernel<<<1, 1024, 0, stream>>>(cursor, rowptr);
  scatter_edges_kernel<<<(N_EDGES + 255) / 256, 256, 0, stream>>>(src, dst, cursor, ebuf);

  cvt_x_kernel<<<(N_NODES * 32 + 255) / 256, 256, 0, stream>>>(x, axb);
  cvt_w_kernel<<<384, 256, 0, stream>>>(W1l, W1r, W2l, W2r, W1bt, W2bt);

  agg_mean1_kernel<<<N_NODES / 4, 256, 0, stream>>>(rowptr, ebuf, axb);

  gemm_bf16_kernel<true><<<dim3((N_NODES + 127) / 128, 2), 256, 0, stream>>>(
      axb, W1bt, b1, h, N_NODES, 256);
  gemm_bf16_kernel<false><<<dim3((N_NODES + 127) / 128, 1), 256, 0, stream>>>(
      h, W2bt, nullptr, pq, N_NODES, 128);

  final_kernel<<<N_NODES / 4, 256, 0, stream>>>(rowptr, ebuf, pq, b2, out);
}

// Round 3
// 403.600 us; speedup vs baseline: 3.1017x; 1.4285x over previous
//
#include <hip/hip_runtime.h>

#define N_NODES 100000
#define N_EDGES 1600000
#define GK 256   // K dim of both GEMMs (concat for layer 1, D1 for layer 2)

typedef __attribute__((ext_vector_type(8))) short bf16x8;
typedef __attribute__((ext_vector_type(4))) float f32x4;
typedef unsigned short ushort_t;

__device__ __forceinline__ float bf2f(unsigned int bits16) {
  union { unsigned int i; float f; } v; v.i = bits16 << 16; return v.f;
}
__device__ __forceinline__ unsigned short f2bf(float f) {
  union { float f; unsigned int i; } v; v.f = f;
  unsigned int u = v.i;
  unsigned int r = (u + 0x7fffu + ((u >> 16) & 1u)) >> 16;  // RNE
  return (unsigned short)r;
}
__device__ __forceinline__ void gload16(const void* g, void* l) {
  __builtin_amdgcn_global_load_lds(
      (const __attribute__((address_space(1))) void*)g,
      (__attribute__((address_space(3))) void*)l, 16, 0, 0);
}

// ---------------- CSR build ----------------

__global__ void zero_int_kernel(int* __restrict__ p, int n) {
  int i = blockIdx.x * blockDim.x + threadIdx.x;
  if (i < n) p[i] = 0;
}

__global__ void count_deg_kernel(const int* __restrict__ dst, int* __restrict__ deg) {
  int e = blockIdx.x * blockDim.x + threadIdx.x;
  if (e < N_EDGES) atomicAdd(&deg[dst[e]], 1);
}

// stage 1: per-block (1024) scan, in-place deg -> local exclusive, partials[b] = block total
__global__ void block_scan_kernel(int* __restrict__ deg, int* __restrict__ partials) {
  __shared__ int wsum[16];
  int tid = threadIdx.x;
  int i = blockIdx.x * 1024 + tid;
  int lane = tid & 63, wave = tid >> 6;
  int v = (i < N_NODES) ? deg[i] : 0;
  int s = v;
#pragma unroll
  for (int o = 1; o < 64; o <<= 1) { int t = __shfl_up(s, o); if (lane >= o) s += t; }
  if (lane == 63) wsum[wave] = s;
  __syncthreads();
  if (wave == 0) {
    int t = (lane < 16) ? wsum[lane] : 0;
    int ss = t;
#pragma unroll
    for (int o = 1; o < 16; o <<= 1) { int u = __shfl_up(ss, o); if (lane >= o) ss += u; }
    if (lane < 16) wsum[lane] = ss - t;  // exclusive wave offset
    if (lane == 15) partials[blockIdx.x] = ss;  // block total
  }
  __syncthreads();
  if (i < N_NODES) deg[i] = s + wsum[wave] - v;  // local exclusive
}

// stage 2: one wave scans block partials (exclusive, in place)
__global__ void scan_partials_kernel(int* __restrict__ partials, int n) {
  int lane = threadIdx.x;
  int carry = 0;
  for (int base = 0; base < n; base += 64) {
    int i = base + lane;
    int v = (i < n) ? partials[i] : 0;
    int s = v;
#pragma unroll
    for (int o = 1; o < 64; o <<= 1) { int t = __shfl_up(s, o); if (lane >= o) s += t; }
    int tot = __shfl(s, 63);
    if (i < n) partials[i] = carry + s - v;
    carry += tot;
  }
}

// stage 3: add block offsets -> rowptr + cursor
__global__ void add_offsets_kernel(const int* __restrict__ local_excl,
                                   const int* __restrict__ partials,
                                   int* __restrict__ rowptr, int* __restrict__ cursor) {
  int i = blockIdx.x * blockDim.x + threadIdx.x;
  if (i < N_NODES) {
    int r = local_excl[i] + partials[i >> 10];
    rowptr[i] = r;
    cursor[i] = r;
  }
  if (i == 0) rowptr[N_NODES] = N_EDGES;
}

__global__ void scatter_edges_kernel(const int* __restrict__ src, const int* __restrict__ dst,
                                     int* cursor, int* __restrict__ ebuf) {
  int e = blockIdx.x * blockDim.x + threadIdx.x;
  if (e < N_EDGES) {
    int p = atomicAdd(&cursor[dst[e]], 1);
    ebuf[p] = src[e];
  }
}

// ---------------- conversions ----------------
// axb layout: [N][256] bf16, cols 0..127 = mean1 (filled by agg), 128..255 = x
__global__ void cvt_x_kernel(const float* __restrict__ x, ushort_t* __restrict__ axb) {
  int idx = blockIdx.x * blockDim.x + threadIdx.x;  // one thread per 4 elems
  if (idx >= N_NODES * 32) return;
  int n = idx >> 5, j = (idx & 31) << 2;
  float4 v = *(const float4*)(x + (size_t)n * 128 + j);
  ushort4 o;
  o.x = f2bf(v.x); o.y = f2bf(v.y); o.z = f2bf(v.z); o.w = f2bf(v.w);
  *(ushort4*)(axb + (size_t)n * 256 + 128 + j) = o;
}

// W1bt [256 cols][256 k] = transpose of [W1l;W1r]; W2bt [128 cols][256 k] = transpose of [W2l|W2r]
__global__ void cvt_w_kernel(const float* __restrict__ W1l, const float* __restrict__ W1r,
                             const float* __restrict__ W2l, const float* __restrict__ W2r,
                             ushort_t* __restrict__ W1bt, ushort_t* __restrict__ W2bt) {
  int idx = blockIdx.x * blockDim.x + threadIdx.x;
  if (idx < 65536) {
    int n = idx >> 8, k = idx & 255;
    float v = (k < 128) ? W1l[(size_t)k * 256 + n] : W1r[(size_t)(k - 128) * 256 + n];
    W1bt[idx] = f2bf(v);
  } else if (idx < 65536 + 32768) {
    int t = idx - 65536;
    int n = t >> 8, k = t & 255;
    float v = (n < 64) ? W2l[(size_t)k * 64 + n] : W2r[(size_t)k * 64 + (n - 64)];
    W2bt[t] = f2bf(v);
  }
}

// ---------------- layer-1 mean aggregation (bf16 gather, f32 acc) ----------------
// one wave per node; lane l owns features 2l, 2l+1
__global__ void agg_mean1_kernel(const int* __restrict__ rowptr, const int* __restrict__ ebuf,
                                 ushort_t* __restrict__ axb) {
  int node = blockIdx.x * 4 + (threadIdx.x >> 6);
  int lane = threadIdx.x & 63;
  int beg = rowptr[node], end = rowptr[node + 1];
  const ushort_t* xb = axb + 128;  // x part of rows
  float a0 = 0.f, a1 = 0.f;
  int e = beg;
  for (; e + 4 <= end; e += 4) {
    int s0 = ebuf[e], s1 = ebuf[e + 1], s2 = ebuf[e + 2], s3 = ebuf[e + 3];
    unsigned int v0 = *(const unsigned int*)(xb + (size_t)s0 * 256 + lane * 2);
    unsigned int v1 = *(const unsigned int*)(xb + (size_t)s1 * 256 + lane * 2);
    unsigned int v2 = *(const unsigned int*)(xb + (size_t)s2 * 256 + lane * 2);
    unsigned int v3 = *(const unsigned int*)(xb + (size_t)s3 * 256 + lane * 2);
    a0 += bf2f(v0 & 0xffff) + bf2f(v1 & 0xffff) + bf2f(v2 & 0xffff) + bf2f(v3 & 0xffff);
    a1 += bf2f(v0 >> 16) + bf2f(v1 >> 16) + bf2f(v2 >> 16) + bf2f(v3 >> 16);
  }
  for (; e < end; ++e) {
    int s = ebuf[e];
    unsigned int v = *(const unsigned int*)(xb + (size_t)s * 256 + lane * 2);
    a0 += bf2f(v & 0xffff);
    a1 += bf2f(v >> 16);
  }
  float inv = (end > beg) ? 1.0f / (float)(end - beg) : 0.0f;
  unsigned int o = (unsigned int)f2bf(a0 * inv) | ((unsigned int)f2bf(a1 * inv) << 16);
  *(unsigned int*)(axb + (size_t)node * 256 + lane * 2) = o;
}

// ---------------- bf16 MFMA GEMM (K=256 fixed) ----------------
// C[M][NC] (bf16) = A[M][256] (bf16, row-major) @ Bt[NC][256]^T (bf16)
// tile 128x128, BK=64, 4 waves (2x2), wave = 64x64 = 4x4 fragments of 16x16x32
// LDS XOR-swizzle: 16B slot index within row ^= (row&7)  (involution; staged pre-swizzled)
template<bool RELU>
__launch_bounds__(256)
__global__ void gemm_bf16_kernel(const ushort_t* __restrict__ A, const ushort_t* __restrict__ Bt,
                                 const float* __restrict__ bias, ushort_t* __restrict__ C,
                                 int M, int NC) {
  __shared__ ushort_t ldsA[128 * 64];  // 16 KB
  __shared__ ushort_t ldsB[128 * 64];  // 16 KB
  const int tid = threadIdx.x;
  const int lane = tid & 63;
  const int wm = (tid >> 6) & 1, wn = tid >> 7;
  const int rowBase = blockIdx.x * 128;
  const int colBase = blockIdx.y * 128;
  f32x4 acc[4][4];
#pragma unroll
  for (int i = 0; i < 4; ++i)
#pragma unroll
    for (int j = 0; j < 4; ++j) acc[i][j] = (f32x4){0.f, 0.f, 0.f, 0.f};

  for (int k0 = 0; k0 < GK; k0 += 64) {
#pragma unroll
    for (int i = 0; i < 4; ++i) {
      int s = tid + i * 256;          // 16B slot id; lane-contiguous per wave
      int row = s >> 3, off16 = s & 7;
      int k16 = off16 ^ (row & 7);    // inverse-swizzled global source
      int ga = rowBase + row; if (ga > M - 1) ga = M - 1;
      gload16(A + (size_t)ga * GK + k0 + k16 * 8, &ldsA[s * 8]);
      gload16(Bt + (size_t)(colBase + row) * GK + k0 + k16 * 8, &ldsB[s * 8]);
    }
    __syncthreads();
#pragma unroll
    for (int kc = 0; kc < 2; ++kc) {
      bf16x8 af[4], bfr[4];
#pragma unroll
      for (int i = 0; i < 4; ++i) {
        int rA = wm * 64 + i * 16 + (lane & 15);
        int oA = (kc * 4 + (lane >> 4)) ^ (rA & 7);   // swizzled read
        af[i] = *(const bf16x8*)&ldsA[rA * 64 + oA * 8];
        int rB = wn * 64 + i * 16 + (lane & 15);
        int oB = (kc * 4 + (lane >> 4)) ^ (rB & 7);
        bfr[i] = *(const bf16x8*)&ldsB[rB * 64 + oB * 8];
      }
#pragma unroll
      for (int mi = 0; mi < 4; ++mi)
#pragma unroll
        for (int ni = 0; ni < 4; ++ni)
          acc[mi][ni] = __builtin_amdgcn_mfma_f32_16x16x32_bf16(af[mi], bfr[ni], acc[mi][ni], 0, 0, 0);
    }
    __syncthreads();
  }
  // epilogue: C/D layout col=lane&15, row=(lane>>4)*4+r  [m89-verified]
#pragma unroll
  for (int mi = 0; mi < 4; ++mi) {
#pragma unroll
    for (int r = 0; r < 4; ++r) {
      int grow = rowBase + wm * 64 + mi * 16 + (lane >> 4) * 4 + r;
      if (grow >= M) continue;
#pragma unroll
      for (int ni = 0; ni < 4; ++ni) {
        int gcol = colBase + wn * 64 + ni * 16 + (lane & 15);
        float v = acc[mi][ni][r];
        if (RELU) v = fmaxf(v + bias[gcol], 0.f);
        C[(size_t)grow * NC + gcol] = f2bf(v);
      }
    }
  }
}

// ---------------- final: aggregate P (bf16), + b2 + Q, log_softmax ----------------
// one wave per node; lane t owns class t
__global__ void final_kernel(const int* __restrict__ rowptr, const int* __restrict__ ebuf,
                             const ushort_t* __restrict__ pq, const float* __restrict__ b2,
                             float* __restrict__ out) {
  int node = blockIdx.x * 4 + (threadIdx.x >> 6);
  int t = threadIdx.x & 63;
  int beg = rowptr[node], end = rowptr[node + 1];
  float acc = 0.f;
  int e = beg;
  for (; e + 4 <= end; e += 4) {
    int s0 = ebuf[e], s1 = ebuf[e + 1], s2 = ebuf[e + 2], s3 = ebuf[e + 3];
    acc += bf2f(pq[(size_t)s0 * 128 + t]) + bf2f(pq[(size_t)s1 * 128 + t]) +
           bf2f(pq[(size_t)s2 * 128 + t]) + bf2f(pq[(size_t)s3 * 128 + t]);
  }
  for (; e < end; ++e) acc += bf2f(pq[(size_t)ebuf[e] * 128 + t]);
  float inv = (end > beg) ? 1.0f / (float)(end - beg) : 0.0f;
  float v = acc * inv + b2[t] + bf2f(pq[(size_t)node * 128 + 64 + t]);
  float m = v;
  for (int o = 32; o > 0; o >>= 1) m = fmaxf(m, __shfl_xor(m, o));
  float ex = expf(v - m);
  float ssum = ex;
  for (int o = 32; o > 0; o >>= 1) ssum += __shfl_xor(ssum, o);
  out[(size_t)node * 64 + t] = v - m - logf(ssum);
}

// ---------------- launch ----------------

extern "C" void kernel_launch(void* const* d_in, const int* in_sizes, int n_in,
                              void* d_out, int out_size, void* d_ws, size_t ws_size,
                              hipStream_t stream) {
  const float* x   = (const float*)d_in[0];
  const int*   ei  = (const int*)d_in[1];
  const float* W1l = (const float*)d_in[2];
  const float* b1  = (const float*)d_in[3];
  const float* W1r = (const float*)d_in[4];
  const float* W2l = (const float*)d_in[5];
  const float* b2  = (const float*)d_in[6];
  const float* W2r = (const float*)d_in[7];
  float* out = (float*)d_out;
  const int* src = ei;
  const int* dst = ei + N_EDGES;

  char* w = (char*)d_ws;
  int*      deg      = (int*)(w);                            // 400 KB (→ local exclusive)
  int*      rowptr   = (int*)(w + 512 * 1024);               // 400 KB
  int*      cursor   = (int*)(w + 1024 * 1024);              // 400 KB
  int*      partials = (int*)(w + 1536 * 1024);              // 512 B
  int*      ebuf     = (int*)(w + 2048 * 1024);              // 6.4 MB (ends 8.4MB)
  ushort_t* W1bt     = (ushort_t*)(w + 8704ull * 1024);      // 128 KB (8.5MB)
  ushort_t* W2bt     = (ushort_t*)(w + 8960ull * 1024);      // 64 KB  (8.75MB)
  ushort_t* axb      = (ushort_t*)(w + 9ull * 1024 * 1024);  // 51.2 MB [N][256] bf16
  ushort_t* h        = (ushort_t*)(w + 61ull * 1024 * 1024); // 51.2 MB [N][256] bf16
  ushort_t* pq       = (ushort_t*)(w + 113ull * 1024 * 1024);// 25.6 MB [N][128] bf16

  const int NBLK = (N_NODES + 1023) / 1024;  // 98

  zero_int_kernel<<<(N_NODES + 255) / 256, 256, 0, stream>>>(deg, N_NODES);
  count_deg_kernel<<<(N_EDGES + 255) / 256, 256, 0, stream>>>(dst, deg);
  block_scan_kernel<<<NBLK, 1024, 0, stream>>>(deg, partials);
  scan_partials_kernel<<<1, 64, 0, stream>>>(partials, NBLK);
  add_offsets_kernel<<<(N_NODES + 255) / 256, 256, 0, stream>>>(deg, partials, rowptr, cursor);
  scatter_edges_kernel<<<(N_EDGES + 255) / 256, 256, 0, stream>>>(src, dst, cursor, ebuf);

  cvt_x_kernel<<<(N_NODES * 32 + 255) / 256, 256, 0, stream>>>(x, axb);
  cvt_w_kernel<<<384, 256, 0, stream>>>(W1l, W1r, W2l, W2r, W1bt, W2bt);

  agg_mean1_kernel<<<N_NODES / 4, 256, 0, stream>>>(rowptr, ebuf, axb);

  gemm_bf16_kernel<true><<<dim3((N_NODES + 127) / 128, 2), 256, 0, stream>>>(
      axb, W1bt, b1, h, N_NODES, 256);
  gemm_bf16_kernel<false><<<dim3((N_NODES + 127) / 128, 1), 256, 0, stream>>>(
      h, W2bt, nullptr, pq, N_NODES, 128);

  final_kernel<<<N_NODES / 4, 256, 0, stream>>>(rowptr, ebuf, pq, b2, out);
}

// Round 4
// 355.579 us; speedup vs baseline: 3.5206x; 1.1350x over previous
//
#include <hip/hip_runtime.h>

#define N_NODES 100000
#define N_EDGES 1600000
#define GK 256   // K dim of both GEMMs (concat for layer 1, D1 for layer 2)
#define BPX 128  // edge slices per XCD for bucketized CSR build
#define BUCKET_DIV 12500  // nodes per XCD bucket (100000/8)

typedef __attribute__((ext_vector_type(8))) short bf16x8;
typedef __attribute__((ext_vector_type(4))) float f32x4;
typedef unsigned short ushort_t;

__device__ __forceinline__ float bf2f(unsigned int bits16) {
  union { unsigned int i; float f; } v; v.i = bits16 << 16; return v.f;
}
__device__ __forceinline__ unsigned short f2bf(float f) {
  union { float f; unsigned int i; } v; v.f = f;
  unsigned int u = v.i;
  unsigned int r = (u + 0x7fffu + ((u >> 16) & 1u)) >> 16;  // RNE
  return (unsigned short)r;
}
__device__ __forceinline__ void gload16(const void* g, void* l) {
  __builtin_amdgcn_global_load_lds(
      (const __attribute__((address_space(1))) void*)g,
      (__attribute__((address_space(3))) void*)l, 16, 0, 0);
}

// ---------------- CSR build ----------------

__global__ void zero_int_kernel(int* __restrict__ p, int n) {
  int i = blockIdx.x * blockDim.x + threadIdx.x;
  if (i < n) p[i] = 0;
}

// XCD-bucketized degree count: block's bucket = blockIdx.x & 7 (round-robin
// dispatch heuristic). Each bucket's deg region is touched by one XCD only ->
// atomics stay L2-local. Correct regardless of actual dispatch mapping.
__global__ void count_deg_bucket_kernel(const int* __restrict__ dst, int* __restrict__ deg) {
  int xcd = blockIdx.x & 7;
  int slice = blockIdx.x >> 3;
  const int S = N_EDGES / BPX;  // 12500
  int lo = slice * S, hi = lo + S;
  for (int e = lo + threadIdx.x * 4; e < hi; e += blockDim.x * 4) {
    int4 d4 = *(const int4*)(dst + e);
    if (d4.x / BUCKET_DIV == xcd) atomicAdd(&deg[d4.x], 1);
    if (d4.y / BUCKET_DIV == xcd) atomicAdd(&deg[d4.y], 1);
    if (d4.z / BUCKET_DIV == xcd) atomicAdd(&deg[d4.z], 1);
    if (d4.w / BUCKET_DIV == xcd) atomicAdd(&deg[d4.w], 1);
  }
}

// stage 1: per-block (1024) scan, in-place deg -> local exclusive, partials[b] = block total
__global__ void block_scan_kernel(int* __restrict__ deg, int* __restrict__ partials) {
  __shared__ int wsum[16];
  int tid = threadIdx.x;
  int i = blockIdx.x * 1024 + tid;
  int lane = tid & 63, wave = tid >> 6;
  int v = (i < N_NODES) ? deg[i] : 0;
  int s = v;
#pragma unroll
  for (int o = 1; o < 64; o <<= 1) { int t = __shfl_up(s, o); if (lane >= o) s += t; }
  if (lane == 63) wsum[wave] = s;
  __syncthreads();
  if (wave == 0) {
    int t = (lane < 16) ? wsum[lane] : 0;
    int ss = t;
#pragma unroll
    for (int o = 1; o < 16; o <<= 1) { int u = __shfl_up(ss, o); if (lane >= o) ss += u; }
    if (lane < 16) wsum[lane] = ss - t;  // exclusive wave offset
    if (lane == 15) partials[blockIdx.x] = ss;  // block total
  }
  __syncthreads();
  if (i < N_NODES) deg[i] = s + wsum[wave] - v;  // local exclusive
}

// stage 2: one wave scans block partials (exclusive, in place)
__global__ void scan_partials_kernel(int* __restrict__ partials, int n) {
  int lane = threadIdx.x;
  int carry = 0;
  for (int base = 0; base < n; base += 64) {
    int i = base + lane;
    int v = (i < n) ? partials[i] : 0;
    int s = v;
#pragma unroll
    for (int o = 1; o < 64; o <<= 1) { int t = __shfl_up(s, o); if (lane >= o) s += t; }
    int tot = __shfl(s, 63);
    if (i < n) partials[i] = carry + s - v;
    carry += tot;
  }
}

// stage 3: add block offsets -> rowptr + cursor
__global__ void add_offsets_kernel(const int* __restrict__ local_excl,
                                   const int* __restrict__ partials,
                                   int* __restrict__ rowptr, int* __restrict__ cursor) {
  int i = blockIdx.x * blockDim.x + threadIdx.x;
  if (i < N_NODES) {
    int r = local_excl[i] + partials[i >> 10];
    rowptr[i] = r;
    cursor[i] = r;
  }
  if (i == 0) rowptr[N_NODES] = N_EDGES;
}

// XCD-bucketized scatter: each bucket's cursor+ebuf region owned by one XCD ->
// random 4B ebuf writes coalesce in that XCD's L2 (fixes 16x write amplification).
__global__ void scatter_edges_bucket_kernel(const int* __restrict__ src, const int* __restrict__ dst,
                                            int* cursor, int* __restrict__ ebuf) {
  int xcd = blockIdx.x & 7;
  int slice = blockIdx.x >> 3;
  const int S = N_EDGES / BPX;  // 12500
  int lo = slice * S, hi = lo + S;
  for (int e = lo + threadIdx.x * 4; e < hi; e += blockDim.x * 4) {
    int4 d4 = *(const int4*)(dst + e);
    int4 s4 = *(const int4*)(src + e);
    if (d4.x / BUCKET_DIV == xcd) ebuf[atomicAdd(&cursor[d4.x], 1)] = s4.x;
    if (d4.y / BUCKET_DIV == xcd) ebuf[atomicAdd(&cursor[d4.y], 1)] = s4.y;
    if (d4.z / BUCKET_DIV == xcd) ebuf[atomicAdd(&cursor[d4.z], 1)] = s4.z;
    if (d4.w / BUCKET_DIV == xcd) ebuf[atomicAdd(&cursor[d4.w], 1)] = s4.w;
  }
}

// ---------------- conversions ----------------
// axb layout: [N][256] bf16, cols 0..127 = mean1 (filled by agg), 128..255 = x
__global__ void cvt_x_kernel(const float* __restrict__ x, ushort_t* __restrict__ axb) {
  int idx = blockIdx.x * blockDim.x + threadIdx.x;  // one thread per 4 elems
  if (idx >= N_NODES * 32) return;
  int n = idx >> 5, j = (idx & 31) << 2;
  float4 v = *(const float4*)(x + (size_t)n * 128 + j);
  ushort4 o;
  o.x = f2bf(v.x); o.y = f2bf(v.y); o.z = f2bf(v.z); o.w = f2bf(v.w);
  *(ushort4*)(axb + (size_t)n * 256 + 128 + j) = o;
}

// W1bt [256 cols][256 k] = transpose of [W1l;W1r]; W2bt [128 cols][256 k] = transpose of [W2l|W2r]
__global__ void cvt_w_kernel(const float* __restrict__ W1l, const float* __restrict__ W1r,
                             const float* __restrict__ W2l, const float* __restrict__ W2r,
                             ushort_t* __restrict__ W1bt, ushort_t* __restrict__ W2bt) {
  int idx = blockIdx.x * blockDim.x + threadIdx.x;
  if (idx < 65536) {
    int n = idx >> 8, k = idx & 255;
    float v = (k < 128) ? W1l[(size_t)k * 256 + n] : W1r[(size_t)(k - 128) * 256 + n];
    W1bt[idx] = f2bf(v);
  } else if (idx < 65536 + 32768) {
    int t = idx - 65536;
    int n = t >> 8, k = t & 255;
    float v = (n < 64) ? W2l[(size_t)k * 64 + n] : W2r[(size_t)k * 64 + (n - 64)];
    W2bt[t] = f2bf(v);
  }
}

// ---------------- layer-1 mean aggregation (bf16 gather, f32 acc) ----------------
// one wave per node; lane l owns features 2l, 2l+1
__global__ void agg_mean1_kernel(const int* __restrict__ rowptr, const int* __restrict__ ebuf,
                                 ushort_t* __restrict__ axb) {
  int node = blockIdx.x * 4 + (threadIdx.x >> 6);
  int lane = threadIdx.x & 63;
  int beg = rowptr[node], end = rowptr[node + 1];
  const ushort_t* xb = axb + 128;  // x part of rows
  float a0 = 0.f, a1 = 0.f;
  int e = beg;
  for (; e + 4 <= end; e += 4) {
    int s0 = ebuf[e], s1 = ebuf[e + 1], s2 = ebuf[e + 2], s3 = ebuf[e + 3];
    unsigned int v0 = *(const unsigned int*)(xb + (size_t)s0 * 256 + lane * 2);
    unsigned int v1 = *(const unsigned int*)(xb + (size_t)s1 * 256 + lane * 2);
    unsigned int v2 = *(const unsigned int*)(xb + (size_t)s2 * 256 + lane * 2);
    unsigned int v3 = *(const unsigned int*)(xb + (size_t)s3 * 256 + lane * 2);
    a0 += bf2f(v0 & 0xffff) + bf2f(v1 & 0xffff) + bf2f(v2 & 0xffff) + bf2f(v3 & 0xffff);
    a1 += bf2f(v0 >> 16) + bf2f(v1 >> 16) + bf2f(v2 >> 16) + bf2f(v3 >> 16);
  }
  for (; e < end; ++e) {
    int s = ebuf[e];
    unsigned int v = *(const unsigned int*)(xb + (size_t)s * 256 + lane * 2);
    a0 += bf2f(v & 0xffff);
    a1 += bf2f(v >> 16);
  }
  float inv = (end > beg) ? 1.0f / (float)(end - beg) : 0.0f;
  unsigned int o = (unsigned int)f2bf(a0 * inv) | ((unsigned int)f2bf(a1 * inv) << 16);
  *(unsigned int*)(axb + (size_t)node * 256 + lane * 2) = o;
}

// ---------------- bf16 MFMA GEMM (K=256 fixed) ----------------
// C[M][NC] (bf16) = A[M][256] (bf16, row-major) @ Bt[NC][256]^T (bf16)
// tile 128x128, BK=64, 4 waves (2x2), wave = 64x64 = 4x4 fragments of 16x16x32
// LDS XOR-swizzle: 16B slot index within row ^= (row&7)  (involution; staged pre-swizzled)
template<bool RELU>
__launch_bounds__(256)
__global__ void gemm_bf16_kernel(const ushort_t* __restrict__ A, const ushort_t* __restrict__ Bt,
                                 const float* __restrict__ bias, ushort_t* __restrict__ C,
                                 int M, int NC) {
  __shared__ ushort_t ldsA[128 * 64];  // 16 KB
  __shared__ ushort_t ldsB[128 * 64];  // 16 KB
  const int tid = threadIdx.x;
  const int lane = tid & 63;
  const int wm = (tid >> 6) & 1, wn = tid >> 7;
  const int rowBase = blockIdx.x * 128;
  const int colBase = blockIdx.y * 128;
  f32x4 acc[4][4];
#pragma unroll
  for (int i = 0; i < 4; ++i)
#pragma unroll
    for (int j = 0; j < 4; ++j) acc[i][j] = (f32x4){0.f, 0.f, 0.f, 0.f};

  for (int k0 = 0; k0 < GK; k0 += 64) {
#pragma unroll
    for (int i = 0; i < 4; ++i) {
      int s = tid + i * 256;          // 16B slot id; lane-contiguous per wave
      int row = s >> 3, off16 = s & 7;
      int k16 = off16 ^ (row & 7);    // inverse-swizzled global source
      int ga = rowBase + row; if (ga > M - 1) ga = M - 1;
      gload16(A + (size_t)ga * GK + k0 + k16 * 8, &ldsA[s * 8]);
      gload16(Bt + (size_t)(colBase + row) * GK + k0 + k16 * 8, &ldsB[s * 8]);
    }
    __syncthreads();
#pragma unroll
    for (int kc = 0; kc < 2; ++kc) {
      bf16x8 af[4], bfr[4];
#pragma unroll
      for (int i = 0; i < 4; ++i) {
        int rA = wm * 64 + i * 16 + (lane & 15);
        int oA = (kc * 4 + (lane >> 4)) ^ (rA & 7);   // swizzled read
        af[i] = *(const bf16x8*)&ldsA[rA * 64 + oA * 8];
        int rB = wn * 64 + i * 16 + (lane & 15);
        int oB = (kc * 4 + (lane >> 4)) ^ (rB & 7);
        bfr[i] = *(const bf16x8*)&ldsB[rB * 64 + oB * 8];
      }
#pragma unroll
      for (int mi = 0; mi < 4; ++mi)
#pragma unroll
        for (int ni = 0; ni < 4; ++ni)
          acc[mi][ni] = __builtin_amdgcn_mfma_f32_16x16x32_bf16(af[mi], bfr[ni], acc[mi][ni], 0, 0, 0);
    }
    __syncthreads();
  }
  // epilogue: C/D layout col=lane&15, row=(lane>>4)*4+r  [m89-verified]
#pragma unroll
  for (int mi = 0; mi < 4; ++mi) {
#pragma unroll
    for (int r = 0; r < 4; ++r) {
      int grow = rowBase + wm * 64 + mi * 16 + (lane >> 4) * 4 + r;
      if (grow >= M) continue;
#pragma unroll
      for (int ni = 0; ni < 4; ++ni) {
        int gcol = colBase + wn * 64 + ni * 16 + (lane & 15);
        float v = acc[mi][ni][r];
        if (RELU) v = fmaxf(v + bias[gcol], 0.f);
        C[(size_t)grow * NC + gcol] = f2bf(v);
      }
    }
  }
}

// ---------------- final: aggregate P (bf16), + b2 + Q, log_softmax ----------------
// one wave per node; lane t owns class t
__global__ void final_kernel(const int* __restrict__ rowptr, const int* __restrict__ ebuf,
                             const ushort_t* __restrict__ pq, const float* __restrict__ b2,
                             float* __restrict__ out) {
  int node = blockIdx.x * 4 + (threadIdx.x >> 6);
  int t = threadIdx.x & 63;
  int beg = rowptr[node], end = rowptr[node + 1];
  float acc = 0.f;
  int e = beg;
  for (; e + 4 <= end; e += 4) {
    int s0 = ebuf[e], s1 = ebuf[e + 1], s2 = ebuf[e + 2], s3 = ebuf[e + 3];
    acc += bf2f(pq[(size_t)s0 * 128 + t]) + bf2f(pq[(size_t)s1 * 128 + t]) +
           bf2f(pq[(size_t)s2 * 128 + t]) + bf2f(pq[(size_t)s3 * 128 + t]);
  }
  for (; e < end; ++e) acc += bf2f(pq[(size_t)ebuf[e] * 128 + t]);
  float inv = (end > beg) ? 1.0f / (float)(end - beg) : 0.0f;
  float v = acc * inv + b2[t] + bf2f(pq[(size_t)node * 128 + 64 + t]);
  float m = v;
  for (int o = 32; o > 0; o >>= 1) m = fmaxf(m, __shfl_xor(m, o));
  float ex = expf(v - m);
  float ssum = ex;
  for (int o = 32; o > 0; o >>= 1) ssum += __shfl_xor(ssum, o);
  out[(size_t)node * 64 + t] = v - m - logf(ssum);
}

// ---------------- launch ----------------

extern "C" void kernel_launch(void* const* d_in, const int* in_sizes, int n_in,
                              void* d_out, int out_size, void* d_ws, size_t ws_size,
                              hipStream_t stream) {
  const float* x   = (const float*)d_in[0];
  const int*   ei  = (const int*)d_in[1];
  const float* W1l = (const float*)d_in[2];
  const float* b1  = (const float*)d_in[3];
  const float* W1r = (const float*)d_in[4];
  const float* W2l = (const float*)d_in[5];
  const float* b2  = (const float*)d_in[6];
  const float* W2r = (const float*)d_in[7];
  float* out = (float*)d_out;
  const int* src = ei;
  const int* dst = ei + N_EDGES;

  char* w = (char*)d_ws;
  int*      deg      = (int*)(w);                            // 400 KB (→ local exclusive)
  int*      rowptr   = (int*)(w + 512 * 1024);               // 400 KB
  int*      cursor   = (int*)(w + 1024 * 1024);              // 400 KB
  int*      partials = (int*)(w + 1536 * 1024);              // 512 B
  int*      ebuf     = (int*)(w + 2048 * 1024);              // 6.4 MB (ends 8.4MB)
  ushort_t* W1bt     = (ushort_t*)(w + 8704ull * 1024);      // 128 KB (8.5MB)
  ushort_t* W2bt     = (ushort_t*)(w + 8960ull * 1024);      // 64 KB  (8.75MB)
  ushort_t* axb      = (ushort_t*)(w + 9ull * 1024 * 1024);  // 51.2 MB [N][256] bf16
  ushort_t* h        = (ushort_t*)(w + 61ull * 1024 * 1024); // 51.2 MB [N][256] bf16
  ushort_t* pq       = (ushort_t*)(w + 113ull * 1024 * 1024);// 25.6 MB [N][128] bf16

  const int NBLK = (N_NODES + 1023) / 1024;  // 98

  zero_int_kernel<<<(N_NODES + 255) / 256, 256, 0, stream>>>(deg, N_NODES);
  count_deg_bucket_kernel<<<8 * BPX, 256, 0, stream>>>(dst, deg);
  block_scan_kernel<<<NBLK, 1024, 0, stream>>>(deg, partials);
  scan_partials_kernel<<<1, 64, 0, stream>>>(partials, NBLK);
  add_offsets_kernel<<<(N_NODES + 255) / 256, 256, 0, stream>>>(deg, partials, rowptr, cursor);
  scatter_edges_bucket_kernel<<<8 * BPX, 256, 0, stream>>>(src, dst, cursor, ebuf);

  cvt_x_kernel<<<(N_NODES * 32 + 255) / 256, 256, 0, stream>>>(x, axb);
  cvt_w_kernel<<<384, 256, 0, stream>>>(W1l, W1r, W2l, W2r, W1bt, W2bt);

  agg_mean1_kernel<<<N_NODES / 4, 256, 0, stream>>>(rowptr, ebuf, axb);

  gemm_bf16_kernel<true><<<dim3((N_NODES + 127) / 128, 2), 256, 0, stream>>>(
      axb, W1bt, b1, h, N_NODES, 256);
  gemm_bf16_kernel<false><<<dim3((N_NODES + 127) / 128, 1), 256, 0, stream>>>(
      h, W2bt, nullptr, pq, N_NODES, 128);

  final_kernel<<<N_NODES / 4, 256, 0, stream>>>(rowptr, ebuf, pq, b2, out);
}

// Round 5
// 334.486 us; speedup vs baseline: 3.7426x; 1.0631x over previous
//
#include <hip/hip_runtime.h>

#define N_NODES 100000
#define N_EDGES 1600000
#define GK 256   // K dim of both GEMMs (concat for layer 1, D1 for layer 2)
#define BPX 128  // edge slices per XCD for bucketized CSR build
#define BUCKET_DIV 12500  // nodes per XCD bucket (100000/8)

typedef __attribute__((ext_vector_type(8))) short bf16x8;
typedef __attribute__((ext_vector_type(4))) float f32x4;
typedef unsigned short ushort_t;

__device__ __forceinline__ float bf2f(unsigned int bits16) {
  union { unsigned int i; float f; } v; v.i = bits16 << 16; return v.f;
}
__device__ __forceinline__ unsigned short f2bf(float f) {
  union { float f; unsigned int i; } v; v.f = f;
  unsigned int u = v.i;
  unsigned int r = (u + 0x7fffu + ((u >> 16) & 1u)) >> 16;  // RNE
  return (unsigned short)r;
}
__device__ __forceinline__ void gload16(const void* g, void* l) {
  __builtin_amdgcn_global_load_lds(
      (const __attribute__((address_space(1))) void*)g,
      (__attribute__((address_space(3))) void*)l, 16, 0, 0);
}

// ---------------- CSR build ----------------

__global__ void zero_int_kernel(int* __restrict__ p, int n) {
  int i = blockIdx.x * blockDim.x + threadIdx.x;
  if (i < n) p[i] = 0;
}

// XCD-bucketized degree count (see R3 notes): bucket = blockIdx.x & 7
__global__ void count_deg_bucket_kernel(const int* __restrict__ dst, int* __restrict__ deg) {
  int xcd = blockIdx.x & 7;
  int slice = blockIdx.x >> 3;
  const int S = N_EDGES / BPX;  // 12500
  int lo = slice * S, hi = lo + S;
  for (int e = lo + threadIdx.x * 4; e < hi; e += blockDim.x * 4) {
    int4 d4 = *(const int4*)(dst + e);
    if (d4.x / BUCKET_DIV == xcd) atomicAdd(&deg[d4.x], 1);
    if (d4.y / BUCKET_DIV == xcd) atomicAdd(&deg[d4.y], 1);
    if (d4.z / BUCKET_DIV == xcd) atomicAdd(&deg[d4.z], 1);
    if (d4.w / BUCKET_DIV == xcd) atomicAdd(&deg[d4.w], 1);
  }
}

// stage 1: per-block (1024) scan, in-place deg -> local exclusive, partials[b] = block total
__global__ void block_scan_kernel(int* __restrict__ deg, int* __restrict__ partials) {
  __shared__ int wsum[16];
  int tid = threadIdx.x;
  int i = blockIdx.x * 1024 + tid;
  int lane = tid & 63, wave = tid >> 6;
  int v = (i < N_NODES) ? deg[i] : 0;
  int s = v;
#pragma unroll
  for (int o = 1; o < 64; o <<= 1) { int t = __shfl_up(s, o); if (lane >= o) s += t; }
  if (lane == 63) wsum[wave] = s;
  __syncthreads();
  if (wave == 0) {
    int t = (lane < 16) ? wsum[lane] : 0;
    int ss = t;
#pragma unroll
    for (int o = 1; o < 16; o <<= 1) { int u = __shfl_up(ss, o); if (lane >= o) ss += u; }
    if (lane < 16) wsum[lane] = ss - t;  // exclusive wave offset
    if (lane == 15) partials[blockIdx.x] = ss;  // block total
  }
  __syncthreads();
  if (i < N_NODES) deg[i] = s + wsum[wave] - v;  // local exclusive
}

// stage 2: one wave scans block partials (exclusive, in place)
__global__ void scan_partials_kernel(int* __restrict__ partials, int n) {
  int lane = threadIdx.x;
  int carry = 0;
  for (int base = 0; base < n; base += 64) {
    int i = base + lane;
    int v = (i < n) ? partials[i] : 0;
    int s = v;
#pragma unroll
    for (int o = 1; o < 64; o <<= 1) { int t = __shfl_up(s, o); if (lane >= o) s += t; }
    int tot = __shfl(s, 63);
    if (i < n) partials[i] = carry + s - v;
    carry += tot;
  }
}

// stage 3: add block offsets -> rowptr + cursor
__global__ void add_offsets_kernel(const int* __restrict__ local_excl,
                                   const int* __restrict__ partials,
                                   int* __restrict__ rowptr, int* __restrict__ cursor) {
  int i = blockIdx.x * blockDim.x + threadIdx.x;
  if (i < N_NODES) {
    int r = local_excl[i] + partials[i >> 10];
    rowptr[i] = r;
    cursor[i] = r;
  }
  if (i == 0) rowptr[N_NODES] = N_EDGES;
}

// XCD-bucketized scatter (fixes 16x write amplification; see R3 notes)
__global__ void scatter_edges_bucket_kernel(const int* __restrict__ src, const int* __restrict__ dst,
                                            int* cursor, int* __restrict__ ebuf) {
  int xcd = blockIdx.x & 7;
  int slice = blockIdx.x >> 3;
  const int S = N_EDGES / BPX;  // 12500
  int lo = slice * S, hi = lo + S;
  for (int e = lo + threadIdx.x * 4; e < hi; e += blockDim.x * 4) {
    int4 d4 = *(const int4*)(dst + e);
    int4 s4 = *(const int4*)(src + e);
    if (d4.x / BUCKET_DIV == xcd) ebuf[atomicAdd(&cursor[d4.x], 1)] = s4.x;
    if (d4.y / BUCKET_DIV == xcd) ebuf[atomicAdd(&cursor[d4.y], 1)] = s4.y;
    if (d4.z / BUCKET_DIV == xcd) ebuf[atomicAdd(&cursor[d4.z], 1)] = s4.z;
    if (d4.w / BUCKET_DIV == xcd) ebuf[atomicAdd(&cursor[d4.w], 1)] = s4.w;
  }
}

// ---------------- conversions ----------------
// axb layout: [N][256] bf16, cols 0..127 = mean1 (filled by agg), 128..255 = x
__global__ void cvt_x_kernel(const float* __restrict__ x, ushort_t* __restrict__ axb) {
  int idx = blockIdx.x * blockDim.x + threadIdx.x;  // one thread per 4 elems
  if (idx >= N_NODES * 32) return;
  int n = idx >> 5, j = (idx & 31) << 2;
  float4 v = *(const float4*)(x + (size_t)n * 128 + j);
  ushort4 o;
  o.x = f2bf(v.x); o.y = f2bf(v.y); o.z = f2bf(v.z); o.w = f2bf(v.w);
  *(ushort4*)(axb + (size_t)n * 256 + 128 + j) = o;
}

// W1bt [256 cols][256 k] = transpose of [W1l;W1r]; W2bt [128 cols][256 k] = transpose of [W2l|W2r]
__global__ void cvt_w_kernel(const float* __restrict__ W1l, const float* __restrict__ W1r,
                             const float* __restrict__ W2l, const float* __restrict__ W2r,
                             ushort_t* __restrict__ W1bt, ushort_t* __restrict__ W2bt) {
  int idx = blockIdx.x * blockDim.x + threadIdx.x;
  if (idx < 65536) {
    int n = idx >> 8, k = idx & 255;
    float v = (k < 128) ? W1l[(size_t)k * 256 + n] : W1r[(size_t)(k - 128) * 256 + n];
    W1bt[idx] = f2bf(v);
  } else if (idx < 65536 + 32768) {
    int t = idx - 65536;
    int n = t >> 8, k = t & 255;
    float v = (n < 64) ? W2l[(size_t)k * 64 + n] : W2r[(size_t)k * 64 + (n - 64)];
    W2bt[t] = f2bf(v);
  }
}

// ---------------- layer-1 mean aggregation ----------------
// wave per node, 2 edges per iteration: half h (lanes 32-63 = h1) services edge
// e+h; lane j=l&31 loads 8B = features 4j..4j+3. Cross-half combine via shfl_xor(32).
__global__ void agg_mean1_kernel(const int* __restrict__ rowptr, const int* __restrict__ ebuf,
                                 ushort_t* __restrict__ axb) {
  int node = blockIdx.x * 4 + (threadIdx.x >> 6);
  int l = threadIdx.x & 63;
  int half = l >> 5, j = l & 31;
  int beg = rowptr[node], end = rowptr[node + 1];
  const ushort_t* xb = axb + 128;  // x part of rows
  float a0 = 0.f, a1 = 0.f, a2 = 0.f, a3 = 0.f;
  int e = beg;
  for (; e + 8 <= end; e += 8) {
#pragma unroll
    for (int k = 0; k < 4; ++k) {
      int s = ebuf[e + 2 * k + half];
      uint2 v = *(const uint2*)(xb + (size_t)s * 256 + 4 * j);
      a0 += bf2f(v.x & 0xffff); a1 += bf2f(v.x >> 16);
      a2 += bf2f(v.y & 0xffff); a3 += bf2f(v.y >> 16);
    }
  }
  for (; e + 2 <= end; e += 2) {
    int s = ebuf[e + half];
    uint2 v = *(const uint2*)(xb + (size_t)s * 256 + 4 * j);
    a0 += bf2f(v.x & 0xffff); a1 += bf2f(v.x >> 16);
    a2 += bf2f(v.y & 0xffff); a3 += bf2f(v.y >> 16);
  }
  if (e < end && half == 0) {  // odd tail: half 0 only
    int s = ebuf[e];
    uint2 v = *(const uint2*)(xb + (size_t)s * 256 + 4 * j);
    a0 += bf2f(v.x & 0xffff); a1 += bf2f(v.x >> 16);
    a2 += bf2f(v.y & 0xffff); a3 += bf2f(v.y >> 16);
  }
  a0 += __shfl_xor(a0, 32); a1 += __shfl_xor(a1, 32);
  a2 += __shfl_xor(a2, 32); a3 += __shfl_xor(a3, 32);
  if (half == 0) {
    float inv = (end > beg) ? 1.0f / (float)(end - beg) : 0.0f;
    uint2 o;
    o.x = (unsigned int)f2bf(a0 * inv) | ((unsigned int)f2bf(a1 * inv) << 16);
    o.y = (unsigned int)f2bf(a2 * inv) | ((unsigned int)f2bf(a3 * inv) << 16);
    *(uint2*)(axb + (size_t)node * 256 + 4 * j) = o;
  }
}

// ---------------- bf16 MFMA GEMM (K=256 fixed) ----------------
// C[M][NC] (bf16) = A[M][256] (bf16, row-major) @ Bt[NC][256]^T (bf16)
// tile 128x128, BK=64, 4 waves (2x2), wave = 64x64 = 4x4 fragments of 16x16x32
// LDS XOR-swizzle: 16B slot index within row ^= (row&7)  (involution; staged pre-swizzled)
template<bool RELU>
__launch_bounds__(256)
__global__ void gemm_bf16_kernel(const ushort_t* __restrict__ A, const ushort_t* __restrict__ Bt,
                                 const float* __restrict__ bias, ushort_t* __restrict__ C,
                                 int M, int NC) {
  __shared__ ushort_t ldsA[128 * 64];  // 16 KB
  __shared__ ushort_t ldsB[128 * 64];  // 16 KB
  const int tid = threadIdx.x;
  const int lane = tid & 63;
  const int wm = (tid >> 6) & 1, wn = tid >> 7;
  const int rowBase = blockIdx.x * 128;
  const int colBase = blockIdx.y * 128;
  f32x4 acc[4][4];
#pragma unroll
  for (int i = 0; i < 4; ++i)
#pragma unroll
    for (int j = 0; j < 4; ++j) acc[i][j] = (f32x4){0.f, 0.f, 0.f, 0.f};

  for (int k0 = 0; k0 < GK; k0 += 64) {
#pragma unroll
    for (int i = 0; i < 4; ++i) {
      int s = tid + i * 256;          // 16B slot id; lane-contiguous per wave
      int row = s >> 3, off16 = s & 7;
      int k16 = off16 ^ (row & 7);    // inverse-swizzled global source
      int ga = rowBase + row; if (ga > M - 1) ga = M - 1;
      gload16(A + (size_t)ga * GK + k0 + k16 * 8, &ldsA[s * 8]);
      gload16(Bt + (size_t)(colBase + row) * GK + k0 + k16 * 8, &ldsB[s * 8]);
    }
    __syncthreads();
#pragma unroll
    for (int kc = 0; kc < 2; ++kc) {
      bf16x8 af[4], bfr[4];
#pragma unroll
      for (int i = 0; i < 4; ++i) {
        int rA = wm * 64 + i * 16 + (lane & 15);
        int oA = (kc * 4 + (lane >> 4)) ^ (rA & 7);   // swizzled read
        af[i] = *(const bf16x8*)&ldsA[rA * 64 + oA * 8];
        int rB = wn * 64 + i * 16 + (lane & 15);
        int oB = (kc * 4 + (lane >> 4)) ^ (rB & 7);
        bfr[i] = *(const bf16x8*)&ldsB[rB * 64 + oB * 8];
      }
#pragma unroll
      for (int mi = 0; mi < 4; ++mi)
#pragma unroll
        for (int ni = 0; ni < 4; ++ni)
          acc[mi][ni] = __builtin_amdgcn_mfma_f32_16x16x32_bf16(af[mi], bfr[ni], acc[mi][ni], 0, 0, 0);
    }
    __syncthreads();
  }
  // epilogue: C/D layout col=lane&15, row=(lane>>4)*4+r  [m89-verified]
#pragma unroll
  for (int mi = 0; mi < 4; ++mi) {
#pragma unroll
    for (int r = 0; r < 4; ++r) {
      int grow = rowBase + wm * 64 + mi * 16 + (lane >> 4) * 4 + r;
      if (grow >= M) continue;
#pragma unroll
      for (int ni = 0; ni < 4; ++ni) {
        int gcol = colBase + wn * 64 + ni * 16 + (lane & 15);
        float v = acc[mi][ni][r];
        if (RELU) v = fmaxf(v + bias[gcol], 0.f);
        C[(size_t)grow * NC + gcol] = f2bf(v);
      }
    }
  }
}

// ---------------- final: aggregate P, + b2 + Q, log_softmax ----------------
// wave per node, 2 edges per iteration (half h services edge e+h);
// lane j=l&31 loads 4B = classes 2j,2j+1. Cross-half combine via shfl_xor(32).
__global__ void final_kernel(const int* __restrict__ rowptr, const int* __restrict__ ebuf,
                             const ushort_t* __restrict__ pq, const float* __restrict__ b2,
                             float* __restrict__ out) {
  int node = blockIdx.x * 4 + (threadIdx.x >> 6);
  int l = threadIdx.x & 63;
  int half = l >> 5, j = l & 31;
  int beg = rowptr[node], end = rowptr[node + 1];
  float a0 = 0.f, a1 = 0.f;
  int e = beg;
  for (; e + 8 <= end; e += 8) {
#pragma unroll
    for (int k = 0; k < 4; ++k) {
      int s = ebuf[e + 2 * k + half];
      unsigned int v = *(const unsigned int*)(pq + (size_t)s * 128 + 2 * j);
      a0 += bf2f(v & 0xffff); a1 += bf2f(v >> 16);
    }
  }
  for (; e + 2 <= end; e += 2) {
    int s = ebuf[e + half];
    unsigned int v = *(const unsigned int*)(pq + (size_t)s * 128 + 2 * j);
    a0 += bf2f(v & 0xffff); a1 += bf2f(v >> 16);
  }
  if (e < end && half == 0) {
    int s = ebuf[e];
    unsigned int v = *(const unsigned int*)(pq + (size_t)s * 128 + 2 * j);
    a0 += bf2f(v & 0xffff); a1 += bf2f(v >> 16);
  }
  a0 += __shfl_xor(a0, 32);
  a1 += __shfl_xor(a1, 32);
  float inv = (end > beg) ? 1.0f / (float)(end - beg) : 0.0f;
  unsigned int q = *(const unsigned int*)(pq + (size_t)node * 128 + 64 + 2 * j);
  float v0 = a0 * inv + b2[2 * j] + bf2f(q & 0xffff);
  float v1 = a1 * inv + b2[2 * j + 1] + bf2f(q >> 16);
  // log_softmax over 64 classes held 2-per-lane across 32 lanes (halves identical)
  float m = fmaxf(v0, v1);
#pragma unroll
  for (int o = 16; o > 0; o >>= 1) m = fmaxf(m, __shfl_xor(m, o));
  float ssum = expf(v0 - m) + expf(v1 - m);
#pragma unroll
  for (int o = 16; o > 0; o >>= 1) ssum += __shfl_xor(ssum, o);
  if (half == 0) {
    float ls = logf(ssum);
    float2 o2 = {v0 - m - ls, v1 - m - ls};
    *(float2*)(out + (size_t)node * 64 + 2 * j) = o2;
  }
}

// ---------------- launch ----------------

extern "C" void kernel_launch(void* const* d_in, const int* in_sizes, int n_in,
                              void* d_out, int out_size, void* d_ws, size_t ws_size,
                              hipStream_t stream) {
  const float* x   = (const float*)d_in[0];
  const int*   ei  = (const int*)d_in[1];
  const float* W1l = (const float*)d_in[2];
  const float* b1  = (const float*)d_in[3];
  const float* W1r = (const float*)d_in[4];
  const float* W2l = (const float*)d_in[5];
  const float* b2  = (const float*)d_in[6];
  const float* W2r = (const float*)d_in[7];
  float* out = (float*)d_out;
  const int* src = ei;
  const int* dst = ei + N_EDGES;

  char* w = (char*)d_ws;
  int*      deg      = (int*)(w);                            // 400 KB (→ local exclusive)
  int*      rowptr   = (int*)(w + 512 * 1024);               // 400 KB
  int*      cursor   = (int*)(w + 1024 * 1024);              // 400 KB
  int*      partials = (int*)(w + 1536 * 1024);              // 512 B
  int*      ebuf     = (int*)(w + 2048 * 1024);              // 6.4 MB (ends 8.4MB)
  ushort_t* W1bt     = (ushort_t*)(w + 8704ull * 1024);      // 128 KB (8.5MB)
  ushort_t* W2bt     = (ushort_t*)(w + 8960ull * 1024);      // 64 KB  (8.75MB)
  ushort_t* axb      = (ushort_t*)(w + 9ull * 1024 * 1024);  // 51.2 MB [N][256] bf16
  ushort_t* h        = (ushort_t*)(w + 61ull * 1024 * 1024); // 51.2 MB [N][256] bf16
  ushort_t* pq       = (ushort_t*)(w + 113ull * 1024 * 1024);// 25.6 MB [N][128] bf16

  const int NBLK = (N_NODES + 1023) / 1024;  // 98

  zero_int_kernel<<<(N_NODES + 255) / 256, 256, 0, stream>>>(deg, N_NODES);
  count_deg_bucket_kernel<<<8 * BPX, 256, 0, stream>>>(dst, deg);
  block_scan_kernel<<<NBLK, 1024, 0, stream>>>(deg, partials);
  scan_partials_kernel<<<1, 64, 0, stream>>>(partials, NBLK);
  add_offsets_kernel<<<(N_NODES + 255) / 256, 256, 0, stream>>>(deg, partials, rowptr, cursor);
  scatter_edges_bucket_kernel<<<8 * BPX, 256, 0, stream>>>(src, dst, cursor, ebuf);

  cvt_x_kernel<<<(N_NODES * 32 + 255) / 256, 256, 0, stream>>>(x, axb);
  cvt_w_kernel<<<384, 256, 0, stream>>>(W1l, W1r, W2l, W2r, W1bt, W2bt);

  agg_mean1_kernel<<<N_NODES / 4, 256, 0, stream>>>(rowptr, ebuf, axb);

  gemm_bf16_kernel<true><<<dim3((N_NODES + 127) / 128, 2), 256, 0, stream>>>(
      axb, W1bt, b1, h, N_NODES, 256);
  gemm_bf16_kernel<false><<<dim3((N_NODES + 127) / 128, 1), 256, 0, stream>>>(
      h, W2bt, nullptr, pq, N_NODES, 128);

  final_kernel<<<N_NODES / 4, 256, 0, stream>>>(rowptr, ebuf, pq, b2, out);
}

// Round 6
// 239.327 us; speedup vs baseline: 5.2308x; 1.3976x over previous
//
#include <hip/hip_runtime.h>

#define N_NODES 100000
#define N_EDGES 1600000
#define GK 256      // K dim of both GEMMs
#define NBKT 196    // buckets of 512 nodes: (100000+511)>>9
#define NBIN 128    // blocks for bin count/scatter
#define EPB (N_EDGES / NBIN)  // 12500 edges per bin block

typedef __attribute__((ext_vector_type(8))) short bf16x8;
typedef __attribute__((ext_vector_type(4))) float f32x4;
typedef unsigned short ushort_t;

__device__ __forceinline__ float bf2f(unsigned int bits16) {
  union { unsigned int i; float f; } v; v.i = bits16 << 16; return v.f;
}
__device__ __forceinline__ unsigned short f2bf(float f) {
  union { float f; unsigned int i; } v; v.f = f;
  unsigned int u = v.i;
  unsigned int r = (u + 0x7fffu + ((u >> 16) & 1u)) >> 16;  // RNE
  return (unsigned short)r;
}
__device__ __forceinline__ void gload16(const void* g, void* l) {
  __builtin_amdgcn_global_load_lds(
      (const __attribute__((address_space(1))) void*)g,
      (__attribute__((address_space(3))) void*)l, 16, 0, 0);
}

// ---------------- bucket-sort CSR build (coalesced writes by construction) ----

__global__ void zero_int_kernel(int* __restrict__ p, int n) {
  int i = blockIdx.x * blockDim.x + threadIdx.x;
  if (i < n) p[i] = 0;
}

// Phase A: global bucket counts via per-block LDS histogram
__global__ void bin_count_kernel(const int* __restrict__ dst, int* __restrict__ bucketCount) {
  __shared__ int hist[NBKT];
  int tid = threadIdx.x;
  for (int i = tid; i < NBKT; i += 256) hist[i] = 0;
  __syncthreads();
  const int4* d4 = (const int4*)(dst + blockIdx.x * EPB);
  for (int i = tid; i < EPB / 4; i += 256) {
    int4 v = d4[i];
    atomicAdd(&hist[v.x >> 9], 1); atomicAdd(&hist[v.y >> 9], 1);
    atomicAdd(&hist[v.z >> 9], 1); atomicAdd(&hist[v.w >> 9], 1);
  }
  __syncthreads();
  for (int i = tid; i < NBKT; i += 256)
    if (hist[i]) atomicAdd(&bucketCount[i], hist[i]);
}

// Phase A2: one-wave exclusive scan of bucket counts -> base + cursor
__global__ void scan_buckets_kernel(const int* __restrict__ cnt, int* __restrict__ base,
                                    int* __restrict__ cursor, int* __restrict__ rowptr) {
  int lane = threadIdx.x;
  int carry = 0;
  for (int b0 = 0; b0 < NBKT; b0 += 64) {
    int i = b0 + lane;
    int v = (i < NBKT) ? cnt[i] : 0;
    int s = v;
#pragma unroll
    for (int o = 1; o < 64; o <<= 1) { int t = __shfl_up(s, o); if (lane >= o) s += t; }
    int tot = __shfl(s, 63);
    if (i < NBKT) { base[i] = carry + s - v; cursor[i] = carry + s - v; }
    carry += tot;
  }
  if (lane == 0) { base[NBKT] = N_EDGES; rowptr[N_NODES] = N_EDGES; }
}

// Phase B: per-block private-range reservation + sequential packed writes.
// pack = (dst_local<<17) | src   (src < 2^17, dst_local < 512)
__global__ void bin_scatter_kernel(const int* __restrict__ src, const int* __restrict__ dst,
                                   int* __restrict__ cursor, unsigned int* __restrict__ pairs) {
  __shared__ int hist[NBKT];
  __shared__ int curs[NBKT];
  int tid = threadIdx.x;
  for (int i = tid; i < NBKT; i += 256) hist[i] = 0;
  __syncthreads();
  const int4* d4 = (const int4*)(dst + blockIdx.x * EPB);
  const int4* s4 = (const int4*)(src + blockIdx.x * EPB);
  for (int i = tid; i < EPB / 4; i += 256) {
    int4 v = d4[i];
    atomicAdd(&hist[v.x >> 9], 1); atomicAdd(&hist[v.y >> 9], 1);
    atomicAdd(&hist[v.z >> 9], 1); atomicAdd(&hist[v.w >> 9], 1);
  }
  __syncthreads();
  for (int i = tid; i < NBKT; i += 256) curs[i] = atomicAdd(&cursor[i], hist[i]);
  __syncthreads();
  for (int i = tid; i < EPB / 4; i += 256) {
    int4 v = d4[i];
    int4 u = s4[i];
    int p;
    p = atomicAdd(&curs[v.x >> 9], 1); pairs[p] = ((unsigned)(v.x & 511) << 17) | (unsigned)u.x;
    p = atomicAdd(&curs[v.y >> 9], 1); pairs[p] = ((unsigned)(v.y & 511) << 17) | (unsigned)u.y;
    p = atomicAdd(&curs[v.z >> 9], 1); pairs[p] = ((unsigned)(v.z & 511) << 17) | (unsigned)u.z;
    p = atomicAdd(&curs[v.w >> 9], 1); pairs[p] = ((unsigned)(v.w & 511) << 17) | (unsigned)u.w;
  }
}

// Phase C: per-bucket LDS counting sort -> exact rowptr + ebuf (block-local 32KB writes)
__launch_bounds__(256)
__global__ void bucket_csr_kernel(const unsigned int* __restrict__ pairs,
                                  const int* __restrict__ base,
                                  int* __restrict__ rowptr, int* __restrict__ ebuf) {
  __shared__ int hist[512];
  __shared__ int curs[512];
  __shared__ int wsum[4];
  int b = blockIdx.x;
  int tid = threadIdx.x;
  int n0 = b << 9;
  int nn = N_NODES - n0; if (nn > 512) nn = 512;
  int lo = base[b], hi = base[b + 1];
  hist[tid] = 0; hist[tid + 256] = 0;
  __syncthreads();
  for (int i = lo + tid; i < hi; i += 256)
    atomicAdd(&hist[pairs[i] >> 17], 1);
  __syncthreads();
  // block-exclusive scan over 512 counters (thread t owns 2t, 2t+1)
  int h0 = hist[2 * tid], h1 = hist[2 * tid + 1];
  int ps = h0 + h1;
  int lane = tid & 63, wave = tid >> 6;
  int s = ps;
#pragma unroll
  for (int o = 1; o < 64; o <<= 1) { int t = __shfl_up(s, o); if (lane >= o) s += t; }
  if (lane == 63) wsum[wave] = s;
  __syncthreads();
  if (tid == 0) { int c = 0; for (int k = 0; k < 4; ++k) { int t = wsum[k]; wsum[k] = c; c += t; } }
  __syncthreads();
  int base0 = lo + (s - ps) + wsum[wave];
  curs[2 * tid] = base0;
  curs[2 * tid + 1] = base0 + h0;
  if (2 * tid < nn)     rowptr[n0 + 2 * tid] = base0;
  if (2 * tid + 1 < nn) rowptr[n0 + 2 * tid + 1] = base0 + h0;
  __syncthreads();
  for (int i = lo + tid; i < hi; i += 256) {
    unsigned int p = pairs[i];
    int pos = atomicAdd(&curs[p >> 17], 1);
    ebuf[pos] = (int)(p & 0x1FFFF);
  }
}

// ---------------- conversions ----------------
// axb layout: [N][256] bf16, cols 0..127 = mean1 (filled by agg), 128..255 = x
__global__ void cvt_x_kernel(const float* __restrict__ x, ushort_t* __restrict__ axb) {
  int idx = blockIdx.x * blockDim.x + threadIdx.x;  // one thread per 4 elems
  if (idx >= N_NODES * 32) return;
  int n = idx >> 5, j = (idx & 31) << 2;
  float4 v = *(const float4*)(x + (size_t)n * 128 + j);
  ushort4 o;
  o.x = f2bf(v.x); o.y = f2bf(v.y); o.z = f2bf(v.z); o.w = f2bf(v.w);
  *(ushort4*)(axb + (size_t)n * 256 + 128 + j) = o;
}

// W1bt [256 cols][256 k] = transpose of [W1l;W1r]; W2bt [128 cols][256 k] = transpose of [W2l|W2r]
__global__ void cvt_w_kernel(const float* __restrict__ W1l, const float* __restrict__ W1r,
                             const float* __restrict__ W2l, const float* __restrict__ W2r,
                             ushort_t* __restrict__ W1bt, ushort_t* __restrict__ W2bt) {
  int idx = blockIdx.x * blockDim.x + threadIdx.x;
  if (idx < 65536) {
    int n = idx >> 8, k = idx & 255;
    float v = (k < 128) ? W1l[(size_t)k * 256 + n] : W1r[(size_t)(k - 128) * 256 + n];
    W1bt[idx] = f2bf(v);
  } else if (idx < 65536 + 32768) {
    int t = idx - 65536;
    int n = t >> 8, k = t & 255;
    float v = (n < 64) ? W2l[(size_t)k * 64 + n] : W2r[(size_t)k * 64 + (n - 64)];
    W2bt[t] = f2bf(v);
  }
}

// ---------------- layer-1 mean aggregation ----------------
// wave per node, 2 edges/iter (half h services edge e+h); lane j=l&31 loads 8B.
__global__ void agg_mean1_kernel(const int* __restrict__ rowptr, const int* __restrict__ ebuf,
                                 ushort_t* __restrict__ axb) {
  int node = blockIdx.x * 4 + (threadIdx.x >> 6);
  int l = threadIdx.x & 63;
  int half = l >> 5, j = l & 31;
  int beg = rowptr[node], end = rowptr[node + 1];
  const ushort_t* xb = axb + 128;  // x part of rows
  float a0 = 0.f, a1 = 0.f, a2 = 0.f, a3 = 0.f;
  int e = beg;
  for (; e + 8 <= end; e += 8) {
#pragma unroll
    for (int k = 0; k < 4; ++k) {
      int s = ebuf[e + 2 * k + half];
      uint2 v = *(const uint2*)(xb + (size_t)s * 256 + 4 * j);
      a0 += bf2f(v.x & 0xffff); a1 += bf2f(v.x >> 16);
      a2 += bf2f(v.y & 0xffff); a3 += bf2f(v.y >> 16);
    }
  }
  for (; e + 2 <= end; e += 2) {
    int s = ebuf[e + half];
    uint2 v = *(const uint2*)(xb + (size_t)s * 256 + 4 * j);
    a0 += bf2f(v.x & 0xffff); a1 += bf2f(v.x >> 16);
    a2 += bf2f(v.y & 0xffff); a3 += bf2f(v.y >> 16);
  }
  if (e < end && half == 0) {  // odd tail: half 0 only
    int s = ebuf[e];
    uint2 v = *(const uint2*)(xb + (size_t)s * 256 + 4 * j);
    a0 += bf2f(v.x & 0xffff); a1 += bf2f(v.x >> 16);
    a2 += bf2f(v.y & 0xffff); a3 += bf2f(v.y >> 16);
  }
  a0 += __shfl_xor(a0, 32); a1 += __shfl_xor(a1, 32);
  a2 += __shfl_xor(a2, 32); a3 += __shfl_xor(a3, 32);
  if (half == 0) {
    float inv = (end > beg) ? 1.0f / (float)(end - beg) : 0.0f;
    uint2 o;
    o.x = (unsigned int)f2bf(a0 * inv) | ((unsigned int)f2bf(a1 * inv) << 16);
    o.y = (unsigned int)f2bf(a2 * inv) | ((unsigned int)f2bf(a3 * inv) << 16);
    *(uint2*)(axb + (size_t)node * 256 + 4 * j) = o;
  }
}

// ---------------- bf16 MFMA GEMM (K=256 fixed) ----------------
template<bool RELU>
__launch_bounds__(256)
__global__ void gemm_bf16_kernel(const ushort_t* __restrict__ A, const ushort_t* __restrict__ Bt,
                                 const float* __restrict__ bias, ushort_t* __restrict__ C,
                                 int M, int NC) {
  __shared__ ushort_t ldsA[128 * 64];  // 16 KB
  __shared__ ushort_t ldsB[128 * 64];  // 16 KB
  const int tid = threadIdx.x;
  const int lane = tid & 63;
  const int wm = (tid >> 6) & 1, wn = tid >> 7;
  const int rowBase = blockIdx.x * 128;
  const int colBase = blockIdx.y * 128;
  f32x4 acc[4][4];
#pragma unroll
  for (int i = 0; i < 4; ++i)
#pragma unroll
    for (int j = 0; j < 4; ++j) acc[i][j] = (f32x4){0.f, 0.f, 0.f, 0.f};

  for (int k0 = 0; k0 < GK; k0 += 64) {
#pragma unroll
    for (int i = 0; i < 4; ++i) {
      int s = tid + i * 256;          // 16B slot id; lane-contiguous per wave
      int row = s >> 3, off16 = s & 7;
      int k16 = off16 ^ (row & 7);    // inverse-swizzled global source
      int ga = rowBase + row; if (ga > M - 1) ga = M - 1;
      gload16(A + (size_t)ga * GK + k0 + k16 * 8, &ldsA[s * 8]);
      gload16(Bt + (size_t)(colBase + row) * GK + k0 + k16 * 8, &ldsB[s * 8]);
    }
    __syncthreads();
#pragma unroll
    for (int kc = 0; kc < 2; ++kc) {
      bf16x8 af[4], bfr[4];
#pragma unroll
      for (int i = 0; i < 4; ++i) {
        int rA = wm * 64 + i * 16 + (lane & 15);
        int oA = (kc * 4 + (lane >> 4)) ^ (rA & 7);   // swizzled read
        af[i] = *(const bf16x8*)&ldsA[rA * 64 + oA * 8];
        int rB = wn * 64 + i * 16 + (lane & 15);
        int oB = (kc * 4 + (lane >> 4)) ^ (rB & 7);
        bfr[i] = *(const bf16x8*)&ldsB[rB * 64 + oB * 8];
      }
#pragma unroll
      for (int mi = 0; mi < 4; ++mi)
#pragma unroll
        for (int ni = 0; ni < 4; ++ni)
          acc[mi][ni] = __builtin_amdgcn_mfma_f32_16x16x32_bf16(af[mi], bfr[ni], acc[mi][ni], 0, 0, 0);
    }
    __syncthreads();
  }
#pragma unroll
  for (int mi = 0; mi < 4; ++mi) {
#pragma unroll
    for (int r = 0; r < 4; ++r) {
      int grow = rowBase + wm * 64 + mi * 16 + (lane >> 4) * 4 + r;
      if (grow >= M) continue;
#pragma unroll
      for (int ni = 0; ni < 4; ++ni) {
        int gcol = colBase + wn * 64 + ni * 16 + (lane & 15);
        float v = acc[mi][ni][r];
        if (RELU) v = fmaxf(v + bias[gcol], 0.f);
        C[(size_t)grow * NC + gcol] = f2bf(v);
      }
    }
  }
}

// ---------------- final: aggregate P, + b2 + Q, log_softmax ----------------
__global__ void final_kernel(const int* __restrict__ rowptr, const int* __restrict__ ebuf,
                             const ushort_t* __restrict__ pq, const float* __restrict__ b2,
                             float* __restrict__ out) {
  int node = blockIdx.x * 4 + (threadIdx.x >> 6);
  int l = threadIdx.x & 63;
  int half = l >> 5, j = l & 31;
  int beg = rowptr[node], end = rowptr[node + 1];
  float a0 = 0.f, a1 = 0.f;
  int e = beg;
  for (; e + 8 <= end; e += 8) {
#pragma unroll
    for (int k = 0; k < 4; ++k) {
      int s = ebuf[e + 2 * k + half];
      unsigned int v = *(const unsigned int*)(pq + (size_t)s * 128 + 2 * j);
      a0 += bf2f(v & 0xffff); a1 += bf2f(v >> 16);
    }
  }
  for (; e + 2 <= end; e += 2) {
    int s = ebuf[e + half];
    unsigned int v = *(const unsigned int*)(pq + (size_t)s * 128 + 2 * j);
    a0 += bf2f(v & 0xffff); a1 += bf2f(v >> 16);
  }
  if (e < end && half == 0) {
    int s = ebuf[e];
    unsigned int v = *(const unsigned int*)(pq + (size_t)s * 128 + 2 * j);
    a0 += bf2f(v & 0xffff); a1 += bf2f(v >> 16);
  }
  a0 += __shfl_xor(a0, 32);
  a1 += __shfl_xor(a1, 32);
  float inv = (end > beg) ? 1.0f / (float)(end - beg) : 0.0f;
  unsigned int q = *(const unsigned int*)(pq + (size_t)node * 128 + 64 + 2 * j);
  float v0 = a0 * inv + b2[2 * j] + bf2f(q & 0xffff);
  float v1 = a1 * inv + b2[2 * j + 1] + bf2f(q >> 16);
  float m = fmaxf(v0, v1);
#pragma unroll
  for (int o = 16; o > 0; o >>= 1) m = fmaxf(m, __shfl_xor(m, o));
  float ssum = expf(v0 - m) + expf(v1 - m);
#pragma unroll
  for (int o = 16; o > 0; o >>= 1) ssum += __shfl_xor(ssum, o);
  if (half == 0) {
    float ls = logf(ssum);
    float2 o2 = {v0 - m - ls, v1 - m - ls};
    *(float2*)(out + (size_t)node * 64 + 2 * j) = o2;
  }
}

// ---------------- launch ----------------

extern "C" void kernel_launch(void* const* d_in, const int* in_sizes, int n_in,
                              void* d_out, int out_size, void* d_ws, size_t ws_size,
                              hipStream_t stream) {
  const float* x   = (const float*)d_in[0];
  const int*   ei  = (const int*)d_in[1];
  const float* W1l = (const float*)d_in[2];
  const float* b1  = (const float*)d_in[3];
  const float* W1r = (const float*)d_in[4];
  const float* W2l = (const float*)d_in[5];
  const float* b2  = (const float*)d_in[6];
  const float* W2r = (const float*)d_in[7];
  float* out = (float*)d_out;
  const int* src = ei;
  const int* dst = ei + N_EDGES;

  char* w = (char*)d_ws;
  int*      bucketCount = (int*)(w);                          // 784 B
  int*      bucketBase  = (int*)(w + 1024);                   // 788 B
  int*      bucketCur   = (int*)(w + 2048);                   // 784 B
  int*      rowptr      = (int*)(w + 4096);                   // 400 KB
  int*      ebuf        = (int*)(w + 512ull * 1024);          // 6.4 MB (ends 6.9MB)
  ushort_t* W1bt        = (ushort_t*)(w + 7ull * 1024 * 1024);       // 128 KB
  ushort_t* W2bt        = (ushort_t*)(w + 7ull * 1024 * 1024 + 256 * 1024);  // 64 KB
  ushort_t* axb         = (ushort_t*)(w + 8ull * 1024 * 1024);       // 51.2 MB (ends 59.2)
  ushort_t* h           = (ushort_t*)(w + 60ull * 1024 * 1024);      // 51.2 MB (ends 111.2)
  unsigned int* pairs   = (unsigned int*)(w + 60ull * 1024 * 1024);  // 6.4 MB, aliases h (dead before gemm1)
  ushort_t* pq          = (ushort_t*)(w + 112ull * 1024 * 1024);     // 25.6 MB (ends 137.6)

  zero_int_kernel<<<1, 256, 0, stream>>>(bucketCount, NBKT);
  bin_count_kernel<<<NBIN, 256, 0, stream>>>(dst, bucketCount);
  scan_buckets_kernel<<<1, 64, 0, stream>>>(bucketCount, bucketBase, bucketCur, rowptr);
  bin_scatter_kernel<<<NBIN, 256, 0, stream>>>(src, dst, bucketCur, pairs);
  bucket_csr_kernel<<<NBKT, 256, 0, stream>>>(pairs, bucketBase, rowptr, ebuf);

  cvt_x_kernel<<<(N_NODES * 32 + 255) / 256, 256, 0, stream>>>(x, axb);
  cvt_w_kernel<<<384, 256, 0, stream>>>(W1l, W1r, W2l, W2r, W1bt, W2bt);

  agg_mean1_kernel<<<N_NODES / 4, 256, 0, stream>>>(rowptr, ebuf, axb);

  gemm_bf16_kernel<true><<<dim3((N_NODES + 127) / 128, 2), 256, 0, stream>>>(
      axb, W1bt, b1, h, N_NODES, 256);
  gemm_bf16_kernel<false><<<dim3((N_NODES + 127) / 128, 1), 256, 0, stream>>>(
      h, W2bt, nullptr, pq, N_NODES, 128);

  final_kernel<<<N_NODES / 4, 256, 0, stream>>>(rowptr, ebuf, pq, b2, out);
}

// Round 7
// 227.443 us; speedup vs baseline: 5.5041x; 1.0523x over previous
//
#include <hip/hip_runtime.h>

#define N_NODES 100000
#define N_EDGES 1600000
#define GK 256      // K dim of both GEMMs
#define NBKT 196    // buckets of 512 nodes: (100000+511)>>9
#define NBIN 128    // blocks for bin count/scatter
#define EPB (N_EDGES / NBIN)  // 12500 edges per bin block

typedef __attribute__((ext_vector_type(8))) short bf16x8;
typedef __attribute__((ext_vector_type(4))) float f32x4;
typedef __attribute__((ext_vector_type(2))) float f32x2;
typedef unsigned short ushort_t;

__device__ __forceinline__ float bf2f(unsigned int bits16) {
  union { unsigned int i; float f; } v; v.i = bits16 << 16; return v.f;
}
__device__ __forceinline__ unsigned short f2bf(float f) {
  union { float f; unsigned int i; } v; v.f = f;
  unsigned int u = v.i;
  unsigned int r = (u + 0x7fffu + ((u >> 16) & 1u)) >> 16;  // RNE
  return (unsigned short)r;
}
__device__ __forceinline__ void gload16(const void* g, void* l) {
  __builtin_amdgcn_global_load_lds(
      (const __attribute__((address_space(1))) void*)g,
      (__attribute__((address_space(3))) void*)l, 16, 0, 0);
}

// ---------------- bucket-sort CSR build (coalesced writes by construction) ----

__global__ void zero_int_kernel(int* __restrict__ p, int n) {
  int i = blockIdx.x * blockDim.x + threadIdx.x;
  if (i < n) p[i] = 0;
}

__global__ void bin_count_kernel(const int* __restrict__ dst, int* __restrict__ bucketCount) {
  __shared__ int hist[NBKT];
  int tid = threadIdx.x;
  for (int i = tid; i < NBKT; i += 256) hist[i] = 0;
  __syncthreads();
  const int4* d4 = (const int4*)(dst + blockIdx.x * EPB);
  for (int i = tid; i < EPB / 4; i += 256) {
    int4 v = d4[i];
    atomicAdd(&hist[v.x >> 9], 1); atomicAdd(&hist[v.y >> 9], 1);
    atomicAdd(&hist[v.z >> 9], 1); atomicAdd(&hist[v.w >> 9], 1);
  }
  __syncthreads();
  for (int i = tid; i < NBKT; i += 256)
    if (hist[i]) atomicAdd(&bucketCount[i], hist[i]);
}

__global__ void scan_buckets_kernel(const int* __restrict__ cnt, int* __restrict__ base,
                                    int* __restrict__ cursor, int* __restrict__ rowptr) {
  int lane = threadIdx.x;
  int carry = 0;
  for (int b0 = 0; b0 < NBKT; b0 += 64) {
    int i = b0 + lane;
    int v = (i < NBKT) ? cnt[i] : 0;
    int s = v;
#pragma unroll
    for (int o = 1; o < 64; o <<= 1) { int t = __shfl_up(s, o); if (lane >= o) s += t; }
    int tot = __shfl(s, 63);
    if (i < NBKT) { base[i] = carry + s - v; cursor[i] = carry + s - v; }
    carry += tot;
  }
  if (lane == 0) { base[NBKT] = N_EDGES; rowptr[N_NODES] = N_EDGES; }
}

// pack = (dst_local<<17) | src
__global__ void bin_scatter_kernel(const int* __restrict__ src, const int* __restrict__ dst,
                                   int* __restrict__ cursor, unsigned int* __restrict__ pairs) {
  __shared__ int hist[NBKT];
  __shared__ int curs[NBKT];
  int tid = threadIdx.x;
  for (int i = tid; i < NBKT; i += 256) hist[i] = 0;
  __syncthreads();
  const int4* d4 = (const int4*)(dst + blockIdx.x * EPB);
  const int4* s4 = (const int4*)(src + blockIdx.x * EPB);
  for (int i = tid; i < EPB / 4; i += 256) {
    int4 v = d4[i];
    atomicAdd(&hist[v.x >> 9], 1); atomicAdd(&hist[v.y >> 9], 1);
    atomicAdd(&hist[v.z >> 9], 1); atomicAdd(&hist[v.w >> 9], 1);
  }
  __syncthreads();
  for (int i = tid; i < NBKT; i += 256) curs[i] = atomicAdd(&cursor[i], hist[i]);
  __syncthreads();
  for (int i = tid; i < EPB / 4; i += 256) {
    int4 v = d4[i];
    int4 u = s4[i];
    int p;
    p = atomicAdd(&curs[v.x >> 9], 1); pairs[p] = ((unsigned)(v.x & 511) << 17) | (unsigned)u.x;
    p = atomicAdd(&curs[v.y >> 9], 1); pairs[p] = ((unsigned)(v.y & 511) << 17) | (unsigned)u.y;
    p = atomicAdd(&curs[v.z >> 9], 1); pairs[p] = ((unsigned)(v.z & 511) << 17) | (unsigned)u.z;
    p = atomicAdd(&curs[v.w >> 9], 1); pairs[p] = ((unsigned)(v.w & 511) << 17) | (unsigned)u.w;
  }
}

__launch_bounds__(256)
__global__ void bucket_csr_kernel(const unsigned int* __restrict__ pairs,
                                  const int* __restrict__ base,
                                  int* __restrict__ rowptr, int* __restrict__ ebuf) {
  __shared__ int hist[512];
  __shared__ int curs[512];
  __shared__ int wsum[4];
  int b = blockIdx.x;
  int tid = threadIdx.x;
  int n0 = b << 9;
  int nn = N_NODES - n0; if (nn > 512) nn = 512;
  int lo = base[b], hi = base[b + 1];
  hist[tid] = 0; hist[tid + 256] = 0;
  __syncthreads();
  for (int i = lo + tid; i < hi; i += 256)
    atomicAdd(&hist[pairs[i] >> 17], 1);
  __syncthreads();
  int h0 = hist[2 * tid], h1 = hist[2 * tid + 1];
  int ps = h0 + h1;
  int lane = tid & 63, wave = tid >> 6;
  int s = ps;
#pragma unroll
  for (int o = 1; o < 64; o <<= 1) { int t = __shfl_up(s, o); if (lane >= o) s += t; }
  if (lane == 63) wsum[wave] = s;
  __syncthreads();
  if (tid == 0) { int c = 0; for (int k = 0; k < 4; ++k) { int t = wsum[k]; wsum[k] = c; c += t; } }
  __syncthreads();
  int base0 = lo + (s - ps) + wsum[wave];
  curs[2 * tid] = base0;
  curs[2 * tid + 1] = base0 + h0;
  if (2 * tid < nn)     rowptr[n0 + 2 * tid] = base0;
  if (2 * tid + 1 < nn) rowptr[n0 + 2 * tid + 1] = base0 + h0;
  __syncthreads();
  for (int i = lo + tid; i < hi; i += 256) {
    unsigned int p = pairs[i];
    int pos = atomicAdd(&curs[p >> 17], 1);
    ebuf[pos] = (int)(p & 0x1FFFF);
  }
}

// ---------------- conversions ----------------
// axb: [N][256] bf16 (cols 0..127 mean1, 128..255 x);  xq: [N][128] fp8 e4m3 copy of x
__global__ void cvt_x_kernel(const float* __restrict__ x, ushort_t* __restrict__ axb,
                             unsigned int* __restrict__ xq) {
  int idx = blockIdx.x * blockDim.x + threadIdx.x;  // one thread per 4 elems
  if (idx >= N_NODES * 32) return;
  int n = idx >> 5, j = (idx & 31) << 2;
  float4 v = *(const float4*)(x + (size_t)n * 128 + j);
  ushort4 o;
  o.x = f2bf(v.x); o.y = f2bf(v.y); o.z = f2bf(v.z); o.w = f2bf(v.w);
  *(ushort4*)(axb + (size_t)n * 256 + 128 + j) = o;
  unsigned int q = __builtin_amdgcn_cvt_pk_fp8_f32(v.x, v.y, 0, false);
  q = __builtin_amdgcn_cvt_pk_fp8_f32(v.z, v.w, q, true);
  xq[(size_t)n * 32 + (j >> 2)] = q;
}

__global__ void cvt_w_kernel(const float* __restrict__ W1l, const float* __restrict__ W1r,
                             const float* __restrict__ W2l, const float* __restrict__ W2r,
                             ushort_t* __restrict__ W1bt, ushort_t* __restrict__ W2bt) {
  int idx = blockIdx.x * blockDim.x + threadIdx.x;
  if (idx < 65536) {
    int n = idx >> 8, k = idx & 255;
    float v = (k < 128) ? W1l[(size_t)k * 256 + n] : W1r[(size_t)(k - 128) * 256 + n];
    W1bt[idx] = f2bf(v);
  } else if (idx < 65536 + 32768) {
    int t = idx - 65536;
    int n = t >> 8, k = t & 255;
    float v = (n < 64) ? W2l[(size_t)k * 64 + n] : W2r[(size_t)k * 64 + (n - 64)];
    W2bt[t] = f2bf(v);
  }
}

// ---------------- layer-1 mean aggregation (fp8 gather, f32 acc, bf16 out) ----
// wave per node, 2 edges/iter (half h services edge e+h); lane j=l&31 loads 4B = 4 feats fp8
__global__ void agg_mean1_kernel(const int* __restrict__ rowptr, const int* __restrict__ ebuf,
                                 const unsigned int* __restrict__ xq, ushort_t* __restrict__ axb) {
  int node = blockIdx.x * 4 + (threadIdx.x >> 6);
  int l = threadIdx.x & 63;
  int half = l >> 5, j = l & 31;
  int beg = rowptr[node], end = rowptr[node + 1];
  float a0 = 0.f, a1 = 0.f, a2 = 0.f, a3 = 0.f;
  int e = beg;
  for (; e + 8 <= end; e += 8) {
#pragma unroll
    for (int k = 0; k < 4; ++k) {
      int s = ebuf[e + 2 * k + half];
      unsigned int u = xq[(size_t)s * 32 + j];
      f32x2 lo = __builtin_amdgcn_cvt_pk_f32_fp8(u, false);
      f32x2 hi = __builtin_amdgcn_cvt_pk_f32_fp8(u, true);
      a0 += lo[0]; a1 += lo[1]; a2 += hi[0]; a3 += hi[1];
    }
  }
  for (; e + 2 <= end; e += 2) {
    int s = ebuf[e + half];
    unsigned int u = xq[(size_t)s * 32 + j];
    f32x2 lo = __builtin_amdgcn_cvt_pk_f32_fp8(u, false);
    f32x2 hi = __builtin_amdgcn_cvt_pk_f32_fp8(u, true);
    a0 += lo[0]; a1 += lo[1]; a2 += hi[0]; a3 += hi[1];
  }
  if (e < end && half == 0) {
    int s = ebuf[e];
    unsigned int u = xq[(size_t)s * 32 + j];
    f32x2 lo = __builtin_amdgcn_cvt_pk_f32_fp8(u, false);
    f32x2 hi = __builtin_amdgcn_cvt_pk_f32_fp8(u, true);
    a0 += lo[0]; a1 += lo[1]; a2 += hi[0]; a3 += hi[1];
  }
  a0 += __shfl_xor(a0, 32); a1 += __shfl_xor(a1, 32);
  a2 += __shfl_xor(a2, 32); a3 += __shfl_xor(a3, 32);
  if (half == 0) {
    float inv = (end > beg) ? 1.0f / (float)(end - beg) : 0.0f;
    uint2 o;
    o.x = (unsigned int)f2bf(a0 * inv) | ((unsigned int)f2bf(a1 * inv) << 16);
    o.y = (unsigned int)f2bf(a2 * inv) | ((unsigned int)f2bf(a3 * inv) << 16);
    *(uint2*)(axb + (size_t)node * 256 + 4 * j) = o;
  }
}

// ---------------- bf16 MFMA GEMM (K=256 fixed) ----------------
// MODE 0: C = relu(A@Bt^T + bias) bf16, NC cols.  MODE 1 (layer2, NC=128):
//   cols 0..63 (wn==0) -> P8 fp8 [N][64];  cols 64..127 (wn==1) -> QB bf16 [N][64]
template<int MODE>
__launch_bounds__(256)
__global__ void gemm_bf16_kernel(const ushort_t* __restrict__ A, const ushort_t* __restrict__ Bt,
                                 const float* __restrict__ bias, ushort_t* __restrict__ C,
                                 unsigned char* __restrict__ P8, ushort_t* __restrict__ QB,
                                 int M, int NC) {
  __shared__ ushort_t ldsA[128 * 64];  // 16 KB
  __shared__ ushort_t ldsB[128 * 64];  // 16 KB
  const int tid = threadIdx.x;
  const int lane = tid & 63;
  const int wm = (tid >> 6) & 1, wn = tid >> 7;
  const int rowBase = blockIdx.x * 128;
  const int colBase = blockIdx.y * 128;
  f32x4 acc[4][4];
#pragma unroll
  for (int i = 0; i < 4; ++i)
#pragma unroll
    for (int j = 0; j < 4; ++j) acc[i][j] = (f32x4){0.f, 0.f, 0.f, 0.f};

  for (int k0 = 0; k0 < GK; k0 += 64) {
#pragma unroll
    for (int i = 0; i < 4; ++i) {
      int s = tid + i * 256;          // 16B slot id
      int row = s >> 3, off16 = s & 7;
      int k16 = off16 ^ (row & 7);    // inverse-swizzled global source
      int ga = rowBase + row; if (ga > M - 1) ga = M - 1;
      gload16(A + (size_t)ga * GK + k0 + k16 * 8, &ldsA[s * 8]);
      gload16(Bt + (size_t)(colBase + row) * GK + k0 + k16 * 8, &ldsB[s * 8]);
    }
    __syncthreads();
#pragma unroll
    for (int kc = 0; kc < 2; ++kc) {
      bf16x8 af[4], bfr[4];
#pragma unroll
      for (int i = 0; i < 4; ++i) {
        int rA = wm * 64 + i * 16 + (lane & 15);
        int oA = (kc * 4 + (lane >> 4)) ^ (rA & 7);   // swizzled read
        af[i] = *(const bf16x8*)&ldsA[rA * 64 + oA * 8];
        int rB = wn * 64 + i * 16 + (lane & 15);
        int oB = (kc * 4 + (lane >> 4)) ^ (rB & 7);
        bfr[i] = *(const bf16x8*)&ldsB[rB * 64 + oB * 8];
      }
#pragma unroll
      for (int mi = 0; mi < 4; ++mi)
#pragma unroll
        for (int ni = 0; ni < 4; ++ni)
          acc[mi][ni] = __builtin_amdgcn_mfma_f32_16x16x32_bf16(af[mi], bfr[ni], acc[mi][ni], 0, 0, 0);
    }
    __syncthreads();
  }
#pragma unroll
  for (int mi = 0; mi < 4; ++mi) {
#pragma unroll
    for (int r = 0; r < 4; ++r) {
      int grow = rowBase + wm * 64 + mi * 16 + (lane >> 4) * 4 + r;
      if (grow >= M) continue;
#pragma unroll
      for (int ni = 0; ni < 4; ++ni) {
        float v = acc[mi][ni][r];
        if (MODE == 0) {
          int gcol = colBase + wn * 64 + ni * 16 + (lane & 15);
          C[(size_t)grow * NC + gcol] = f2bf(fmaxf(v + bias[gcol], 0.f));
        } else {
          int c = ni * 16 + (lane & 15);  // 0..63 within half
          if (wn == 0) {
            unsigned int u = __builtin_amdgcn_cvt_pk_fp8_f32(v, v, 0, false);
            P8[(size_t)grow * 64 + c] = (unsigned char)(u & 0xff);
          } else {
            QB[(size_t)grow * 64 + c] = f2bf(v);
          }
        }
      }
    }
  }
}

// ---------------- final: aggregate P (fp8), + b2 + Q, log_softmax ----------------
// wave per node, 4 edges/iter (quarter q services edge e+q); lane j=l&15 loads 4B = 4 classes
__global__ void final_kernel(const int* __restrict__ rowptr, const int* __restrict__ ebuf,
                             const unsigned int* __restrict__ p8, const ushort_t* __restrict__ qb,
                             const float* __restrict__ b2, float* __restrict__ out) {
  int node = blockIdx.x * 4 + (threadIdx.x >> 6);
  int l = threadIdx.x & 63;
  int q4 = l >> 4, j = l & 15;
  int beg = rowptr[node], end = rowptr[node + 1];
  float a0 = 0.f, a1 = 0.f, a2 = 0.f, a3 = 0.f;
  int e = beg;
  for (; e + 16 <= end; e += 16) {
#pragma unroll
    for (int k = 0; k < 4; ++k) {
      int s = ebuf[e + 4 * k + q4];
      unsigned int u = p8[(size_t)s * 16 + j];
      f32x2 lo = __builtin_amdgcn_cvt_pk_f32_fp8(u, false);
      f32x2 hi = __builtin_amdgcn_cvt_pk_f32_fp8(u, true);
      a0 += lo[0]; a1 += lo[1]; a2 += hi[0]; a3 += hi[1];
    }
  }
  for (; e + 4 <= end; e += 4) {
    int s = ebuf[e + q4];
    unsigned int u = p8[(size_t)s * 16 + j];
    f32x2 lo = __builtin_amdgcn_cvt_pk_f32_fp8(u, false);
    f32x2 hi = __builtin_amdgcn_cvt_pk_f32_fp8(u, true);
    a0 += lo[0]; a1 += lo[1]; a2 += hi[0]; a3 += hi[1];
  }
  if (q4 < end - e) {
    int s = ebuf[e + q4];
    unsigned int u = p8[(size_t)s * 16 + j];
    f32x2 lo = __builtin_amdgcn_cvt_pk_f32_fp8(u, false);
    f32x2 hi = __builtin_amdgcn_cvt_pk_f32_fp8(u, true);
    a0 += lo[0]; a1 += lo[1]; a2 += hi[0]; a3 += hi[1];
  }
  // combine quarters
  a0 += __shfl_xor(a0, 32); a1 += __shfl_xor(a1, 32);
  a2 += __shfl_xor(a2, 32); a3 += __shfl_xor(a3, 32);
  a0 += __shfl_xor(a0, 16); a1 += __shfl_xor(a1, 16);
  a2 += __shfl_xor(a2, 16); a3 += __shfl_xor(a3, 16);
  float inv = (end > beg) ? 1.0f / (float)(end - beg) : 0.0f;
  uint2 qv = *(const uint2*)(qb + (size_t)node * 64 + 4 * j);
  float4 bv = *(const float4*)(b2 + 4 * j);
  float v0 = a0 * inv + bv.x + bf2f(qv.x & 0xffff);
  float v1 = a1 * inv + bv.y + bf2f(qv.x >> 16);
  float v2 = a2 * inv + bv.z + bf2f(qv.y & 0xffff);
  float v3 = a3 * inv + bv.w + bf2f(qv.y >> 16);
  // log_softmax over 64 classes held 4-per-lane across 16 lanes (quarters identical)
  float m = fmaxf(fmaxf(v0, v1), fmaxf(v2, v3));
#pragma unroll
  for (int o = 8; o > 0; o >>= 1) m = fmaxf(m, __shfl_xor(m, o));
  float ssum = expf(v0 - m) + expf(v1 - m) + expf(v2 - m) + expf(v3 - m);
#pragma unroll
  for (int o = 8; o > 0; o >>= 1) ssum += __shfl_xor(ssum, o);
  if (q4 == 0) {
    float ls = logf(ssum);
    float4 o4 = {v0 - m - ls, v1 - m - ls, v2 - m - ls, v3 - m - ls};
    *(float4*)(out + (size_t)node * 64 + 4 * j) = o4;
  }
}

// ---------------- launch ----------------

extern "C" void kernel_launch(void* const* d_in, const int* in_sizes, int n_in,
                              void* d_out, int out_size, void* d_ws, size_t ws_size,
                              hipStream_t stream) {
  const float* x   = (const float*)d_in[0];
  const int*   ei  = (const int*)d_in[1];
  const float* W1l = (const float*)d_in[2];
  const float* b1  = (const float*)d_in[3];
  const float* W1r = (const float*)d_in[4];
  const float* W2l = (const float*)d_in[5];
  const float* b2  = (const float*)d_in[6];
  const float* W2r = (const float*)d_in[7];
  float* out = (float*)d_out;
  const int* src = ei;
  const int* dst = ei + N_EDGES;

  char* w = (char*)d_ws;
  int*      bucketCount = (int*)(w);                          // 784 B
  int*      bucketBase  = (int*)(w + 1024);
  int*      bucketCur   = (int*)(w + 2048);
  int*      rowptr      = (int*)(w + 4096);                   // 400 KB
  int*      ebuf        = (int*)(w + 512ull * 1024);          // 6.4 MB
  ushort_t* W1bt        = (ushort_t*)(w + 7ull * 1024 * 1024);       // 128 KB
  ushort_t* W2bt        = (ushort_t*)(w + 7ull * 1024 * 1024 + 256 * 1024);  // 64 KB
  ushort_t* axb         = (ushort_t*)(w + 8ull * 1024 * 1024);       // 51.2 MB (ends 59.2)
  ushort_t* h           = (ushort_t*)(w + 60ull * 1024 * 1024);      // 51.2 MB (ends 111.2)
  unsigned int* pairs   = (unsigned int*)(w + 60ull * 1024 * 1024);  // 6.4 MB, aliases h
  unsigned int* xq      = (unsigned int*)(w + 112ull * 1024 * 1024); // 12.8 MB fp8 x (ends 124.8)
  unsigned int* p8      = (unsigned int*)(w + 125ull * 1024 * 1024); // 6.4 MB fp8 P (ends 131.4)
  ushort_t*     qb      = (ushort_t*)(w + 132ull * 1024 * 1024);     // 12.8 MB bf16 Q (ends 144.8)

  zero_int_kernel<<<1, 256, 0, stream>>>(bucketCount, NBKT);
  bin_count_kernel<<<NBIN, 256, 0, stream>>>(dst, bucketCount);
  scan_buckets_kernel<<<1, 64, 0, stream>>>(bucketCount, bucketBase, bucketCur, rowptr);
  bin_scatter_kernel<<<NBIN, 256, 0, stream>>>(src, dst, bucketCur, pairs);
  bucket_csr_kernel<<<NBKT, 256, 0, stream>>>(pairs, bucketBase, rowptr, ebuf);

  cvt_x_kernel<<<(N_NODES * 32 + 255) / 256, 256, 0, stream>>>(x, axb, xq);
  cvt_w_kernel<<<384, 256, 0, stream>>>(W1l, W1r, W2l, W2r, W1bt, W2bt);

  agg_mean1_kernel<<<N_NODES / 4, 256, 0, stream>>>(rowptr, ebuf, xq, axb);

  gemm_bf16_kernel<0><<<dim3((N_NODES + 127) / 128, 2), 256, 0, stream>>>(
      axb, W1bt, b1, h, nullptr, nullptr, N_NODES, 256);
  gemm_bf16_kernel<1><<<dim3((N_NODES + 127) / 128, 1), 256, 0, stream>>>(
      h, W2bt, nullptr, nullptr, (unsigned char*)p8, qb, N_NODES, 128);

  final_kernel<<<N_NODES / 4, 256, 0, stream>>>(rowptr, ebuf, p8, qb, b2, out);
}

// Round 8
// 225.993 us; speedup vs baseline: 5.5394x; 1.0064x over previous
//
#include <hip/hip_runtime.h>

#define N_NODES 100000
#define N_EDGES 1600000
#define GK 256      // K dim of both GEMMs
#define NBKT 196    // buckets of 512 nodes: (100000+511)>>9
#define NBIN 128    // blocks for bin count/scatter
#define EPB (N_EDGES / NBIN)  // 12500 edges per bin block

typedef __attribute__((ext_vector_type(8))) short bf16x8;
typedef __attribute__((ext_vector_type(4))) float f32x4;
typedef __attribute__((ext_vector_type(2))) float f32x2;
typedef unsigned short ushort_t;

__device__ __forceinline__ float bf2f(unsigned int bits16) {
  union { unsigned int i; float f; } v; v.i = bits16 << 16; return v.f;
}
__device__ __forceinline__ unsigned short f2bf(float f) {
  union { float f; unsigned int i; } v; v.f = f;
  unsigned int u = v.i;
  unsigned int r = (u + 0x7fffu + ((u >> 16) & 1u)) >> 16;  // RNE
  return (unsigned short)r;
}
__device__ __forceinline__ void gload16(const void* g, void* l) {
  __builtin_amdgcn_global_load_lds(
      (const __attribute__((address_space(1))) void*)g,
      (__attribute__((address_space(3))) void*)l, 16, 0, 0);
}

// ---------------- bucket-sort CSR build (coalesced writes by construction) ----

__global__ void zero_int_kernel(int* __restrict__ p, int n) {
  int i = blockIdx.x * blockDim.x + threadIdx.x;
  if (i < n) p[i] = 0;
}

__global__ void bin_count_kernel(const int* __restrict__ dst, int* __restrict__ bucketCount) {
  __shared__ int hist[NBKT];
  int tid = threadIdx.x;
  for (int i = tid; i < NBKT; i += 256) hist[i] = 0;
  __syncthreads();
  const int4* d4 = (const int4*)(dst + blockIdx.x * EPB);
  for (int i = tid; i < EPB / 4; i += 256) {
    int4 v = d4[i];
    atomicAdd(&hist[v.x >> 9], 1); atomicAdd(&hist[v.y >> 9], 1);
    atomicAdd(&hist[v.z >> 9], 1); atomicAdd(&hist[v.w >> 9], 1);
  }
  __syncthreads();
  for (int i = tid; i < NBKT; i += 256)
    if (hist[i]) atomicAdd(&bucketCount[i], hist[i]);
}

__global__ void scan_buckets_kernel(const int* __restrict__ cnt, int* __restrict__ base,
                                    int* __restrict__ cursor, int* __restrict__ rowptr) {
  int lane = threadIdx.x;
  int carry = 0;
  for (int b0 = 0; b0 < NBKT; b0 += 64) {
    int i = b0 + lane;
    int v = (i < NBKT) ? cnt[i] : 0;
    int s = v;
#pragma unroll
    for (int o = 1; o < 64; o <<= 1) { int t = __shfl_up(s, o); if (lane >= o) s += t; }
    int tot = __shfl(s, 63);
    if (i < NBKT) { base[i] = carry + s - v; cursor[i] = carry + s - v; }
    carry += tot;
  }
  if (lane == 0) { base[NBKT] = N_EDGES; rowptr[N_NODES] = N_EDGES; }
}

// pack = (dst_local<<17) | src
__global__ void bin_scatter_kernel(const int* __restrict__ src, const int* __restrict__ dst,
                                   int* __restrict__ cursor, unsigned int* __restrict__ pairs) {
  __shared__ int hist[NBKT];
  __shared__ int curs[NBKT];
  int tid = threadIdx.x;
  for (int i = tid; i < NBKT; i += 256) hist[i] = 0;
  __syncthreads();
  const int4* d4 = (const int4*)(dst + blockIdx.x * EPB);
  const int4* s4 = (const int4*)(src + blockIdx.x * EPB);
  for (int i = tid; i < EPB / 4; i += 256) {
    int4 v = d4[i];
    atomicAdd(&hist[v.x >> 9], 1); atomicAdd(&hist[v.y >> 9], 1);
    atomicAdd(&hist[v.z >> 9], 1); atomicAdd(&hist[v.w >> 9], 1);
  }
  __syncthreads();
  for (int i = tid; i < NBKT; i += 256) curs[i] = atomicAdd(&cursor[i], hist[i]);
  __syncthreads();
  for (int i = tid; i < EPB / 4; i += 256) {
    int4 v = d4[i];
    int4 u = s4[i];
    int p;
    p = atomicAdd(&curs[v.x >> 9], 1); pairs[p] = ((unsigned)(v.x & 511) << 17) | (unsigned)u.x;
    p = atomicAdd(&curs[v.y >> 9], 1); pairs[p] = ((unsigned)(v.y & 511) << 17) | (unsigned)u.y;
    p = atomicAdd(&curs[v.z >> 9], 1); pairs[p] = ((unsigned)(v.z & 511) << 17) | (unsigned)u.z;
    p = atomicAdd(&curs[v.w >> 9], 1); pairs[p] = ((unsigned)(v.w & 511) << 17) | (unsigned)u.w;
  }
}

__launch_bounds__(256)
__global__ void bucket_csr_kernel(const unsigned int* __restrict__ pairs,
                                  const int* __restrict__ base,
                                  int* __restrict__ rowptr, int* __restrict__ ebuf) {
  __shared__ int hist[512];
  __shared__ int curs[512];
  __shared__ int wsum[4];
  int b = blockIdx.x;
  int tid = threadIdx.x;
  int n0 = b << 9;
  int nn = N_NODES - n0; if (nn > 512) nn = 512;
  int lo = base[b], hi = base[b + 1];
  hist[tid] = 0; hist[tid + 256] = 0;
  __syncthreads();
  for (int i = lo + tid; i < hi; i += 256)
    atomicAdd(&hist[pairs[i] >> 17], 1);
  __syncthreads();
  int h0 = hist[2 * tid], h1 = hist[2 * tid + 1];
  int ps = h0 + h1;
  int lane = tid & 63, wave = tid >> 6;
  int s = ps;
#pragma unroll
  for (int o = 1; o < 64; o <<= 1) { int t = __shfl_up(s, o); if (lane >= o) s += t; }
  if (lane == 63) wsum[wave] = s;
  __syncthreads();
  if (tid == 0) { int c = 0; for (int k = 0; k < 4; ++k) { int t = wsum[k]; wsum[k] = c; c += t; } }
  __syncthreads();
  int base0 = lo + (s - ps) + wsum[wave];
  curs[2 * tid] = base0;
  curs[2 * tid + 1] = base0 + h0;
  if (2 * tid < nn)     rowptr[n0 + 2 * tid] = base0;
  if (2 * tid + 1 < nn) rowptr[n0 + 2 * tid + 1] = base0 + h0;
  __syncthreads();
  for (int i = lo + tid; i < hi; i += 256) {
    unsigned int p = pairs[i];
    int pos = atomicAdd(&curs[p >> 17], 1);
    ebuf[pos] = (int)(p & 0x1FFFF);
  }
}

// ---------------- conversions (merged x + weights) ----------------
// axb: [N][256] bf16 (cols 0..127 mean1, 128..255 x);  xq: [N][128] fp8 e4m3
#define CVT_X_WORK (N_NODES * 32)
__global__ void cvt_all_kernel(const float* __restrict__ x,
                               const float* __restrict__ W1l, const float* __restrict__ W1r,
                               const float* __restrict__ W2l, const float* __restrict__ W2r,
                               ushort_t* __restrict__ axb, unsigned int* __restrict__ xq,
                               ushort_t* __restrict__ W1bt, ushort_t* __restrict__ W2bt) {
  int idx = blockIdx.x * blockDim.x + threadIdx.x;
  if (idx < CVT_X_WORK) {
    int n = idx >> 5, j = (idx & 31) << 2;
    float4 v = *(const float4*)(x + (size_t)n * 128 + j);
    ushort4 o;
    o.x = f2bf(v.x); o.y = f2bf(v.y); o.z = f2bf(v.z); o.w = f2bf(v.w);
    *(ushort4*)(axb + (size_t)n * 256 + 128 + j) = o;
    unsigned int q = __builtin_amdgcn_cvt_pk_fp8_f32(v.x, v.y, 0, false);
    q = __builtin_amdgcn_cvt_pk_fp8_f32(v.z, v.w, q, true);
    xq[(size_t)n * 32 + (j >> 2)] = q;
  } else if (idx < CVT_X_WORK + 65536) {
    int t = idx - CVT_X_WORK;
    int n = t >> 8, k = t & 255;
    float v = (k < 128) ? W1l[(size_t)k * 256 + n] : W1r[(size_t)(k - 128) * 256 + n];
    W1bt[t] = f2bf(v);
  } else if (idx < CVT_X_WORK + 65536 + 32768) {
    int t = idx - CVT_X_WORK - 65536;
    int n = t >> 8, k = t & 255;
    float v = (n < 64) ? W2l[(size_t)k * 64 + n] : W2r[(size_t)k * 64 + (n - 64)];
    W2bt[t] = f2bf(v);
  }
}

// ---------------- layer-1 mean aggregation (fp8 gather, pk-f32 acc) ----------
// wave per node, 2 edges/iter (half h services edge e+h); lane j=l&31 loads 4B = 4 feats fp8
__global__ void agg_mean1_kernel(const int* __restrict__ rowptr, const int* __restrict__ ebuf,
                                 const unsigned int* __restrict__ xq, ushort_t* __restrict__ axb) {
  int node = blockIdx.x * 4 + (threadIdx.x >> 6);
  int l = threadIdx.x & 63;
  int half = l >> 5, j = l & 31;
  int beg = rowptr[node], end = rowptr[node + 1];
  f32x2 acc01 = {0.f, 0.f}, acc23 = {0.f, 0.f};
  int e = beg;
  for (; e + 8 <= end; e += 8) {
    int s0 = ebuf[e + half];
    int s1 = ebuf[e + 2 + half];
    int s2 = ebuf[e + 4 + half];
    int s3 = ebuf[e + 6 + half];
    unsigned int u0 = xq[(unsigned)(s0 * 32 + j)];
    unsigned int u1 = xq[(unsigned)(s1 * 32 + j)];
    unsigned int u2 = xq[(unsigned)(s2 * 32 + j)];
    unsigned int u3 = xq[(unsigned)(s3 * 32 + j)];
    acc01 += __builtin_amdgcn_cvt_pk_f32_fp8(u0, false);
    acc23 += __builtin_amdgcn_cvt_pk_f32_fp8(u0, true);
    acc01 += __builtin_amdgcn_cvt_pk_f32_fp8(u1, false);
    acc23 += __builtin_amdgcn_cvt_pk_f32_fp8(u1, true);
    acc01 += __builtin_amdgcn_cvt_pk_f32_fp8(u2, false);
    acc23 += __builtin_amdgcn_cvt_pk_f32_fp8(u2, true);
    acc01 += __builtin_amdgcn_cvt_pk_f32_fp8(u3, false);
    acc23 += __builtin_amdgcn_cvt_pk_f32_fp8(u3, true);
  }
  for (; e + 2 <= end; e += 2) {
    int s = ebuf[e + half];
    unsigned int u = xq[(unsigned)(s * 32 + j)];
    acc01 += __builtin_amdgcn_cvt_pk_f32_fp8(u, false);
    acc23 += __builtin_amdgcn_cvt_pk_f32_fp8(u, true);
  }
  if (e < end && half == 0) {
    int s = ebuf[e];
    unsigned int u = xq[(unsigned)(s * 32 + j)];
    acc01 += __builtin_amdgcn_cvt_pk_f32_fp8(u, false);
    acc23 += __builtin_amdgcn_cvt_pk_f32_fp8(u, true);
  }
  float a0 = acc01[0] + __shfl_xor(acc01[0], 32);
  float a1 = acc01[1] + __shfl_xor(acc01[1], 32);
  float a2 = acc23[0] + __shfl_xor(acc23[0], 32);
  float a3 = acc23[1] + __shfl_xor(acc23[1], 32);
  if (half == 0) {
    float inv = (end > beg) ? 1.0f / (float)(end - beg) : 0.0f;
    uint2 o;
    o.x = (unsigned int)f2bf(a0 * inv) | ((unsigned int)f2bf(a1 * inv) << 16);
    o.y = (unsigned int)f2bf(a2 * inv) | ((unsigned int)f2bf(a3 * inv) << 16);
    *(uint2*)(axb + (size_t)node * 256 + 4 * j) = o;
  }
}

// ---------------- bf16 MFMA GEMM (K=256 fixed) ----------------
// MODE 0: C = relu(A@Bt^T + bias) bf16.  MODE 1 (layer2, NC=128):
//   cols 0..63 (wn==0) -> P8 fp8 [N][64];  cols 64..127 (wn==1) -> QB bf16 [N][64]
template<int MODE>
__launch_bounds__(256)
__global__ void gemm_bf16_kernel(const ushort_t* __restrict__ A, const ushort_t* __restrict__ Bt,
                                 const float* __restrict__ bias, ushort_t* __restrict__ C,
                                 unsigned char* __restrict__ P8, ushort_t* __restrict__ QB,
                                 int M, int NC) {
  __shared__ ushort_t ldsA[128 * 64];  // 16 KB
  __shared__ ushort_t ldsB[128 * 64];  // 16 KB
  const int tid = threadIdx.x;
  const int lane = tid & 63;
  const int wm = (tid >> 6) & 1, wn = tid >> 7;
  const int rowBase = blockIdx.x * 128;
  const int colBase = blockIdx.y * 128;
  f32x4 acc[4][4];
#pragma unroll
  for (int i = 0; i < 4; ++i)
#pragma unroll
    for (int j = 0; j < 4; ++j) acc[i][j] = (f32x4){0.f, 0.f, 0.f, 0.f};

  for (int k0 = 0; k0 < GK; k0 += 64) {
#pragma unroll
    for (int i = 0; i < 4; ++i) {
      int s = tid + i * 256;          // 16B slot id
      int row = s >> 3, off16 = s & 7;
      int k16 = off16 ^ (row & 7);    // inverse-swizzled global source
      int ga = rowBase + row; if (ga > M - 1) ga = M - 1;
      gload16(A + (size_t)ga * GK + k0 + k16 * 8, &ldsA[s * 8]);
      gload16(Bt + (size_t)(colBase + row) * GK + k0 + k16 * 8, &ldsB[s * 8]);
    }
    __syncthreads();
#pragma unroll
    for (int kc = 0; kc < 2; ++kc) {
      bf16x8 af[4], bfr[4];
#pragma unroll
      for (int i = 0; i < 4; ++i) {
        int rA = wm * 64 + i * 16 + (lane & 15);
        int oA = (kc * 4 + (lane >> 4)) ^ (rA & 7);   // swizzled read
        af[i] = *(const bf16x8*)&ldsA[rA * 64 + oA * 8];
        int rB = wn * 64 + i * 16 + (lane & 15);
        int oB = (kc * 4 + (lane >> 4)) ^ (rB & 7);
        bfr[i] = *(const bf16x8*)&ldsB[rB * 64 + oB * 8];
      }
#pragma unroll
      for (int mi = 0; mi < 4; ++mi)
#pragma unroll
        for (int ni = 0; ni < 4; ++ni)
          acc[mi][ni] = __builtin_amdgcn_mfma_f32_16x16x32_bf16(af[mi], bfr[ni], acc[mi][ni], 0, 0, 0);
    }
    __syncthreads();
  }
#pragma unroll
  for (int mi = 0; mi < 4; ++mi) {
#pragma unroll
    for (int r = 0; r < 4; ++r) {
      int grow = rowBase + wm * 64 + mi * 16 + (lane >> 4) * 4 + r;
      if (grow >= M) continue;
#pragma unroll
      for (int ni = 0; ni < 4; ++ni) {
        float v = acc[mi][ni][r];
        if (MODE == 0) {
          int gcol = colBase + wn * 64 + ni * 16 + (lane & 15);
          C[(size_t)grow * NC + gcol] = f2bf(fmaxf(v + bias[gcol], 0.f));
        } else {
          int c = ni * 16 + (lane & 15);  // 0..63 within half
          if (wn == 0) {
            unsigned int u = __builtin_amdgcn_cvt_pk_fp8_f32(v, v, 0, false);
            P8[(size_t)grow * 64 + c] = (unsigned char)(u & 0xff);
          } else {
            QB[(size_t)grow * 64 + c] = f2bf(v);
          }
        }
      }
    }
  }
}

// ---------------- final: aggregate P (fp8), + b2 + Q, log_softmax ----------------
// wave per node, 4 edges/iter (quarter q services edge e+q); lane j=l&15 loads 4B = 4 classes
__global__ void final_kernel(const int* __restrict__ rowptr, const int* __restrict__ ebuf,
                             const unsigned int* __restrict__ p8, const ushort_t* __restrict__ qb,
                             const float* __restrict__ b2, float* __restrict__ out) {
  int node = blockIdx.x * 4 + (threadIdx.x >> 6);
  int l = threadIdx.x & 63;
  int q4 = l >> 4, j = l & 15;
  int beg = rowptr[node], end = rowptr[node + 1];
  f32x2 acc01 = {0.f, 0.f}, acc23 = {0.f, 0.f};
  int e = beg;
  for (; e + 16 <= end; e += 16) {
    int s0 = ebuf[e + q4];
    int s1 = ebuf[e + 4 + q4];
    int s2 = ebuf[e + 8 + q4];
    int s3 = ebuf[e + 12 + q4];
    unsigned int u0 = p8[(unsigned)(s0 * 16 + j)];
    unsigned int u1 = p8[(unsigned)(s1 * 16 + j)];
    unsigned int u2 = p8[(unsigned)(s2 * 16 + j)];
    unsigned int u3 = p8[(unsigned)(s3 * 16 + j)];
    acc01 += __builtin_amdgcn_cvt_pk_f32_fp8(u0, false);
    acc23 += __builtin_amdgcn_cvt_pk_f32_fp8(u0, true);
    acc01 += __builtin_amdgcn_cvt_pk_f32_fp8(u1, false);
    acc23 += __builtin_amdgcn_cvt_pk_f32_fp8(u1, true);
    acc01 += __builtin_amdgcn_cvt_pk_f32_fp8(u2, false);
    acc23 += __builtin_amdgcn_cvt_pk_f32_fp8(u2, true);
    acc01 += __builtin_amdgcn_cvt_pk_f32_fp8(u3, false);
    acc23 += __builtin_amdgcn_cvt_pk_f32_fp8(u3, true);
  }
  for (; e + 4 <= end; e += 4) {
    int s = ebuf[e + q4];
    unsigned int u = p8[(unsigned)(s * 16 + j)];
    acc01 += __builtin_amdgcn_cvt_pk_f32_fp8(u, false);
    acc23 += __builtin_amdgcn_cvt_pk_f32_fp8(u, true);
  }
  if (q4 < end - e) {
    int s = ebuf[e + q4];
    unsigned int u = p8[(unsigned)(s * 16 + j)];
    acc01 += __builtin_amdgcn_cvt_pk_f32_fp8(u, false);
    acc23 += __builtin_amdgcn_cvt_pk_f32_fp8(u, true);
  }
  // combine quarters
  float a0 = acc01[0], a1 = acc01[1], a2 = acc23[0], a3 = acc23[1];
  a0 += __shfl_xor(a0, 32); a1 += __shfl_xor(a1, 32);
  a2 += __shfl_xor(a2, 32); a3 += __shfl_xor(a3, 32);
  a0 += __shfl_xor(a0, 16); a1 += __shfl_xor(a1, 16);
  a2 += __shfl_xor(a2, 16); a3 += __shfl_xor(a3, 16);
  float inv = (end > beg) ? 1.0f / (float)(end - beg) : 0.0f;
  uint2 qv = *(const uint2*)(qb + (size_t)node * 64 + 4 * j);
  float4 bv = *(const float4*)(b2 + 4 * j);
  float v0 = a0 * inv + bv.x + bf2f(qv.x & 0xffff);
  float v1 = a1 * inv + bv.y + bf2f(qv.x >> 16);
  float v2 = a2 * inv + bv.z + bf2f(qv.y & 0xffff);
  float v3 = a3 * inv + bv.w + bf2f(qv.y >> 16);
  // log_softmax over 64 classes held 4-per-lane across 16 lanes (quarters identical)
  float m = fmaxf(fmaxf(v0, v1), fmaxf(v2, v3));
#pragma unroll
  for (int o = 8; o > 0; o >>= 1) m = fmaxf(m, __shfl_xor(m, o));
  float ssum = expf(v0 - m) + expf(v1 - m) + expf(v2 - m) + expf(v3 - m);
#pragma unroll
  for (int o = 8; o > 0; o >>= 1) ssum += __shfl_xor(ssum, o);
  if (q4 == 0) {
    float ls = logf(ssum);
    float4 o4 = {v0 - m - ls, v1 - m - ls, v2 - m - ls, v3 - m - ls};
    *(float4*)(out + (size_t)node * 64 + 4 * j) = o4;
  }
}

// ---------------- launch ----------------

extern "C" void kernel_launch(void* const* d_in, const int* in_sizes, int n_in,
                              void* d_out, int out_size, void* d_ws, size_t ws_size,
                              hipStream_t stream) {
  const float* x   = (const float*)d_in[0];
  const int*   ei  = (const int*)d_in[1];
  const float* W1l = (const float*)d_in[2];
  const float* b1  = (const float*)d_in[3];
  const float* W1r = (const float*)d_in[4];
  const float* W2l = (const float*)d_in[5];
  const float* b2  = (const float*)d_in[6];
  const float* W2r = (const float*)d_in[7];
  float* out = (float*)d_out;
  const int* src = ei;
  const int* dst = ei + N_EDGES;

  char* w = (char*)d_ws;
  int*      bucketCount = (int*)(w);                          // 784 B
  int*      bucketBase  = (int*)(w + 1024);
  int*      bucketCur   = (int*)(w + 2048);
  int*      rowptr      = (int*)(w + 4096);                   // 400 KB
  int*      ebuf        = (int*)(w + 512ull * 1024);          // 6.4 MB
  ushort_t* W1bt        = (ushort_t*)(w + 7ull * 1024 * 1024);       // 128 KB
  ushort_t* W2bt        = (ushort_t*)(w + 7ull * 1024 * 1024 + 256 * 1024);  // 64 KB
  ushort_t* axb         = (ushort_t*)(w + 8ull * 1024 * 1024);       // 51.2 MB (ends 59.2)
  ushort_t* h           = (ushort_t*)(w + 60ull * 1024 * 1024);      // 51.2 MB (ends 111.2)
  unsigned int* pairs   = (unsigned int*)(w + 60ull * 1024 * 1024);  // 6.4 MB, aliases h
  unsigned int* xq      = (unsigned int*)(w + 112ull * 1024 * 1024); // 12.8 MB fp8 x
  unsigned int* p8      = (unsigned int*)(w + 125ull * 1024 * 1024); // 6.4 MB fp8 P
  ushort_t*     qb      = (ushort_t*)(w + 132ull * 1024 * 1024);     // 12.8 MB bf16 Q

  zero_int_kernel<<<1, 256, 0, stream>>>(bucketCount, NBKT);
  bin_count_kernel<<<NBIN, 256, 0, stream>>>(dst, bucketCount);
  scan_buckets_kernel<<<1, 64, 0, stream>>>(bucketCount, bucketBase, bucketCur, rowptr);
  bin_scatter_kernel<<<NBIN, 256, 0, stream>>>(src, dst, bucketCur, pairs);
  bucket_csr_kernel<<<NBKT, 256, 0, stream>>>(pairs, bucketBase, rowptr, ebuf);

  const int CVT_TOTAL = CVT_X_WORK + 65536 + 32768;
  cvt_all_kernel<<<(CVT_TOTAL + 255) / 256, 256, 0, stream>>>(
      x, W1l, W1r, W2l, W2r, axb, xq, W1bt, W2bt);

  agg_mean1_kernel<<<N_NODES / 4, 256, 0, stream>>>(rowptr, ebuf, xq, axb);

  gemm_bf16_kernel<0><<<dim3((N_NODES + 127) / 128, 2), 256, 0, stream>>>(
      axb, W1bt, b1, h, nullptr, nullptr, N_NODES, 256);
  gemm_bf16_kernel<1><<<dim3((N_NODES + 127) / 128, 1), 256, 0, stream>>>(
      h, W2bt, nullptr, nullptr, (unsigned char*)p8, qb, N_NODES, 128);

  final_kernel<<<N_NODES / 4, 256, 0, stream>>>(rowptr, ebuf, p8, qb, b2, out);
}

// Round 9
// 225.595 us; speedup vs baseline: 5.5491x; 1.0018x over previous
//
#include <hip/hip_runtime.h>

#define N_NODES 100000
#define N_EDGES 1600000
#define GK 256      // K dim of both GEMMs
#define NBKT 196    // buckets of 512 nodes: (100000+511)>>9
#define NBIN 128    // blocks for bin count/scatter
#define EPB (N_EDGES / NBIN)  // 12500 edges per bin block

typedef __attribute__((ext_vector_type(8))) short bf16x8;
typedef __attribute__((ext_vector_type(4))) float f32x4;
typedef __attribute__((ext_vector_type(2))) float f32x2;
typedef unsigned short ushort_t;

__device__ __forceinline__ float bf2f(unsigned int bits16) {
  union { unsigned int i; float f; } v; v.i = bits16 << 16; return v.f;
}
__device__ __forceinline__ unsigned short f2bf(float f) {
  union { float f; unsigned int i; } v; v.f = f;
  unsigned int u = v.i;
  unsigned int r = (u + 0x7fffu + ((u >> 16) & 1u)) >> 16;  // RNE
  return (unsigned short)r;
}
__device__ __forceinline__ void gload16(const void* g, void* l) {
  __builtin_amdgcn_global_load_lds(
      (const __attribute__((address_space(1))) void*)g,
      (__attribute__((address_space(3))) void*)l, 16, 0, 0);
}

// ---------------- bucket-sort CSR build (coalesced writes by construction) ----

__global__ void zero_int_kernel(int* __restrict__ p, int n) {
  int i = blockIdx.x * blockDim.x + threadIdx.x;
  if (i < n) p[i] = 0;
}

__global__ void bin_count_kernel(const int* __restrict__ dst, int* __restrict__ bucketCount) {
  __shared__ int hist[NBKT];
  int tid = threadIdx.x;
  for (int i = tid; i < NBKT; i += 256) hist[i] = 0;
  __syncthreads();
  const int4* d4 = (const int4*)(dst + blockIdx.x * EPB);
  for (int i = tid; i < EPB / 4; i += 256) {
    int4 v = d4[i];
    atomicAdd(&hist[v.x >> 9], 1); atomicAdd(&hist[v.y >> 9], 1);
    atomicAdd(&hist[v.z >> 9], 1); atomicAdd(&hist[v.w >> 9], 1);
  }
  __syncthreads();
  for (int i = tid; i < NBKT; i += 256)
    if (hist[i]) atomicAdd(&bucketCount[i], hist[i]);
}

__global__ void scan_buckets_kernel(const int* __restrict__ cnt, int* __restrict__ base,
                                    int* __restrict__ cursor, int* __restrict__ rowptr) {
  int lane = threadIdx.x;
  int carry = 0;
  for (int b0 = 0; b0 < NBKT; b0 += 64) {
    int i = b0 + lane;
    int v = (i < NBKT) ? cnt[i] : 0;
    int s = v;
#pragma unroll
    for (int o = 1; o < 64; o <<= 1) { int t = __shfl_up(s, o); if (lane >= o) s += t; }
    int tot = __shfl(s, 63);
    if (i < NBKT) { base[i] = carry + s - v; cursor[i] = carry + s - v; }
    carry += tot;
  }
  if (lane == 0) { base[NBKT] = N_EDGES; rowptr[N_NODES] = N_EDGES; }
}

// pack = (dst_local<<17) | src
__global__ void bin_scatter_kernel(const int* __restrict__ src, const int* __restrict__ dst,
                                   int* __restrict__ cursor, unsigned int* __restrict__ pairs) {
  __shared__ int hist[NBKT];
  __shared__ int curs[NBKT];
  int tid = threadIdx.x;
  for (int i = tid; i < NBKT; i += 256) hist[i] = 0;
  __syncthreads();
  const int4* d4 = (const int4*)(dst + blockIdx.x * EPB);
  const int4* s4 = (const int4*)(src + blockIdx.x * EPB);
  for (int i = tid; i < EPB / 4; i += 256) {
    int4 v = d4[i];
    atomicAdd(&hist[v.x >> 9], 1); atomicAdd(&hist[v.y >> 9], 1);
    atomicAdd(&hist[v.z >> 9], 1); atomicAdd(&hist[v.w >> 9], 1);
  }
  __syncthreads();
  for (int i = tid; i < NBKT; i += 256) curs[i] = atomicAdd(&cursor[i], hist[i]);
  __syncthreads();
  for (int i = tid; i < EPB / 4; i += 256) {
    int4 v = d4[i];
    int4 u = s4[i];
    int p;
    p = atomicAdd(&curs[v.x >> 9], 1); pairs[p] = ((unsigned)(v.x & 511) << 17) | (unsigned)u.x;
    p = atomicAdd(&curs[v.y >> 9], 1); pairs[p] = ((unsigned)(v.y & 511) << 17) | (unsigned)u.y;
    p = atomicAdd(&curs[v.z >> 9], 1); pairs[p] = ((unsigned)(v.z & 511) << 17) | (unsigned)u.z;
    p = atomicAdd(&curs[v.w >> 9], 1); pairs[p] = ((unsigned)(v.w & 511) << 17) | (unsigned)u.w;
  }
}

__launch_bounds__(256)
__global__ void bucket_csr_kernel(const unsigned int* __restrict__ pairs,
                                  const int* __restrict__ base,
                                  int* __restrict__ rowptr, int* __restrict__ ebuf) {
  __shared__ int hist[512];
  __shared__ int curs[512];
  __shared__ int wsum[4];
  int b = blockIdx.x;
  int tid = threadIdx.x;
  int n0 = b << 9;
  int nn = N_NODES - n0; if (nn > 512) nn = 512;
  int lo = base[b], hi = base[b + 1];
  hist[tid] = 0; hist[tid + 256] = 0;
  __syncthreads();
  for (int i = lo + tid; i < hi; i += 256)
    atomicAdd(&hist[pairs[i] >> 17], 1);
  __syncthreads();
  int h0 = hist[2 * tid], h1 = hist[2 * tid + 1];
  int ps = h0 + h1;
  int lane = tid & 63, wave = tid >> 6;
  int s = ps;
#pragma unroll
  for (int o = 1; o < 64; o <<= 1) { int t = __shfl_up(s, o); if (lane >= o) s += t; }
  if (lane == 63) wsum[wave] = s;
  __syncthreads();
  if (tid == 0) { int c = 0; for (int k = 0; k < 4; ++k) { int t = wsum[k]; wsum[k] = c; c += t; } }
  __syncthreads();
  int base0 = lo + (s - ps) + wsum[wave];
  curs[2 * tid] = base0;
  curs[2 * tid + 1] = base0 + h0;
  if (2 * tid < nn)     rowptr[n0 + 2 * tid] = base0;
  if (2 * tid + 1 < nn) rowptr[n0 + 2 * tid + 1] = base0 + h0;
  __syncthreads();
  for (int i = lo + tid; i < hi; i += 256) {
    unsigned int p = pairs[i];
    int pos = atomicAdd(&curs[p >> 17], 1);
    ebuf[pos] = (int)(p & 0x1FFFF);
  }
}

// ---------------- conversions (merged x + weights) ----------------
// axb: [N][256] bf16 (cols 0..127 mean1, 128..255 x);  xq: [N][128] fp8 e4m3
#define CVT_X_WORK (N_NODES * 32)
__global__ void cvt_all_kernel(const float* __restrict__ x,
                               const float* __restrict__ W1l, const float* __restrict__ W1r,
                               const float* __restrict__ W2l, const float* __restrict__ W2r,
                               ushort_t* __restrict__ axb, unsigned int* __restrict__ xq,
                               ushort_t* __restrict__ W1bt, ushort_t* __restrict__ W2bt) {
  int idx = blockIdx.x * blockDim.x + threadIdx.x;
  if (idx < CVT_X_WORK) {
    int n = idx >> 5, j = (idx & 31) << 2;
    float4 v = *(const float4*)(x + (size_t)n * 128 + j);
    ushort4 o;
    o.x = f2bf(v.x); o.y = f2bf(v.y); o.z = f2bf(v.z); o.w = f2bf(v.w);
    *(ushort4*)(axb + (size_t)n * 256 + 128 + j) = o;
    unsigned int q = __builtin_amdgcn_cvt_pk_fp8_f32(v.x, v.y, 0, false);
    q = __builtin_amdgcn_cvt_pk_fp8_f32(v.z, v.w, q, true);
    xq[(size_t)n * 32 + (j >> 2)] = q;
  } else if (idx < CVT_X_WORK + 65536) {
    int t = idx - CVT_X_WORK;
    int n = t >> 8, k = t & 255;
    float v = (k < 128) ? W1l[(size_t)k * 256 + n] : W1r[(size_t)(k - 128) * 256 + n];
    W1bt[t] = f2bf(v);
  } else if (idx < CVT_X_WORK + 65536 + 32768) {
    int t = idx - CVT_X_WORK - 65536;
    int n = t >> 8, k = t & 255;
    float v = (n < 64) ? W2l[(size_t)k * 64 + n] : W2r[(size_t)k * 64 + (n - 64)];
    W2bt[t] = f2bf(v);
  }
}

// ---------------- layer-1 mean aggregation (fp8 gather, uint2/lane) ----------
// wave per node; quarter q = l>>4 services edge e+q; lane j=l&15 loads 8B = feats 8j..8j+7
__global__ void agg_mean1_kernel(const int* __restrict__ rowptr, const int* __restrict__ ebuf,
                                 const uint2* __restrict__ xq2, ushort_t* __restrict__ axb) {
  int node = blockIdx.x * 4 + (threadIdx.x >> 6);
  int l = threadIdx.x & 63;
  int q = l >> 4, j = l & 15;
  int beg = rowptr[node], end = rowptr[node + 1];
  f32x2 a0 = {0.f, 0.f}, a1 = {0.f, 0.f}, a2 = {0.f, 0.f}, a3 = {0.f, 0.f};
  int e = beg;
  for (; e + 8 <= end; e += 8) {           // 8 edges: 2 loads in flight
    int sA = ebuf[e + q];
    int sB = ebuf[e + 4 + q];
    uint2 uA = xq2[(unsigned)(sA * 16 + j)];
    uint2 uB = xq2[(unsigned)(sB * 16 + j)];
    a0 += __builtin_amdgcn_cvt_pk_f32_fp8(uA.x, false);
    a1 += __builtin_amdgcn_cvt_pk_f32_fp8(uA.x, true);
    a2 += __builtin_amdgcn_cvt_pk_f32_fp8(uA.y, false);
    a3 += __builtin_amdgcn_cvt_pk_f32_fp8(uA.y, true);
    a0 += __builtin_amdgcn_cvt_pk_f32_fp8(uB.x, false);
    a1 += __builtin_amdgcn_cvt_pk_f32_fp8(uB.x, true);
    a2 += __builtin_amdgcn_cvt_pk_f32_fp8(uB.y, false);
    a3 += __builtin_amdgcn_cvt_pk_f32_fp8(uB.y, true);
  }
  for (; e + 4 <= end; e += 4) {
    int s = ebuf[e + q];
    uint2 u = xq2[(unsigned)(s * 16 + j)];
    a0 += __builtin_amdgcn_cvt_pk_f32_fp8(u.x, false);
    a1 += __builtin_amdgcn_cvt_pk_f32_fp8(u.x, true);
    a2 += __builtin_amdgcn_cvt_pk_f32_fp8(u.y, false);
    a3 += __builtin_amdgcn_cvt_pk_f32_fp8(u.y, true);
  }
  int r = end - e;
  if (q < r) {
    int s = ebuf[e + q];
    uint2 u = xq2[(unsigned)(s * 16 + j)];
    a0 += __builtin_amdgcn_cvt_pk_f32_fp8(u.x, false);
    a1 += __builtin_amdgcn_cvt_pk_f32_fp8(u.x, true);
    a2 += __builtin_amdgcn_cvt_pk_f32_fp8(u.y, false);
    a3 += __builtin_amdgcn_cvt_pk_f32_fp8(u.y, true);
  }
  float f[8] = {a0[0], a0[1], a1[0], a1[1], a2[0], a2[1], a3[0], a3[1]};
#pragma unroll
  for (int i = 0; i < 8; ++i) {
    f[i] += __shfl_xor(f[i], 16);
    f[i] += __shfl_xor(f[i], 32);
  }
  if (q == 0) {
    float inv = (end > beg) ? 1.0f / (float)(end - beg) : 0.0f;
    uint4 o;
    o.x = (unsigned int)f2bf(f[0] * inv) | ((unsigned int)f2bf(f[1] * inv) << 16);
    o.y = (unsigned int)f2bf(f[2] * inv) | ((unsigned int)f2bf(f[3] * inv) << 16);
    o.z = (unsigned int)f2bf(f[4] * inv) | ((unsigned int)f2bf(f[5] * inv) << 16);
    o.w = (unsigned int)f2bf(f[6] * inv) | ((unsigned int)f2bf(f[7] * inv) << 16);
    *(uint4*)(axb + (size_t)node * 256 + 8 * j) = o;
  }
}

// ---------------- bf16 MFMA GEMM (K=256 fixed) ----------------
// MODE 0: C = relu(A@Bt^T + bias) bf16.  MODE 1 (layer2, NC=128):
//   cols 0..63 (wn==0) -> P8 fp8 [N][64];  cols 64..127 (wn==1) -> QB bf16 [N][64]
template<int MODE>
__launch_bounds__(256)
__global__ void gemm_bf16_kernel(const ushort_t* __restrict__ A, const ushort_t* __restrict__ Bt,
                                 const float* __restrict__ bias, ushort_t* __restrict__ C,
                                 unsigned char* __restrict__ P8, ushort_t* __restrict__ QB,
                                 int M, int NC) {
  __shared__ ushort_t ldsA[128 * 64];  // 16 KB
  __shared__ ushort_t ldsB[128 * 64];  // 16 KB
  const int tid = threadIdx.x;
  const int lane = tid & 63;
  const int wm = (tid >> 6) & 1, wn = tid >> 7;
  const int rowBase = blockIdx.x * 128;
  const int colBase = blockIdx.y * 128;
  f32x4 acc[4][4];
#pragma unroll
  for (int i = 0; i < 4; ++i)
#pragma unroll
    for (int j = 0; j < 4; ++j) acc[i][j] = (f32x4){0.f, 0.f, 0.f, 0.f};

  for (int k0 = 0; k0 < GK; k0 += 64) {
#pragma unroll
    for (int i = 0; i < 4; ++i) {
      int s = tid + i * 256;          // 16B slot id
      int row = s >> 3, off16 = s & 7;
      int k16 = off16 ^ (row & 7);    // inverse-swizzled global source
      int ga = rowBase + row; if (ga > M - 1) ga = M - 1;
      gload16(A + (size_t)ga * GK + k0 + k16 * 8, &ldsA[s * 8]);
      gload16(Bt + (size_t)(colBase + row) * GK + k0 + k16 * 8, &ldsB[s * 8]);
    }
    __syncthreads();
#pragma unroll
    for (int kc = 0; kc < 2; ++kc) {
      bf16x8 af[4], bfr[4];
#pragma unroll
      for (int i = 0; i < 4; ++i) {
        int rA = wm * 64 + i * 16 + (lane & 15);
        int oA = (kc * 4 + (lane >> 4)) ^ (rA & 7);   // swizzled read
        af[i] = *(const bf16x8*)&ldsA[rA * 64 + oA * 8];
        int rB = wn * 64 + i * 16 + (lane & 15);
        int oB = (kc * 4 + (lane >> 4)) ^ (rB & 7);
        bfr[i] = *(const bf16x8*)&ldsB[rB * 64 + oB * 8];
      }
#pragma unroll
      for (int mi = 0; mi < 4; ++mi)
#pragma unroll
        for (int ni = 0; ni < 4; ++ni)
          acc[mi][ni] = __builtin_amdgcn_mfma_f32_16x16x32_bf16(af[mi], bfr[ni], acc[mi][ni], 0, 0, 0);
    }
    __syncthreads();
  }
#pragma unroll
  for (int mi = 0; mi < 4; ++mi) {
#pragma unroll
    for (int r = 0; r < 4; ++r) {
      int grow = rowBase + wm * 64 + mi * 16 + (lane >> 4) * 4 + r;
      if (grow >= M) continue;
#pragma unroll
      for (int ni = 0; ni < 4; ++ni) {
        float v = acc[mi][ni][r];
        if (MODE == 0) {
          int gcol = colBase + wn * 64 + ni * 16 + (lane & 15);
          C[(size_t)grow * NC + gcol] = f2bf(fmaxf(v + bias[gcol], 0.f));
        } else {
          int c = ni * 16 + (lane & 15);  // 0..63 within half
          if (wn == 0) {
            unsigned int u = __builtin_amdgcn_cvt_pk_fp8_f32(v, v, 0, false);
            P8[(size_t)grow * 64 + c] = (unsigned char)(u & 0xff);
          } else {
            QB[(size_t)grow * 64 + c] = f2bf(v);
          }
        }
      }
    }
  }
}

// ---------------- final: aggregate P (fp8), + b2 + Q, log_softmax ----------------
// wave per node; group g = l>>3 services edge e+g; lane j=l&7 loads 8B = classes 8j..8j+7
__global__ void final_kernel(const int* __restrict__ rowptr, const int* __restrict__ ebuf,
                             const uint2* __restrict__ p82, const ushort_t* __restrict__ qb,
                             const float* __restrict__ b2, float* __restrict__ out) {
  int node = blockIdx.x * 4 + (threadIdx.x >> 6);
  int l = threadIdx.x & 63;
  int g = l >> 3, j = l & 7;
  int beg = rowptr[node], end = rowptr[node + 1];
  f32x2 a0 = {0.f, 0.f}, a1 = {0.f, 0.f}, a2 = {0.f, 0.f}, a3 = {0.f, 0.f};
  int e = beg;
  for (; e + 16 <= end; e += 16) {         // 16 edges: 2 loads in flight
    int sA = ebuf[e + g];
    int sB = ebuf[e + 8 + g];
    uint2 uA = p82[(unsigned)(sA * 8 + j)];
    uint2 uB = p82[(unsigned)(sB * 8 + j)];
    a0 += __builtin_amdgcn_cvt_pk_f32_fp8(uA.x, false);
    a1 += __builtin_amdgcn_cvt_pk_f32_fp8(uA.x, true);
    a2 += __builtin_amdgcn_cvt_pk_f32_fp8(uA.y, false);
    a3 += __builtin_amdgcn_cvt_pk_f32_fp8(uA.y, true);
    a0 += __builtin_amdgcn_cvt_pk_f32_fp8(uB.x, false);
    a1 += __builtin_amdgcn_cvt_pk_f32_fp8(uB.x, true);
    a2 += __builtin_amdgcn_cvt_pk_f32_fp8(uB.y, false);
    a3 += __builtin_amdgcn_cvt_pk_f32_fp8(uB.y, true);
  }
  for (; e + 8 <= end; e += 8) {
    int s = ebuf[e + g];
    uint2 u = p82[(unsigned)(s * 8 + j)];
    a0 += __builtin_amdgcn_cvt_pk_f32_fp8(u.x, false);
    a1 += __builtin_amdgcn_cvt_pk_f32_fp8(u.x, true);
    a2 += __builtin_amdgcn_cvt_pk_f32_fp8(u.y, false);
    a3 += __builtin_amdgcn_cvt_pk_f32_fp8(u.y, true);
  }
  int r = end - e;
  if (g < r) {
    int s = ebuf[e + g];
    uint2 u = p82[(unsigned)(s * 8 + j)];
    a0 += __builtin_amdgcn_cvt_pk_f32_fp8(u.x, false);
    a1 += __builtin_amdgcn_cvt_pk_f32_fp8(u.x, true);
    a2 += __builtin_amdgcn_cvt_pk_f32_fp8(u.y, false);
    a3 += __builtin_amdgcn_cvt_pk_f32_fp8(u.y, true);
  }
  float f[8] = {a0[0], a0[1], a1[0], a1[1], a2[0], a2[1], a3[0], a3[1]};
#pragma unroll
  for (int i = 0; i < 8; ++i) {
    f[i] += __shfl_xor(f[i], 8);
    f[i] += __shfl_xor(f[i], 16);
    f[i] += __shfl_xor(f[i], 32);
  }
  float inv = (end > beg) ? 1.0f / (float)(end - beg) : 0.0f;
  uint4 qv = *(const uint4*)(qb + (size_t)node * 64 + 8 * j);   // 8 bf16
  float4 bl = *(const float4*)(b2 + 8 * j);
  float4 bh = *(const float4*)(b2 + 8 * j + 4);
  float v[8];
  v[0] = f[0] * inv + bl.x + bf2f(qv.x & 0xffff);
  v[1] = f[1] * inv + bl.y + bf2f(qv.x >> 16);
  v[2] = f[2] * inv + bl.z + bf2f(qv.y & 0xffff);
  v[3] = f[3] * inv + bl.w + bf2f(qv.y >> 16);
  v[4] = f[4] * inv + bh.x + bf2f(qv.z & 0xffff);
  v[5] = f[5] * inv + bh.y + bf2f(qv.z >> 16);
  v[6] = f[6] * inv + bh.z + bf2f(qv.w & 0xffff);
  v[7] = f[7] * inv + bh.w + bf2f(qv.w >> 16);
  // log_softmax: 8 classes/lane across 8 lanes (groups replicated; xor 1,2,4 stays in-group)
  float m = v[0];
#pragma unroll
  for (int i = 1; i < 8; ++i) m = fmaxf(m, v[i]);
  m = fmaxf(m, __shfl_xor(m, 1));
  m = fmaxf(m, __shfl_xor(m, 2));
  m = fmaxf(m, __shfl_xor(m, 4));
  float ssum = 0.f;
#pragma unroll
  for (int i = 0; i < 8; ++i) ssum += expf(v[i] - m);
  ssum += __shfl_xor(ssum, 1);
  ssum += __shfl_xor(ssum, 2);
  ssum += __shfl_xor(ssum, 4);
  if (g == 0) {
    float ls = m + logf(ssum);
    float4 o0 = {v[0] - ls, v[1] - ls, v[2] - ls, v[3] - ls};
    float4 o1 = {v[4] - ls, v[5] - ls, v[6] - ls, v[7] - ls};
    float* op = out + (size_t)node * 64 + 8 * j;
    *(float4*)op = o0;
    *(float4*)(op + 4) = o1;
  }
}

// ---------------- launch ----------------

extern "C" void kernel_launch(void* const* d_in, const int* in_sizes, int n_in,
                              void* d_out, int out_size, void* d_ws, size_t ws_size,
                              hipStream_t stream) {
  const float* x   = (const float*)d_in[0];
  const int*   ei  = (const int*)d_in[1];
  const float* W1l = (const float*)d_in[2];
  const float* b1  = (const float*)d_in[3];
  const float* W1r = (const float*)d_in[4];
  const float* W2l = (const float*)d_in[5];
  const float* b2  = (const float*)d_in[6];
  const float* W2r = (const float*)d_in[7];
  float* out = (float*)d_out;
  const int* src = ei;
  const int* dst = ei + N_EDGES;

  char* w = (char*)d_ws;
  int*      bucketCount = (int*)(w);                          // 784 B
  int*      bucketBase  = (int*)(w + 1024);
  int*      bucketCur   = (int*)(w + 2048);
  int*      rowptr      = (int*)(w + 4096);                   // 400 KB
  int*      ebuf        = (int*)(w + 512ull * 1024);          // 6.4 MB
  ushort_t* W1bt        = (ushort_t*)(w + 7ull * 1024 * 1024);       // 128 KB
  ushort_t* W2bt        = (ushort_t*)(w + 7ull * 1024 * 1024 + 256 * 1024);  // 64 KB
  ushort_t* axb         = (ushort_t*)(w + 8ull * 1024 * 1024);       // 51.2 MB (ends 59.2)
  ushort_t* h           = (ushort_t*)(w + 60ull * 1024 * 1024);      // 51.2 MB (ends 111.2)
  unsigned int* pairs   = (unsigned int*)(w + 60ull * 1024 * 1024);  // 6.4 MB, aliases h
  unsigned int* xq      = (unsigned int*)(w + 112ull * 1024 * 1024); // 12.8 MB fp8 x
  unsigned int* p8      = (unsigned int*)(w + 125ull * 1024 * 1024); // 6.4 MB fp8 P
  ushort_t*     qb      = (ushort_t*)(w + 132ull * 1024 * 1024);     // 12.8 MB bf16 Q

  zero_int_kernel<<<1, 256, 0, stream>>>(bucketCount, NBKT);
  bin_count_kernel<<<NBIN, 256, 0, stream>>>(dst, bucketCount);
  scan_buckets_kernel<<<1, 64, 0, stream>>>(bucketCount, bucketBase, bucketCur, rowptr);
  bin_scatter_kernel<<<NBIN, 256, 0, stream>>>(src, dst, bucketCur, pairs);
  bucket_csr_kernel<<<NBKT, 256, 0, stream>>>(pairs, bucketBase, rowptr, ebuf);

  const int CVT_TOTAL = CVT_X_WORK + 65536 + 32768;
  cvt_all_kernel<<<(CVT_TOTAL + 255) / 256, 256, 0, stream>>>(
      x, W1l, W1r, W2l, W2r, axb, xq, W1bt, W2bt);

  agg_mean1_kernel<<<N_NODES / 4, 256, 0, stream>>>(rowptr, ebuf, (const uint2*)xq, axb);

  gemm_bf16_kernel<0><<<dim3((N_NODES + 127) / 128, 2), 256, 0, stream>>>(
      axb, W1bt, b1, h, nullptr, nullptr, N_NODES, 256);
  gemm_bf16_kernel<1><<<dim3((N_NODES + 127) / 128, 1), 256, 0, stream>>>(
      h, W2bt, nullptr, nullptr, (unsigned char*)p8, qb, N_NODES, 128);

  final_kernel<<<N_NODES / 4, 256, 0, stream>>>(rowptr, ebuf, (const uint2*)p8, qb, b2, out);
}

// Round 10
// 209.659 us; speedup vs baseline: 5.9709x; 1.0760x over previous
//
#include <hip/hip_runtime.h>

#define N_NODES 100000
#define N_EDGES 1600000
#define GK 256      // K dim of both GEMMs
#define NBKT 196    // buckets of 512 nodes: (100000+511)>>9
#define NBIN 128    // blocks for bin count/scatter
#define EPB (N_EDGES / NBIN)  // 12500 edges per bin block

typedef __attribute__((ext_vector_type(8))) short bf16x8;
typedef __attribute__((ext_vector_type(4))) float f32x4;
typedef __attribute__((ext_vector_type(2))) float f32x2;
typedef unsigned short ushort_t;

__device__ __forceinline__ float bf2f(unsigned int bits16) {
  union { unsigned int i; float f; } v; v.i = bits16 << 16; return v.f;
}
__device__ __forceinline__ unsigned short f2bf(float f) {
  union { float f; unsigned int i; } v; v.f = f;
  unsigned int u = v.i;
  unsigned int r = (u + 0x7fffu + ((u >> 16) & 1u)) >> 16;  // RNE
  return (unsigned short)r;
}
__device__ __forceinline__ unsigned pkbf(f32x2 a) {
  return (unsigned)f2bf(a[0]) | ((unsigned)f2bf(a[1]) << 16);
}
__device__ __forceinline__ void gload16(const void* g, void* l) {
  __builtin_amdgcn_global_load_lds(
      (const __attribute__((address_space(1))) void*)g,
      (__attribute__((address_space(3))) void*)l, 16, 0, 0);
}

// accumulate one u32 (4 fp8) into acc[b], acc[b+1]  (static indices only)
#define ACC_U32(u, b) \
  acc[b] += __builtin_amdgcn_cvt_pk_f32_fp8((u), false); \
  acc[(b) + 1] += __builtin_amdgcn_cvt_pk_f32_fp8((u), true);
#define ACC_U4(U, b) \
  ACC_U32((U).x, (b)) ACC_U32((U).y, (b) + 2) ACC_U32((U).z, (b) + 4) ACC_U32((U).w, (b) + 6)

// ---------------- bucket-sort CSR build (coalesced writes by construction) ----

__global__ void zero_int_kernel(int* __restrict__ p, int n) {
  int i = blockIdx.x * blockDim.x + threadIdx.x;
  if (i < n) p[i] = 0;
}

__global__ void bin_count_kernel(const int* __restrict__ dst, int* __restrict__ bucketCount) {
  __shared__ int hist[NBKT];
  int tid = threadIdx.x;
  for (int i = tid; i < NBKT; i += 256) hist[i] = 0;
  __syncthreads();
  const int4* d4 = (const int4*)(dst + blockIdx.x * EPB);
  for (int i = tid; i < EPB / 4; i += 256) {
    int4 v = d4[i];
    atomicAdd(&hist[v.x >> 9], 1); atomicAdd(&hist[v.y >> 9], 1);
    atomicAdd(&hist[v.z >> 9], 1); atomicAdd(&hist[v.w >> 9], 1);
  }
  __syncthreads();
  for (int i = tid; i < NBKT; i += 256)
    if (hist[i]) atomicAdd(&bucketCount[i], hist[i]);
}

__global__ void scan_buckets_kernel(const int* __restrict__ cnt, int* __restrict__ base,
                                    int* __restrict__ cursor, int* __restrict__ rowptr) {
  int lane = threadIdx.x;
  int carry = 0;
  for (int b0 = 0; b0 < NBKT; b0 += 64) {
    int i = b0 + lane;
    int v = (i < NBKT) ? cnt[i] : 0;
    int s = v;
#pragma unroll
    for (int o = 1; o < 64; o <<= 1) { int t = __shfl_up(s, o); if (lane >= o) s += t; }
    int tot = __shfl(s, 63);
    if (i < NBKT) { base[i] = carry + s - v; cursor[i] = carry + s - v; }
    carry += tot;
  }
  if (lane == 0) { base[NBKT] = N_EDGES; rowptr[N_NODES] = N_EDGES; }
}

// pack = (dst_local<<17) | src
__global__ void bin_scatter_kernel(const int* __restrict__ src, const int* __restrict__ dst,
                                   int* __restrict__ cursor, unsigned int* __restrict__ pairs) {
  __shared__ int hist[NBKT];
  __shared__ int curs[NBKT];
  int tid = threadIdx.x;
  for (int i = tid; i < NBKT; i += 256) hist[i] = 0;
  __syncthreads();
  const int4* d4 = (const int4*)(dst + blockIdx.x * EPB);
  const int4* s4 = (const int4*)(src + blockIdx.x * EPB);
  for (int i = tid; i < EPB / 4; i += 256) {
    int4 v = d4[i];
    atomicAdd(&hist[v.x >> 9], 1); atomicAdd(&hist[v.y >> 9], 1);
    atomicAdd(&hist[v.z >> 9], 1); atomicAdd(&hist[v.w >> 9], 1);
  }
  __syncthreads();
  for (int i = tid; i < NBKT; i += 256) curs[i] = atomicAdd(&cursor[i], hist[i]);
  __syncthreads();
  for (int i = tid; i < EPB / 4; i += 256) {
    int4 v = d4[i];
    int4 u = s4[i];
    int p;
    p = atomicAdd(&curs[v.x >> 9], 1); pairs[p] = ((unsigned)(v.x & 511) << 17) | (unsigned)u.x;
    p = atomicAdd(&curs[v.y >> 9], 1); pairs[p] = ((unsigned)(v.y & 511) << 17) | (unsigned)u.y;
    p = atomicAdd(&curs[v.z >> 9], 1); pairs[p] = ((unsigned)(v.z & 511) << 17) | (unsigned)u.z;
    p = atomicAdd(&curs[v.w >> 9], 1); pairs[p] = ((unsigned)(v.w & 511) << 17) | (unsigned)u.w;
  }
}

__launch_bounds__(256)
__global__ void bucket_csr_kernel(const unsigned int* __restrict__ pairs,
                                  const int* __restrict__ base,
                                  int* __restrict__ rowptr, int* __restrict__ ebuf) {
  __shared__ int hist[512];
  __shared__ int curs[512];
  __shared__ int wsum[4];
  int b = blockIdx.x;
  int tid = threadIdx.x;
  int n0 = b << 9;
  int nn = N_NODES - n0; if (nn > 512) nn = 512;
  int lo = base[b], hi = base[b + 1];
  hist[tid] = 0; hist[tid + 256] = 0;
  __syncthreads();
  for (int i = lo + tid; i < hi; i += 256)
    atomicAdd(&hist[pairs[i] >> 17], 1);
  __syncthreads();
  int h0 = hist[2 * tid], h1 = hist[2 * tid + 1];
  int ps = h0 + h1;
  int lane = tid & 63, wave = tid >> 6;
  int s = ps;
#pragma unroll
  for (int o = 1; o < 64; o <<= 1) { int t = __shfl_up(s, o); if (lane >= o) s += t; }
  if (lane == 63) wsum[wave] = s;
  __syncthreads();
  if (tid == 0) { int c = 0; for (int k = 0; k < 4; ++k) { int t = wsum[k]; wsum[k] = c; c += t; } }
  __syncthreads();
  int base0 = lo + (s - ps) + wsum[wave];
  curs[2 * tid] = base0;
  curs[2 * tid + 1] = base0 + h0;
  if (2 * tid < nn)     rowptr[n0 + 2 * tid] = base0;
  if (2 * tid + 1 < nn) rowptr[n0 + 2 * tid + 1] = base0 + h0;
  __syncthreads();
  for (int i = lo + tid; i < hi; i += 256) {
    unsigned int p = pairs[i];
    int pos = atomicAdd(&curs[p >> 17], 1);
    ebuf[pos] = (int)(p & 0x1FFFF);
  }
}

// ---------------- conversions (merged x + weights) ----------------
// axb: [N][256] bf16 (cols 0..127 mean1, 128..255 x);  xq: [N][128] fp8 e4m3
#define CVT_X_WORK (N_NODES * 32)
__global__ void cvt_all_kernel(const float* __restrict__ x,
                               const float* __restrict__ W1l, const float* __restrict__ W1r,
                               const float* __restrict__ W2l, const float* __restrict__ W2r,
                               ushort_t* __restrict__ axb, unsigned int* __restrict__ xq,
                               ushort_t* __restrict__ W1bt, ushort_t* __restrict__ W2bt) {
  int idx = blockIdx.x * blockDim.x + threadIdx.x;
  if (idx < CVT_X_WORK) {
    int n = idx >> 5, j = (idx & 31) << 2;
    float4 v = *(const float4*)(x + (size_t)n * 128 + j);
    ushort4 o;
    o.x = f2bf(v.x); o.y = f2bf(v.y); o.z = f2bf(v.z); o.w = f2bf(v.w);
    *(ushort4*)(axb + (size_t)n * 256 + 128 + j) = o;
    unsigned int q = __builtin_amdgcn_cvt_pk_fp8_f32(v.x, v.y, 0, false);
    q = __builtin_amdgcn_cvt_pk_fp8_f32(v.z, v.w, q, true);
    xq[(size_t)n * 32 + (j >> 2)] = q;
  } else if (idx < CVT_X_WORK + 65536) {
    int t = idx - CVT_X_WORK;
    int n = t >> 8, k = t & 255;
    float v = (k < 128) ? W1l[(size_t)k * 256 + n] : W1r[(size_t)(k - 128) * 256 + n];
    W1bt[t] = f2bf(v);
  } else if (idx < CVT_X_WORK + 65536 + 32768) {
    int t = idx - CVT_X_WORK - 65536;
    int n = t >> 8, k = t & 255;
    float v = (n < 64) ? W2l[(size_t)k * 64 + n] : W2r[(size_t)k * 64 + (n - 64)];
    W2bt[t] = f2bf(v);
  }
}

// ---------------- layer-1 mean aggregation: 2 lanes per node ----------------
// lane pair (2k,2k+1): half h owns feats h*64..h*64+63 (32 f32x2 acc in registers).
// No cross-lane combine needed (features partitioned). Epilogue amortized over
// 32 concurrent nodes per wave.
__launch_bounds__(256)
__global__ void agg_mean1_kernel(const int* __restrict__ rowptr, const int* __restrict__ ebuf,
                                 const uint4* __restrict__ xq4, ushort_t* __restrict__ axb) {
  int t = blockIdx.x * 256 + threadIdx.x;
  int node = t >> 1, half = t & 1;
  bool valid = node < N_NODES;
  int anode = valid ? node : 0;
  int beg = rowptr[anode], end = rowptr[anode + 1];
  if (!valid) end = beg;
  f32x2 acc[32];
#pragma unroll
  for (int i = 0; i < 32; ++i) acc[i] = (f32x2){0.f, 0.f};
  for (int e = beg; e < end; ++e) {
    int s = ebuf[e];
    const uint4* row = xq4 + (unsigned)(s * 8 + half * 4);  // 4x16B = 64 feats
    uint4 r0 = row[0], r1 = row[1], r2 = row[2], r3 = row[3];
    ACC_U4(r0, 0) ACC_U4(r1, 8) ACC_U4(r2, 16) ACC_U4(r3, 24)
  }
  if (!valid) return;
  float inv = (end > beg) ? 1.0f / (float)(end - beg) : 0.0f;
  f32x2 inv2 = {inv, inv};
#pragma unroll
  for (int i = 0; i < 32; ++i) acc[i] *= inv2;
  uint4* orow = (uint4*)(axb + (size_t)node * 256 + half * 64);
#pragma unroll
  for (int k = 0; k < 8; ++k) {
    uint4 o;
    o.x = pkbf(acc[4 * k + 0]);
    o.y = pkbf(acc[4 * k + 1]);
    o.z = pkbf(acc[4 * k + 2]);
    o.w = pkbf(acc[4 * k + 3]);
    orow[k] = o;
  }
}

// ---------------- bf16 MFMA GEMM (K=256 fixed) ----------------
// MODE 0: C = relu(A@Bt^T + bias) bf16.  MODE 1 (layer2, NC=128):
//   cols 0..63 (wn==0) -> P8 fp8 [N][64];  cols 64..127 (wn==1) -> QB bf16 [N][64]
template<int MODE>
__launch_bounds__(256)
__global__ void gemm_bf16_kernel(const ushort_t* __restrict__ A, const ushort_t* __restrict__ Bt,
                                 const float* __restrict__ bias, ushort_t* __restrict__ C,
                                 unsigned char* __restrict__ P8, ushort_t* __restrict__ QB,
                                 int M, int NC) {
  __shared__ ushort_t ldsA[128 * 64];  // 16 KB
  __shared__ ushort_t ldsB[128 * 64];  // 16 KB
  const int tid = threadIdx.x;
  const int lane = tid & 63;
  const int wm = (tid >> 6) & 1, wn = tid >> 7;
  const int rowBase = blockIdx.x * 128;
  const int colBase = blockIdx.y * 128;
  f32x4 acc[4][4];
#pragma unroll
  for (int i = 0; i < 4; ++i)
#pragma unroll
    for (int j = 0; j < 4; ++j) acc[i][j] = (f32x4){0.f, 0.f, 0.f, 0.f};

  for (int k0 = 0; k0 < GK; k0 += 64) {
#pragma unroll
    for (int i = 0; i < 4; ++i) {
      int s = tid + i * 256;          // 16B slot id
      int row = s >> 3, off16 = s & 7;
      int k16 = off16 ^ (row & 7);    // inverse-swizzled global source
      int ga = rowBase + row; if (ga > M - 1) ga = M - 1;
      gload16(A + (size_t)ga * GK + k0 + k16 * 8, &ldsA[s * 8]);
      gload16(Bt + (size_t)(colBase + row) * GK + k0 + k16 * 8, &ldsB[s * 8]);
    }
    __syncthreads();
#pragma unroll
    for (int kc = 0; kc < 2; ++kc) {
      bf16x8 af[4], bfr[4];
#pragma unroll
      for (int i = 0; i < 4; ++i) {
        int rA = wm * 64 + i * 16 + (lane & 15);
        int oA = (kc * 4 + (lane >> 4)) ^ (rA & 7);   // swizzled read
        af[i] = *(const bf16x8*)&ldsA[rA * 64 + oA * 8];
        int rB = wn * 64 + i * 16 + (lane & 15);
        int oB = (kc * 4 + (lane >> 4)) ^ (rB & 7);
        bfr[i] = *(const bf16x8*)&ldsB[rB * 64 + oB * 8];
      }
#pragma unroll
      for (int mi = 0; mi < 4; ++mi)
#pragma unroll
        for (int ni = 0; ni < 4; ++ni)
          acc[mi][ni] = __builtin_amdgcn_mfma_f32_16x16x32_bf16(af[mi], bfr[ni], acc[mi][ni], 0, 0, 0);
    }
    __syncthreads();
  }
#pragma unroll
  for (int mi = 0; mi < 4; ++mi) {
#pragma unroll
    for (int r = 0; r < 4; ++r) {
      int grow = rowBase + wm * 64 + mi * 16 + (lane >> 4) * 4 + r;
      if (grow >= M) continue;
#pragma unroll
      for (int ni = 0; ni < 4; ++ni) {
        float v = acc[mi][ni][r];
        if (MODE == 0) {
          int gcol = colBase + wn * 64 + ni * 16 + (lane & 15);
          C[(size_t)grow * NC + gcol] = f2bf(fmaxf(v + bias[gcol], 0.f));
        } else {
          int c = ni * 16 + (lane & 15);  // 0..63 within half
          if (wn == 0) {
            unsigned int u = __builtin_amdgcn_cvt_pk_fp8_f32(v, v, 0, false);
            P8[(size_t)grow * 64 + c] = (unsigned char)(u & 0xff);
          } else {
            QB[(size_t)grow * 64 + c] = f2bf(v);
          }
        }
      }
    }
  }
}

// ---------------- final: one lane per node ----------------
// Lane holds all 64 class accumulators (32 f32x2) in registers; the softmax
// epilogue runs concurrently for 64 nodes per wave (no shfl, no redundancy).
__launch_bounds__(256)
__global__ void final_kernel(const int* __restrict__ rowptr, const int* __restrict__ ebuf,
                             const uint4* __restrict__ p84, const ushort_t* __restrict__ qb,
                             const float* __restrict__ b2, float* __restrict__ out) {
  int node = blockIdx.x * 256 + threadIdx.x;
  bool valid = node < N_NODES;
  int anode = valid ? node : 0;
  int beg = rowptr[anode], end = rowptr[anode + 1];
  if (!valid) end = beg;
  f32x2 acc[32];
#pragma unroll
  for (int i = 0; i < 32; ++i) acc[i] = (f32x2){0.f, 0.f};
  for (int e = beg; e < end; ++e) {
    int s = ebuf[e];
    const uint4* row = p84 + (unsigned)(s * 4);  // 64B = 64 classes fp8
    uint4 r0 = row[0], r1 = row[1], r2 = row[2], r3 = row[3];
    ACC_U4(r0, 0) ACC_U4(r1, 8) ACC_U4(r2, 16) ACC_U4(r3, 24)
  }
  if (!valid) return;
  float inv = (end > beg) ? 1.0f / (float)(end - beg) : 0.0f;
  f32x2 inv2 = {inv, inv};
#pragma unroll
  for (int i = 0; i < 32; ++i) acc[i] *= inv2;
  // + b2 (uniform, scalar loads) + Q (this node's bf16 row)
  const uint4* qrow = (const uint4*)(qb + (size_t)node * 64);
#pragma unroll
  for (int k = 0; k < 8; ++k) {
    uint4 q = qrow[k];
    acc[4 * k + 0][0] += b2[8 * k + 0] + bf2f(q.x & 0xffff);
    acc[4 * k + 0][1] += b2[8 * k + 1] + bf2f(q.x >> 16);
    acc[4 * k + 1][0] += b2[8 * k + 2] + bf2f(q.y & 0xffff);
    acc[4 * k + 1][1] += b2[8 * k + 3] + bf2f(q.y >> 16);
    acc[4 * k + 2][0] += b2[8 * k + 4] + bf2f(q.z & 0xffff);
    acc[4 * k + 2][1] += b2[8 * k + 5] + bf2f(q.z >> 16);
    acc[4 * k + 3][0] += b2[8 * k + 6] + bf2f(q.w & 0xffff);
    acc[4 * k + 3][1] += b2[8 * k + 7] + bf2f(q.w >> 16);
  }
  // in-lane log_softmax over 64 values
  float mx[32];
#pragma unroll
  for (int i = 0; i < 32; ++i) mx[i] = fmaxf(acc[i][0], acc[i][1]);
#pragma unroll
  for (int s = 16; s >= 1; s >>= 1)
#pragma unroll
    for (int j = 0; j < 16; ++j)
      if (j < s) mx[j] = fmaxf(mx[j], mx[j + s]);
  float m = mx[0];
  float sm[32];
#pragma unroll
  for (int i = 0; i < 32; ++i)
    sm[i] = __expf(acc[i][0] - m) + __expf(acc[i][1] - m);
#pragma unroll
  for (int s = 16; s >= 1; s >>= 1)
#pragma unroll
    for (int j = 0; j < 16; ++j)
      if (j < s) sm[j] += sm[j + s];
  float ls = m + __logf(sm[0]);
  f32x2 ls2 = {ls, ls};
  float4* orow = (float4*)(out + (size_t)node * 64);
#pragma unroll
  for (int i = 0; i < 16; ++i) {
    f32x2 a = acc[2 * i] - ls2;
    f32x2 b = acc[2 * i + 1] - ls2;
    float4 o = {a[0], a[1], b[0], b[1]};
    orow[i] = o;
  }
}

// ---------------- launch ----------------

extern "C" void kernel_launch(void* const* d_in, const int* in_sizes, int n_in,
                              void* d_out, int out_size, void* d_ws, size_t ws_size,
                              hipStream_t stream) {
  const float* x   = (const float*)d_in[0];
  const int*   ei  = (const int*)d_in[1];
  const float* W1l = (const float*)d_in[2];
  const float* b1  = (const float*)d_in[3];
  const float* W1r = (const float*)d_in[4];
  const float* W2l = (const float*)d_in[5];
  const float* b2  = (const float*)d_in[6];
  const float* W2r = (const float*)d_in[7];
  float* out = (float*)d_out;
  const int* src = ei;
  const int* dst = ei + N_EDGES;

  char* w = (char*)d_ws;
  int*      bucketCount = (int*)(w);                          // 784 B
  int*      bucketBase  = (int*)(w + 1024);
  int*      bucketCur   = (int*)(w + 2048);
  int*      rowptr      = (int*)(w + 4096);                   // 400 KB
  int*      ebuf        = (int*)(w + 512ull * 1024);          // 6.4 MB
  ushort_t* W1bt        = (ushort_t*)(w + 7ull * 1024 * 1024);       // 128 KB
  ushort_t* W2bt        = (ushort_t*)(w + 7ull * 1024 * 1024 + 256 * 1024);  // 64 KB
  ushort_t* axb         = (ushort_t*)(w + 8ull * 1024 * 1024);       // 51.2 MB (ends 59.2)
  ushort_t* h           = (ushort_t*)(w + 60ull * 1024 * 1024);      // 51.2 MB (ends 111.2)
  unsigned int* pairs   = (unsigned int*)(w + 60ull * 1024 * 1024);  // 6.4 MB, aliases h
  unsigned int* xq      = (unsigned int*)(w + 112ull * 1024 * 1024); // 12.8 MB fp8 x
  unsigned int* p8      = (unsigned int*)(w + 125ull * 1024 * 1024); // 6.4 MB fp8 P
  ushort_t*     qb      = (ushort_t*)(w + 132ull * 1024 * 1024);     // 12.8 MB bf16 Q

  zero_int_kernel<<<1, 256, 0, stream>>>(bucketCount, NBKT);
  bin_count_kernel<<<NBIN, 256, 0, stream>>>(dst, bucketCount);
  scan_buckets_kernel<<<1, 64, 0, stream>>>(bucketCount, bucketBase, bucketCur, rowptr);
  bin_scatter_kernel<<<NBIN, 256, 0, stream>>>(src, dst, bucketCur, pairs);
  bucket_csr_kernel<<<NBKT, 256, 0, stream>>>(pairs, bucketBase, rowptr, ebuf);

  const int CVT_TOTAL = CVT_X_WORK + 65536 + 32768;
  cvt_all_kernel<<<(CVT_TOTAL + 255) / 256, 256, 0, stream>>>(
      x, W1l, W1r, W2l, W2r, axb, xq, W1bt, W2bt);

  agg_mean1_kernel<<<(2 * N_NODES + 255) / 256, 256, 0, stream>>>(
      rowptr, ebuf, (const uint4*)xq, axb);

  gemm_bf16_kernel<0><<<dim3((N_NODES + 127) / 128, 2), 256, 0, stream>>>(
      axb, W1bt, b1, h, nullptr, nullptr, N_NODES, 256);
  gemm_bf16_kernel<1><<<dim3((N_NODES + 127) / 128, 1), 256, 0, stream>>>(
      h, W2bt, nullptr, nullptr, (unsigned char*)p8, qb, N_NODES, 128);

  final_kernel<<<(N_NODES + 255) / 256, 256, 0, stream>>>(
      rowptr, ebuf, (const uint4*)p8, qb, b2, out);
}

// Round 11
// 199.878 us; speedup vs baseline: 6.2631x; 1.0489x over previous
//
#include <hip/hip_runtime.h>

#define N_NODES 100000
#define N_EDGES 1600000
#define GK 256      // K dim of both GEMMs
#define NBKT 196    // buckets of 512 nodes: (100000+511)>>9
#define NBIN 128    // blocks for bin count/scatter
#define EPB (N_EDGES / NBIN)  // 12500 edges per bin block

typedef __attribute__((ext_vector_type(8))) short bf16x8;
typedef __attribute__((ext_vector_type(4))) float f32x4;
typedef __attribute__((ext_vector_type(2))) float f32x2;
typedef unsigned short ushort_t;

__device__ __forceinline__ float bf2f(unsigned int bits16) {
  union { unsigned int i; float f; } v; v.i = bits16 << 16; return v.f;
}
__device__ __forceinline__ unsigned short f2bf(float f) {
  union { float f; unsigned int i; } v; v.f = f;
  unsigned int u = v.i;
  unsigned int r = (u + 0x7fffu + ((u >> 16) & 1u)) >> 16;  // RNE
  return (unsigned short)r;
}
__device__ __forceinline__ unsigned pkbf(f32x2 a) {
  return (unsigned)f2bf(a[0]) | ((unsigned)f2bf(a[1]) << 16);
}
__device__ __forceinline__ void gload16(const void* g, void* l) {
  __builtin_amdgcn_global_load_lds(
      (const __attribute__((address_space(1))) void*)g,
      (__attribute__((address_space(3))) void*)l, 16, 0, 0);
}

// accumulate one u32 (4 fp8) into acc[b], acc[b+1]  (static indices only)
#define ACC_U32(u, b) \
  acc[b] += __builtin_amdgcn_cvt_pk_f32_fp8((u), false); \
  acc[(b) + 1] += __builtin_amdgcn_cvt_pk_f32_fp8((u), true);
#define ACC_U4(U, b) \
  ACC_U32((U).x, (b)) ACC_U32((U).y, (b) + 2) ACC_U32((U).z, (b) + 4) ACC_U32((U).w, (b) + 6)

// ---------------- bucket-sort CSR build (coalesced writes by construction) ----

__global__ void zero_int_kernel(int* __restrict__ p, int n) {
  int i = blockIdx.x * blockDim.x + threadIdx.x;
  if (i < n) p[i] = 0;
}

__global__ void bin_count_kernel(const int* __restrict__ dst, int* __restrict__ bucketCount) {
  __shared__ int hist[NBKT];
  int tid = threadIdx.x;
  for (int i = tid; i < NBKT; i += 256) hist[i] = 0;
  __syncthreads();
  const int4* d4 = (const int4*)(dst + blockIdx.x * EPB);
  for (int i = tid; i < EPB / 4; i += 256) {
    int4 v = d4[i];
    atomicAdd(&hist[v.x >> 9], 1); atomicAdd(&hist[v.y >> 9], 1);
    atomicAdd(&hist[v.z >> 9], 1); atomicAdd(&hist[v.w >> 9], 1);
  }
  __syncthreads();
  for (int i = tid; i < NBKT; i += 256)
    if (hist[i]) atomicAdd(&bucketCount[i], hist[i]);
}

__global__ void scan_buckets_kernel(const int* __restrict__ cnt, int* __restrict__ base,
                                    int* __restrict__ cursor, int* __restrict__ rowptr) {
  int lane = threadIdx.x;
  int carry = 0;
  for (int b0 = 0; b0 < NBKT; b0 += 64) {
    int i = b0 + lane;
    int v = (i < NBKT) ? cnt[i] : 0;
    int s = v;
#pragma unroll
    for (int o = 1; o < 64; o <<= 1) { int t = __shfl_up(s, o); if (lane >= o) s += t; }
    int tot = __shfl(s, 63);
    if (i < NBKT) { base[i] = carry + s - v; cursor[i] = carry + s - v; }
    carry += tot;
  }
  if (lane == 0) { base[NBKT] = N_EDGES; rowptr[N_NODES] = N_EDGES; }
}

// pack = (dst_local<<17) | src
__global__ void bin_scatter_kernel(const int* __restrict__ src, const int* __restrict__ dst,
                                   int* __restrict__ cursor, unsigned int* __restrict__ pairs) {
  __shared__ int hist[NBKT];
  __shared__ int curs[NBKT];
  int tid = threadIdx.x;
  for (int i = tid; i < NBKT; i += 256) hist[i] = 0;
  __syncthreads();
  const int4* d4 = (const int4*)(dst + blockIdx.x * EPB);
  const int4* s4 = (const int4*)(src + blockIdx.x * EPB);
  for (int i = tid; i < EPB / 4; i += 256) {
    int4 v = d4[i];
    atomicAdd(&hist[v.x >> 9], 1); atomicAdd(&hist[v.y >> 9], 1);
    atomicAdd(&hist[v.z >> 9], 1); atomicAdd(&hist[v.w >> 9], 1);
  }
  __syncthreads();
  for (int i = tid; i < NBKT; i += 256) curs[i] = atomicAdd(&cursor[i], hist[i]);
  __syncthreads();
  for (int i = tid; i < EPB / 4; i += 256) {
    int4 v = d4[i];
    int4 u = s4[i];
    int p;
    p = atomicAdd(&curs[v.x >> 9], 1); pairs[p] = ((unsigned)(v.x & 511) << 17) | (unsigned)u.x;
    p = atomicAdd(&curs[v.y >> 9], 1); pairs[p] = ((unsigned)(v.y & 511) << 17) | (unsigned)u.y;
    p = atomicAdd(&curs[v.z >> 9], 1); pairs[p] = ((unsigned)(v.z & 511) << 17) | (unsigned)u.z;
    p = atomicAdd(&curs[v.w >> 9], 1); pairs[p] = ((unsigned)(v.w & 511) << 17) | (unsigned)u.w;
  }
}

__launch_bounds__(256)
__global__ void bucket_csr_kernel(const unsigned int* __restrict__ pairs,
                                  const int* __restrict__ base,
                                  int* __restrict__ rowptr, int* __restrict__ ebuf) {
  __shared__ int hist[512];
  __shared__ int curs[512];
  __shared__ int wsum[4];
  int b = blockIdx.x;
  int tid = threadIdx.x;
  int n0 = b << 9;
  int nn = N_NODES - n0; if (nn > 512) nn = 512;
  int lo = base[b], hi = base[b + 1];
  hist[tid] = 0; hist[tid + 256] = 0;
  __syncthreads();
  for (int i = lo + tid; i < hi; i += 256)
    atomicAdd(&hist[pairs[i] >> 17], 1);
  __syncthreads();
  int h0 = hist[2 * tid], h1 = hist[2 * tid + 1];
  int ps = h0 + h1;
  int lane = tid & 63, wave = tid >> 6;
  int s = ps;
#pragma unroll
  for (int o = 1; o < 64; o <<= 1) { int t = __shfl_up(s, o); if (lane >= o) s += t; }
  if (lane == 63) wsum[wave] = s;
  __syncthreads();
  if (tid == 0) { int c = 0; for (int k = 0; k < 4; ++k) { int t = wsum[k]; wsum[k] = c; c += t; } }
  __syncthreads();
  int base0 = lo + (s - ps) + wsum[wave];
  curs[2 * tid] = base0;
  curs[2 * tid + 1] = base0 + h0;
  if (2 * tid < nn)     rowptr[n0 + 2 * tid] = base0;
  if (2 * tid + 1 < nn) rowptr[n0 + 2 * tid + 1] = base0 + h0;
  __syncthreads();
  for (int i = lo + tid; i < hi; i += 256) {
    unsigned int p = pairs[i];
    int pos = atomicAdd(&curs[p >> 17], 1);
    ebuf[pos] = (int)(p & 0x1FFFF);
  }
}

// ---------------- conversions (merged x + weights) ----------------
// axb: [N][256] bf16 (cols 0..127 mean1, 128..255 x);  xq: [N][128] fp8 e4m3
#define CVT_X_WORK (N_NODES * 32)
__global__ void cvt_all_kernel(const float* __restrict__ x,
                               const float* __restrict__ W1l, const float* __restrict__ W1r,
                               const float* __restrict__ W2l, const float* __restrict__ W2r,
                               ushort_t* __restrict__ axb, unsigned int* __restrict__ xq,
                               ushort_t* __restrict__ W1bt, ushort_t* __restrict__ W2bt) {
  int idx = blockIdx.x * blockDim.x + threadIdx.x;
  if (idx < CVT_X_WORK) {
    int n = idx >> 5, j = (idx & 31) << 2;
    float4 v = *(const float4*)(x + (size_t)n * 128 + j);
    ushort4 o;
    o.x = f2bf(v.x); o.y = f2bf(v.y); o.z = f2bf(v.z); o.w = f2bf(v.w);
    *(ushort4*)(axb + (size_t)n * 256 + 128 + j) = o;
    unsigned int q = __builtin_amdgcn_cvt_pk_fp8_f32(v.x, v.y, 0, false);
    q = __builtin_amdgcn_cvt_pk_fp8_f32(v.z, v.w, q, true);
    xq[(size_t)n * 32 + (j >> 2)] = q;
  } else if (idx < CVT_X_WORK + 65536) {
    int t = idx - CVT_X_WORK;
    int n = t >> 8, k = t & 255;
    float v = (k < 128) ? W1l[(size_t)k * 256 + n] : W1r[(size_t)(k - 128) * 256 + n];
    W1bt[t] = f2bf(v);
  } else if (idx < CVT_X_WORK + 65536 + 32768) {
    int t = idx - CVT_X_WORK - 65536;
    int n = t >> 8, k = t & 255;
    float v = (n < 64) ? W2l[(size_t)k * 64 + n] : W2r[(size_t)k * 64 + (n - 64)];
    W2bt[t] = f2bf(v);
  }
}

// ---------------- layer-1 mean aggregation: 4 lanes per node ----------------
// lane q = t&3 owns feats q*32..q*32+31 (16 f32x2 acc); 2-edge unroll = 4 row
// loads in flight/lane; no cross-lane combine (features partitioned).
__launch_bounds__(256)
__global__ void agg_mean1_kernel(const int* __restrict__ rowptr, const int* __restrict__ ebuf,
                                 const uint4* __restrict__ xq4, ushort_t* __restrict__ axb) {
  int t = blockIdx.x * 256 + threadIdx.x;
  int node = t >> 2, q = t & 3;
  bool valid = node < N_NODES;
  int anode = valid ? node : 0;
  int beg = rowptr[anode], end = rowptr[anode + 1];
  if (!valid) end = beg;
  f32x2 acc[16];
#pragma unroll
  for (int i = 0; i < 16; ++i) acc[i] = (f32x2){0.f, 0.f};
  int e = beg;
  for (; e + 2 <= end; e += 2) {
    int s0 = ebuf[e], s1 = ebuf[e + 1];
    const uint4* r0p = xq4 + (unsigned)(s0 * 8 + q * 2);
    const uint4* r1p = xq4 + (unsigned)(s1 * 8 + q * 2);
    uint4 a0 = r0p[0], a1 = r0p[1];
    uint4 b0 = r1p[0], b1 = r1p[1];
    ACC_U4(a0, 0) ACC_U4(a1, 8)
    ACC_U4(b0, 0) ACC_U4(b1, 8)
  }
  if (e < end) {
    int s = ebuf[e];
    const uint4* rp = xq4 + (unsigned)(s * 8 + q * 2);
    uint4 a0 = rp[0], a1 = rp[1];
    ACC_U4(a0, 0) ACC_U4(a1, 8)
  }
  if (!valid) return;
  float inv = (end > beg) ? 1.0f / (float)(end - beg) : 0.0f;
  f32x2 inv2 = {inv, inv};
#pragma unroll
  for (int i = 0; i < 16; ++i) acc[i] *= inv2;
  uint4* orow = (uint4*)(axb + (size_t)node * 256 + q * 32);
#pragma unroll
  for (int k = 0; k < 4; ++k) {
    uint4 o;
    o.x = pkbf(acc[4 * k + 0]);
    o.y = pkbf(acc[4 * k + 1]);
    o.z = pkbf(acc[4 * k + 2]);
    o.w = pkbf(acc[4 * k + 3]);
    orow[k] = o;
  }
}

// ---------------- bf16 MFMA GEMM (K=256 fixed) ----------------
// MODE 0: C = relu(A@Bt^T + bias) bf16.  MODE 1 (layer2, NC=128):
//   cols 0..63 (wn==0) -> P8 fp8 [N][64];  cols 64..127 (wn==1) -> QB bf16 [N][64]
template<int MODE>
__launch_bounds__(256)
__global__ void gemm_bf16_kernel(const ushort_t* __restrict__ A, const ushort_t* __restrict__ Bt,
                                 const float* __restrict__ bias, ushort_t* __restrict__ C,
                                 unsigned char* __restrict__ P8, ushort_t* __restrict__ QB,
                                 int M, int NC) {
  __shared__ ushort_t ldsA[128 * 64];  // 16 KB
  __shared__ ushort_t ldsB[128 * 64];  // 16 KB
  const int tid = threadIdx.x;
  const int lane = tid & 63;
  const int wm = (tid >> 6) & 1, wn = tid >> 7;
  const int rowBase = blockIdx.x * 128;
  const int colBase = blockIdx.y * 128;
  f32x4 acc[4][4];
#pragma unroll
  for (int i = 0; i < 4; ++i)
#pragma unroll
    for (int j = 0; j < 4; ++j) acc[i][j] = (f32x4){0.f, 0.f, 0.f, 0.f};

  for (int k0 = 0; k0 < GK; k0 += 64) {
#pragma unroll
    for (int i = 0; i < 4; ++i) {
      int s = tid + i * 256;          // 16B slot id
      int row = s >> 3, off16 = s & 7;
      int k16 = off16 ^ (row & 7);    // inverse-swizzled global source
      int ga = rowBase + row; if (ga > M - 1) ga = M - 1;
      gload16(A + (size_t)ga * GK + k0 + k16 * 8, &ldsA[s * 8]);
      gload16(Bt + (size_t)(colBase + row) * GK + k0 + k16 * 8, &ldsB[s * 8]);
    }
    __syncthreads();
#pragma unroll
    for (int kc = 0; kc < 2; ++kc) {
      bf16x8 af[4], bfr[4];
#pragma unroll
      for (int i = 0; i < 4; ++i) {
        int rA = wm * 64 + i * 16 + (lane & 15);
        int oA = (kc * 4 + (lane >> 4)) ^ (rA & 7);   // swizzled read
        af[i] = *(const bf16x8*)&ldsA[rA * 64 + oA * 8];
        int rB = wn * 64 + i * 16 + (lane & 15);
        int oB = (kc * 4 + (lane >> 4)) ^ (rB & 7);
        bfr[i] = *(const bf16x8*)&ldsB[rB * 64 + oB * 8];
      }
#pragma unroll
      for (int mi = 0; mi < 4; ++mi)
#pragma unroll
        for (int ni = 0; ni < 4; ++ni)
          acc[mi][ni] = __builtin_amdgcn_mfma_f32_16x16x32_bf16(af[mi], bfr[ni], acc[mi][ni], 0, 0, 0);
    }
    __syncthreads();
  }
#pragma unroll
  for (int mi = 0; mi < 4; ++mi) {
#pragma unroll
    for (int r = 0; r < 4; ++r) {
      int grow = rowBase + wm * 64 + mi * 16 + (lane >> 4) * 4 + r;
      if (grow >= M) continue;
#pragma unroll
      for (int ni = 0; ni < 4; ++ni) {
        float v = acc[mi][ni][r];
        if (MODE == 0) {
          int gcol = colBase + wn * 64 + ni * 16 + (lane & 15);
          C[(size_t)grow * NC + gcol] = f2bf(fmaxf(v + bias[gcol], 0.f));
        } else {
          int c = ni * 16 + (lane & 15);  // 0..63 within half
          if (wn == 0) {
            unsigned int u = __builtin_amdgcn_cvt_pk_fp8_f32(v, v, 0, false);
            P8[(size_t)grow * 64 + c] = (unsigned char)(u & 0xff);
          } else {
            QB[(size_t)grow * 64 + c] = f2bf(v);
          }
        }
      }
    }
  }
}

// ---------------- final: one lane per node (2-edge unroll) ----------------
__launch_bounds__(256)
__global__ void final_kernel(const int* __restrict__ rowptr, const int* __restrict__ ebuf,
                             const uint4* __restrict__ p84, const ushort_t* __restrict__ qb,
                             const float* __restrict__ b2, float* __restrict__ out) {
  int node = blockIdx.x * 256 + threadIdx.x;
  bool valid = node < N_NODES;
  int anode = valid ? node : 0;
  int beg = rowptr[anode], end = rowptr[anode + 1];
  if (!valid) end = beg;
  f32x2 acc[32];
#pragma unroll
  for (int i = 0; i < 32; ++i) acc[i] = (f32x2){0.f, 0.f};
  int e = beg;
  for (; e + 2 <= end; e += 2) {
    int s0 = ebuf[e], s1 = ebuf[e + 1];
    const uint4* r0p = p84 + (unsigned)(s0 * 4);
    const uint4* r1p = p84 + (unsigned)(s1 * 4);
    uint4 a0 = r0p[0], a1 = r0p[1], a2 = r0p[2], a3 = r0p[3];
    uint4 b0 = r1p[0], b1 = r1p[1], b2_ = r1p[2], b3 = r1p[3];
    ACC_U4(a0, 0) ACC_U4(a1, 8) ACC_U4(a2, 16) ACC_U4(a3, 24)
    ACC_U4(b0, 0) ACC_U4(b1, 8) ACC_U4(b2_, 16) ACC_U4(b3, 24)
  }
  if (e < end) {
    int s = ebuf[e];
    const uint4* row = p84 + (unsigned)(s * 4);
    uint4 r0 = row[0], r1 = row[1], r2 = row[2], r3 = row[3];
    ACC_U4(r0, 0) ACC_U4(r1, 8) ACC_U4(r2, 16) ACC_U4(r3, 24)
  }
  if (!valid) return;
  float inv = (end > beg) ? 1.0f / (float)(end - beg) : 0.0f;
  f32x2 inv2 = {inv, inv};
#pragma unroll
  for (int i = 0; i < 32; ++i) acc[i] *= inv2;
  const uint4* qrow = (const uint4*)(qb + (size_t)node * 64);
#pragma unroll
  for (int k = 0; k < 8; ++k) {
    uint4 q = qrow[k];
    acc[4 * k + 0][0] += b2[8 * k + 0] + bf2f(q.x & 0xffff);
    acc[4 * k + 0][1] += b2[8 * k + 1] + bf2f(q.x >> 16);
    acc[4 * k + 1][0] += b2[8 * k + 2] + bf2f(q.y & 0xffff);
    acc[4 * k + 1][1] += b2[8 * k + 3] + bf2f(q.y >> 16);
    acc[4 * k + 2][0] += b2[8 * k + 4] + bf2f(q.z & 0xffff);
    acc[4 * k + 2][1] += b2[8 * k + 5] + bf2f(q.z >> 16);
    acc[4 * k + 3][0] += b2[8 * k + 6] + bf2f(q.w & 0xffff);
    acc[4 * k + 3][1] += b2[8 * k + 7] + bf2f(q.w >> 16);
  }
  float mx[32];
#pragma unroll
  for (int i = 0; i < 32; ++i) mx[i] = fmaxf(acc[i][0], acc[i][1]);
#pragma unroll
  for (int s = 16; s >= 1; s >>= 1)
#pragma unroll
    for (int j = 0; j < 16; ++j)
      if (j < s) mx[j] = fmaxf(mx[j], mx[j + s]);
  float m = mx[0];
  float sm[32];
#pragma unroll
  for (int i = 0; i < 32; ++i)
    sm[i] = __expf(acc[i][0] - m) + __expf(acc[i][1] - m);
#pragma unroll
  for (int s = 16; s >= 1; s >>= 1)
#pragma unroll
    for (int j = 0; j < 16; ++j)
      if (j < s) sm[j] += sm[j + s];
  float ls = m + __logf(sm[0]);
  f32x2 ls2 = {ls, ls};
  float4* orow = (float4*)(out + (size_t)node * 64);
#pragma unroll
  for (int i = 0; i < 16; ++i) {
    f32x2 a = acc[2 * i] - ls2;
    f32x2 b = acc[2 * i + 1] - ls2;
    float4 o = {a[0], a[1], b[0], b[1]};
    orow[i] = o;
  }
}

// ---------------- launch ----------------

extern "C" void kernel_launch(void* const* d_in, const int* in_sizes, int n_in,
                              void* d_out, int out_size, void* d_ws, size_t ws_size,
                              hipStream_t stream) {
  const float* x   = (const float*)d_in[0];
  const int*   ei  = (const int*)d_in[1];
  const float* W1l = (const float*)d_in[2];
  const float* b1  = (const float*)d_in[3];
  const float* W1r = (const float*)d_in[4];
  const float* W2l = (const float*)d_in[5];
  const float* b2  = (const float*)d_in[6];
  const float* W2r = (const float*)d_in[7];
  float* out = (float*)d_out;
  const int* src = ei;
  const int* dst = ei + N_EDGES;

  char* w = (char*)d_ws;
  int*      bucketCount = (int*)(w);                          // 784 B
  int*      bucketBase  = (int*)(w + 1024);
  int*      bucketCur   = (int*)(w + 2048);
  int*      rowptr      = (int*)(w + 4096);                   // 400 KB
  int*      ebuf        = (int*)(w + 512ull * 1024);          // 6.4 MB
  ushort_t* W1bt        = (ushort_t*)(w + 7ull * 1024 * 1024);       // 128 KB
  ushort_t* W2bt        = (ushort_t*)(w + 7ull * 1024 * 1024 + 256 * 1024);  // 64 KB
  ushort_t* axb         = (ushort_t*)(w + 8ull * 1024 * 1024);       // 51.2 MB (ends 59.2)
  ushort_t* h           = (ushort_t*)(w + 60ull * 1024 * 1024);      // 51.2 MB (ends 111.2)
  unsigned int* pairs   = (unsigned int*)(w + 60ull * 1024 * 1024);  // 6.4 MB, aliases h
  unsigned int* xq      = (unsigned int*)(w + 112ull * 1024 * 1024); // 12.8 MB fp8 x
  unsigned int* p8      = (unsigned int*)(w + 125ull * 1024 * 1024); // 6.4 MB fp8 P
  ushort_t*     qb      = (ushort_t*)(w + 132ull * 1024 * 1024);     // 12.8 MB bf16 Q

  zero_int_kernel<<<1, 256, 0, stream>>>(bucketCount, NBKT);
  bin_count_kernel<<<NBIN, 256, 0, stream>>>(dst, bucketCount);
  scan_buckets_kernel<<<1, 64, 0, stream>>>(bucketCount, bucketBase, bucketCur, rowptr);
  bin_scatter_kernel<<<NBIN, 256, 0, stream>>>(src, dst, bucketCur, pairs);
  bucket_csr_kernel<<<NBKT, 256, 0, stream>>>(pairs, bucketBase, rowptr, ebuf);

  const int CVT_TOTAL = CVT_X_WORK + 65536 + 32768;
  cvt_all_kernel<<<(CVT_TOTAL + 255) / 256, 256, 0, stream>>>(
      x, W1l, W1r, W2l, W2r, axb, xq, W1bt, W2bt);

  agg_mean1_kernel<<<(4 * N_NODES + 255) / 256, 256, 0, stream>>>(
      rowptr, ebuf, (const uint4*)xq, axb);

  gemm_bf16_kernel<0><<<dim3((N_NODES + 127) / 128, 2), 256, 0, stream>>>(
      axb, W1bt, b1, h, nullptr, nullptr, N_NODES, 256);
  gemm_bf16_kernel<1><<<dim3((N_NODES + 127) / 128, 1), 256, 0, stream>>>(
      h, W2bt, nullptr, nullptr, (unsigned char*)p8, qb, N_NODES, 128);

  final_kernel<<<(N_NODES + 255) / 256, 256, 0, stream>>>(
      rowptr, ebuf, (const uint4*)p8, qb, b2, out);
}

// Round 12
// 195.946 us; speedup vs baseline: 6.3888x; 1.0201x over previous
//
#include <hip/hip_runtime.h>

#define N_NODES 100000
#define N_EDGES 1600000
#define GK 256      // K dim of both GEMMs
#define NBKT 196    // buckets of 512 nodes: (100000+511)>>9
#define NBIN 128    // blocks for bin count/scatter
#define EPB (N_EDGES / NBIN)  // 12500 edges per bin block

typedef __attribute__((ext_vector_type(8))) short bf16x8;
typedef __attribute__((ext_vector_type(4))) float f32x4;
typedef __attribute__((ext_vector_type(2))) float f32x2;
typedef unsigned short ushort_t;

__device__ __forceinline__ float bf2f(unsigned int bits16) {
  union { unsigned int i; float f; } v; v.i = bits16 << 16; return v.f;
}
__device__ __forceinline__ unsigned short f2bf(float f) {
  union { float f; unsigned int i; } v; v.f = f;
  unsigned int u = v.i;
  unsigned int r = (u + 0x7fffu + ((u >> 16) & 1u)) >> 16;  // RNE
  return (unsigned short)r;
}
__device__ __forceinline__ unsigned pkbf(f32x2 a) {
  return (unsigned)f2bf(a[0]) | ((unsigned)f2bf(a[1]) << 16);
}
__device__ __forceinline__ void gload16(const void* g, void* l) {
  __builtin_amdgcn_global_load_lds(
      (const __attribute__((address_space(1))) void*)g,
      (__attribute__((address_space(3))) void*)l, 16, 0, 0);
}

// accumulate one u32 (4 fp8) into acc[b], acc[b+1]  (static indices only)
#define ACC_U32(u, b) \
  acc[b] += __builtin_amdgcn_cvt_pk_f32_fp8((u), false); \
  acc[(b) + 1] += __builtin_amdgcn_cvt_pk_f32_fp8((u), true);
#define ACC_U4(U, b) \
  ACC_U32((U).x, (b)) ACC_U32((U).y, (b) + 2) ACC_U32((U).z, (b) + 4) ACC_U32((U).w, (b) + 6)

// ---------------- bucket-sort CSR build (coalesced writes by construction) ----

__global__ void zero_int_kernel(int* __restrict__ p, int n) {
  int i = blockIdx.x * blockDim.x + threadIdx.x;
  if (i < n) p[i] = 0;
}

__global__ void bin_count_kernel(const int* __restrict__ dst, int* __restrict__ bucketCount) {
  __shared__ int hist[NBKT];
  int tid = threadIdx.x;
  for (int i = tid; i < NBKT; i += 256) hist[i] = 0;
  __syncthreads();
  const int4* d4 = (const int4*)(dst + blockIdx.x * EPB);
  for (int i = tid; i < EPB / 4; i += 256) {
    int4 v = d4[i];
    atomicAdd(&hist[v.x >> 9], 1); atomicAdd(&hist[v.y >> 9], 1);
    atomicAdd(&hist[v.z >> 9], 1); atomicAdd(&hist[v.w >> 9], 1);
  }
  __syncthreads();
  for (int i = tid; i < NBKT; i += 256)
    if (hist[i]) atomicAdd(&bucketCount[i], hist[i]);
}

__global__ void scan_buckets_kernel(const int* __restrict__ cnt, int* __restrict__ base,
                                    int* __restrict__ cursor, int* __restrict__ rowptr) {
  int lane = threadIdx.x;
  int carry = 0;
  for (int b0 = 0; b0 < NBKT; b0 += 64) {
    int i = b0 + lane;
    int v = (i < NBKT) ? cnt[i] : 0;
    int s = v;
#pragma unroll
    for (int o = 1; o < 64; o <<= 1) { int t = __shfl_up(s, o); if (lane >= o) s += t; }
    int tot = __shfl(s, 63);
    if (i < NBKT) { base[i] = carry + s - v; cursor[i] = carry + s - v; }
    carry += tot;
  }
  if (lane == 0) { base[NBKT] = N_EDGES; rowptr[N_NODES] = N_EDGES; }
}

// pack = (dst_local<<17) | src
__global__ void bin_scatter_kernel(const int* __restrict__ src, const int* __restrict__ dst,
                                   int* __restrict__ cursor, unsigned int* __restrict__ pairs) {
  __shared__ int hist[NBKT];
  __shared__ int curs[NBKT];
  int tid = threadIdx.x;
  for (int i = tid; i < NBKT; i += 256) hist[i] = 0;
  __syncthreads();
  const int4* d4 = (const int4*)(dst + blockIdx.x * EPB);
  const int4* s4 = (const int4*)(src + blockIdx.x * EPB);
  for (int i = tid; i < EPB / 4; i += 256) {
    int4 v = d4[i];
    atomicAdd(&hist[v.x >> 9], 1); atomicAdd(&hist[v.y >> 9], 1);
    atomicAdd(&hist[v.z >> 9], 1); atomicAdd(&hist[v.w >> 9], 1);
  }
  __syncthreads();
  for (int i = tid; i < NBKT; i += 256) curs[i] = atomicAdd(&cursor[i], hist[i]);
  __syncthreads();
  for (int i = tid; i < EPB / 4; i += 256) {
    int4 v = d4[i];
    int4 u = s4[i];
    int p;
    p = atomicAdd(&curs[v.x >> 9], 1); pairs[p] = ((unsigned)(v.x & 511) << 17) | (unsigned)u.x;
    p = atomicAdd(&curs[v.y >> 9], 1); pairs[p] = ((unsigned)(v.y & 511) << 17) | (unsigned)u.y;
    p = atomicAdd(&curs[v.z >> 9], 1); pairs[p] = ((unsigned)(v.z & 511) << 17) | (unsigned)u.z;
    p = atomicAdd(&curs[v.w >> 9], 1); pairs[p] = ((unsigned)(v.w & 511) << 17) | (unsigned)u.w;
  }
}

__launch_bounds__(256)
__global__ void bucket_csr_kernel(const unsigned int* __restrict__ pairs,
                                  const int* __restrict__ base,
                                  int* __restrict__ rowptr, int* __restrict__ ebuf) {
  __shared__ int hist[512];
  __shared__ int curs[512];
  __shared__ int wsum[4];
  int b = blockIdx.x;
  int tid = threadIdx.x;
  int n0 = b << 9;
  int nn = N_NODES - n0; if (nn > 512) nn = 512;
  int lo = base[b], hi = base[b + 1];
  hist[tid] = 0; hist[tid + 256] = 0;
  __syncthreads();
  for (int i = lo + tid; i < hi; i += 256)
    atomicAdd(&hist[pairs[i] >> 17], 1);
  __syncthreads();
  int h0 = hist[2 * tid], h1 = hist[2 * tid + 1];
  int ps = h0 + h1;
  int lane = tid & 63, wave = tid >> 6;
  int s = ps;
#pragma unroll
  for (int o = 1; o < 64; o <<= 1) { int t = __shfl_up(s, o); if (lane >= o) s += t; }
  if (lane == 63) wsum[wave] = s;
  __syncthreads();
  if (tid == 0) { int c = 0; for (int k = 0; k < 4; ++k) { int t = wsum[k]; wsum[k] = c; c += t; } }
  __syncthreads();
  int base0 = lo + (s - ps) + wsum[wave];
  curs[2 * tid] = base0;
  curs[2 * tid + 1] = base0 + h0;
  if (2 * tid < nn)     rowptr[n0 + 2 * tid] = base0;
  if (2 * tid + 1 < nn) rowptr[n0 + 2 * tid + 1] = base0 + h0;
  __syncthreads();
  for (int i = lo + tid; i < hi; i += 256) {
    unsigned int p = pairs[i];
    int pos = atomicAdd(&curs[p >> 17], 1);
    ebuf[pos] = (int)(p & 0x1FFFF);
  }
}

// ---------------- conversions (merged x + weights) ----------------
// axb: [N][256] bf16 (cols 0..127 mean1, 128..255 x);  xq: [N][128] fp8 e4m3
#define CVT_X_WORK (N_NODES * 32)
__global__ void cvt_all_kernel(const float* __restrict__ x,
                               const float* __restrict__ W1l, const float* __restrict__ W1r,
                               const float* __restrict__ W2l, const float* __restrict__ W2r,
                               ushort_t* __restrict__ axb, unsigned int* __restrict__ xq,
                               ushort_t* __restrict__ W1bt, ushort_t* __restrict__ W2bt) {
  int idx = blockIdx.x * blockDim.x + threadIdx.x;
  if (idx < CVT_X_WORK) {
    int n = idx >> 5, j = (idx & 31) << 2;
    float4 v = *(const float4*)(x + (size_t)n * 128 + j);
    ushort4 o;
    o.x = f2bf(v.x); o.y = f2bf(v.y); o.z = f2bf(v.z); o.w = f2bf(v.w);
    *(ushort4*)(axb + (size_t)n * 256 + 128 + j) = o;
    unsigned int q = __builtin_amdgcn_cvt_pk_fp8_f32(v.x, v.y, 0, false);
    q = __builtin_amdgcn_cvt_pk_fp8_f32(v.z, v.w, q, true);
    xq[(size_t)n * 32 + (j >> 2)] = q;
  } else if (idx < CVT_X_WORK + 65536) {
    int t = idx - CVT_X_WORK;
    int n = t >> 8, k = t & 255;
    float v = (k < 128) ? W1l[(size_t)k * 256 + n] : W1r[(size_t)(k - 128) * 256 + n];
    W1bt[t] = f2bf(v);
  } else if (idx < CVT_X_WORK + 65536 + 32768) {
    int t = idx - CVT_X_WORK - 65536;
    int n = t >> 8, k = t & 255;
    float v = (n < 64) ? W2l[(size_t)k * 64 + n] : W2r[(size_t)k * 64 + (n - 64)];
    W2bt[t] = f2bf(v);
  }
}

// ---------------- layer-1 mean aggregation: 8 lanes per node ----------------
// lane q = t&7 owns feats q*16..q*16+15 (8 f32x2 acc = 1 uint4 per edge);
// 4-edge unroll = 4 loads in flight; no cross-lane combine.
__launch_bounds__(256)
__global__ void agg_mean1_kernel(const int* __restrict__ rowptr, const int* __restrict__ ebuf,
                                 const uint4* __restrict__ xq4, ushort_t* __restrict__ axb) {
  int t = blockIdx.x * 256 + threadIdx.x;
  int node = t >> 3, q = t & 7;
  bool valid = node < N_NODES;
  int anode = valid ? node : 0;
  int beg = rowptr[anode], end = rowptr[anode + 1];
  if (!valid) end = beg;
  f32x2 acc[8];
#pragma unroll
  for (int i = 0; i < 8; ++i) acc[i] = (f32x2){0.f, 0.f};
  int e = beg;
  for (; e + 4 <= end; e += 4) {
    int s0 = ebuf[e], s1 = ebuf[e + 1], s2 = ebuf[e + 2], s3 = ebuf[e + 3];
    uint4 a = xq4[(unsigned)(s0 * 8 + q)];
    uint4 b = xq4[(unsigned)(s1 * 8 + q)];
    uint4 c = xq4[(unsigned)(s2 * 8 + q)];
    uint4 d = xq4[(unsigned)(s3 * 8 + q)];
    ACC_U4(a, 0) ACC_U4(b, 0) ACC_U4(c, 0) ACC_U4(d, 0)
  }
  for (; e < end; ++e) {
    int s = ebuf[e];
    uint4 a = xq4[(unsigned)(s * 8 + q)];
    ACC_U4(a, 0)
  }
  if (!valid) return;
  float inv = (end > beg) ? 1.0f / (float)(end - beg) : 0.0f;
  f32x2 inv2 = {inv, inv};
#pragma unroll
  for (int i = 0; i < 8; ++i) acc[i] *= inv2;
  uint4* orow = (uint4*)(axb + (size_t)node * 256 + q * 16);
  uint4 o0, o1;
  o0.x = pkbf(acc[0]); o0.y = pkbf(acc[1]); o0.z = pkbf(acc[2]); o0.w = pkbf(acc[3]);
  o1.x = pkbf(acc[4]); o1.y = pkbf(acc[5]); o1.z = pkbf(acc[6]); o1.w = pkbf(acc[7]);
  orow[0] = o0;
  orow[1] = o1;
}

// ---------------- bf16 MFMA GEMM (K=256 fixed) ----------------
// MODE 0: C = relu(A@Bt^T + bias) bf16.  MODE 1 (layer2, NC=128):
//   cols 0..63 (wn==0) -> P8 fp8 [N][64];  cols 64..127 (wn==1) -> QB bf16 [N][64]
template<int MODE>
__launch_bounds__(256)
__global__ void gemm_bf16_kernel(const ushort_t* __restrict__ A, const ushort_t* __restrict__ Bt,
                                 const float* __restrict__ bias, ushort_t* __restrict__ C,
                                 unsigned char* __restrict__ P8, ushort_t* __restrict__ QB,
                                 int M, int NC) {
  __shared__ ushort_t ldsA[128 * 64];  // 16 KB
  __shared__ ushort_t ldsB[128 * 64];  // 16 KB
  const int tid = threadIdx.x;
  const int lane = tid & 63;
  const int wm = (tid >> 6) & 1, wn = tid >> 7;
  const int rowBase = blockIdx.x * 128;
  const int colBase = blockIdx.y * 128;
  f32x4 acc[4][4];
#pragma unroll
  for (int i = 0; i < 4; ++i)
#pragma unroll
    for (int j = 0; j < 4; ++j) acc[i][j] = (f32x4){0.f, 0.f, 0.f, 0.f};

  for (int k0 = 0; k0 < GK; k0 += 64) {
#pragma unroll
    for (int i = 0; i < 4; ++i) {
      int s = tid + i * 256;          // 16B slot id
      int row = s >> 3, off16 = s & 7;
      int k16 = off16 ^ (row & 7);    // inverse-swizzled global source
      int ga = rowBase + row; if (ga > M - 1) ga = M - 1;
      gload16(A + (size_t)ga * GK + k0 + k16 * 8, &ldsA[s * 8]);
      gload16(Bt + (size_t)(colBase + row) * GK + k0 + k16 * 8, &ldsB[s * 8]);
    }
    __syncthreads();
#pragma unroll
    for (int kc = 0; kc < 2; ++kc) {
      bf16x8 af[4], bfr[4];
#pragma unroll
      for (int i = 0; i < 4; ++i) {
        int rA = wm * 64 + i * 16 + (lane & 15);
        int oA = (kc * 4 + (lane >> 4)) ^ (rA & 7);   // swizzled read
        af[i] = *(const bf16x8*)&ldsA[rA * 64 + oA * 8];
        int rB = wn * 64 + i * 16 + (lane & 15);
        int oB = (kc * 4 + (lane >> 4)) ^ (rB & 7);
        bfr[i] = *(const bf16x8*)&ldsB[rB * 64 + oB * 8];
      }
#pragma unroll
      for (int mi = 0; mi < 4; ++mi)
#pragma unroll
        for (int ni = 0; ni < 4; ++ni)
          acc[mi][ni] = __builtin_amdgcn_mfma_f32_16x16x32_bf16(af[mi], bfr[ni], acc[mi][ni], 0, 0, 0);
    }
    __syncthreads();
  }
#pragma unroll
  for (int mi = 0; mi < 4; ++mi) {
#pragma unroll
    for (int r = 0; r < 4; ++r) {
      int grow = rowBase + wm * 64 + mi * 16 + (lane >> 4) * 4 + r;
      if (grow >= M) continue;
#pragma unroll
      for (int ni = 0; ni < 4; ++ni) {
        float v = acc[mi][ni][r];
        if (MODE == 0) {
          int gcol = colBase + wn * 64 + ni * 16 + (lane & 15);
          C[(size_t)grow * NC + gcol] = f2bf(fmaxf(v + bias[gcol], 0.f));
        } else {
          int c = ni * 16 + (lane & 15);  // 0..63 within half
          if (wn == 0) {
            unsigned int u = __builtin_amdgcn_cvt_pk_fp8_f32(v, v, 0, false);
            P8[(size_t)grow * 64 + c] = (unsigned char)(u & 0xff);
          } else {
            QB[(size_t)grow * 64 + c] = f2bf(v);
          }
        }
      }
    }
  }
}

// ---------------- final: 2 lanes per node, class-partitioned ----------------
// lane h = t&1 owns classes h*32..h*32+31 (16 f32x2 acc, 2 uint4 per edge);
// softmax combine = 1 shfl_xor level; 4-edge unroll = 8 loads in flight.
__launch_bounds__(256)
__global__ void final_kernel(const int* __restrict__ rowptr, const int* __restrict__ ebuf,
                             const uint4* __restrict__ p84, const ushort_t* __restrict__ qb,
                             const float* __restrict__ b2, float* __restrict__ out) {
  int t = blockIdx.x * 256 + threadIdx.x;
  int node = t >> 1, h = t & 1;
  bool valid = node < N_NODES;
  int anode = valid ? node : 0;
  int beg = rowptr[anode], end = rowptr[anode + 1];
  if (!valid) end = beg;
  f32x2 acc[16];
#pragma unroll
  for (int i = 0; i < 16; ++i) acc[i] = (f32x2){0.f, 0.f};
  int e = beg;
  for (; e + 4 <= end; e += 4) {
    int s0 = ebuf[e], s1 = ebuf[e + 1], s2 = ebuf[e + 2], s3 = ebuf[e + 3];
    const uint4* r0 = p84 + (unsigned)(s0 * 4 + h * 2);
    const uint4* r1 = p84 + (unsigned)(s1 * 4 + h * 2);
    const uint4* r2 = p84 + (unsigned)(s2 * 4 + h * 2);
    const uint4* r3 = p84 + (unsigned)(s3 * 4 + h * 2);
    uint4 a0 = r0[0], a1 = r0[1];
    uint4 b0 = r1[0], b1 = r1[1];
    uint4 c0 = r2[0], c1 = r2[1];
    uint4 d0 = r3[0], d1 = r3[1];
    ACC_U4(a0, 0) ACC_U4(a1, 8)
    ACC_U4(b0, 0) ACC_U4(b1, 8)
    ACC_U4(c0, 0) ACC_U4(c1, 8)
    ACC_U4(d0, 0) ACC_U4(d1, 8)
  }
  for (; e < end; ++e) {
    int s = ebuf[e];
    const uint4* rp = p84 + (unsigned)(s * 4 + h * 2);
    uint4 a0 = rp[0], a1 = rp[1];
    ACC_U4(a0, 0) ACC_U4(a1, 8)
  }
  float inv = (end > beg) ? 1.0f / (float)(end - beg) : 0.0f;
  f32x2 inv2 = {inv, inv};
#pragma unroll
  for (int i = 0; i < 16; ++i) acc[i] *= inv2;
  // + b2 + Q for own 32 classes
  const uint4* qrow = (const uint4*)(qb + (size_t)anode * 64 + h * 32);
  const float* bb = b2 + h * 32;
#pragma unroll
  for (int k = 0; k < 4; ++k) {
    uint4 qv = qrow[k];
    acc[4 * k + 0][0] += bb[8 * k + 0] + bf2f(qv.x & 0xffff);
    acc[4 * k + 0][1] += bb[8 * k + 1] + bf2f(qv.x >> 16);
    acc[4 * k + 1][0] += bb[8 * k + 2] + bf2f(qv.y & 0xffff);
    acc[4 * k + 1][1] += bb[8 * k + 3] + bf2f(qv.y >> 16);
    acc[4 * k + 2][0] += bb[8 * k + 4] + bf2f(qv.z & 0xffff);
    acc[4 * k + 2][1] += bb[8 * k + 5] + bf2f(qv.z >> 16);
    acc[4 * k + 3][0] += bb[8 * k + 6] + bf2f(qv.w & 0xffff);
    acc[4 * k + 3][1] += bb[8 * k + 7] + bf2f(qv.w >> 16);
  }
  // local max/sum over 32, then 1 shfl_xor(1) combine with partner lane
  float mx[16];
#pragma unroll
  for (int i = 0; i < 16; ++i) mx[i] = fmaxf(acc[i][0], acc[i][1]);
#pragma unroll
  for (int s = 8; s >= 1; s >>= 1)
#pragma unroll
    for (int j = 0; j < 8; ++j)
      if (j < s) mx[j] = fmaxf(mx[j], mx[j + s]);
  float m = fmaxf(mx[0], __shfl_xor(mx[0], 1));
  float sm[16];
#pragma unroll
  for (int i = 0; i < 16; ++i)
    sm[i] = __expf(acc[i][0] - m) + __expf(acc[i][1] - m);
#pragma unroll
  for (int s = 8; s >= 1; s >>= 1)
#pragma unroll
    for (int j = 0; j < 8; ++j)
      if (j < s) sm[j] += sm[j + s];
  float ssum = sm[0] + __shfl_xor(sm[0], 1);
  if (!valid) return;
  float ls = m + __logf(ssum);
  f32x2 ls2 = {ls, ls};
  float4* orow = (float4*)(out + (size_t)node * 64 + h * 32);
#pragma unroll
  for (int i = 0; i < 8; ++i) {
    f32x2 a = acc[2 * i] - ls2;
    f32x2 b = acc[2 * i + 1] - ls2;
    float4 o = {a[0], a[1], b[0], b[1]};
    orow[i] = o;
  }
}

// ---------------- launch ----------------

extern "C" void kernel_launch(void* const* d_in, const int* in_sizes, int n_in,
                              void* d_out, int out_size, void* d_ws, size_t ws_size,
                              hipStream_t stream) {
  const float* x   = (const float*)d_in[0];
  const int*   ei  = (const int*)d_in[1];
  const float* W1l = (const float*)d_in[2];
  const float* b1  = (const float*)d_in[3];
  const float* W1r = (const float*)d_in[4];
  const float* W2l = (const float*)d_in[5];
  const float* b2  = (const float*)d_in[6];
  const float* W2r = (const float*)d_in[7];
  float* out = (float*)d_out;
  const int* src = ei;
  const int* dst = ei + N_EDGES;

  char* w = (char*)d_ws;
  int*      bucketCount = (int*)(w);                          // 784 B
  int*      bucketBase  = (int*)(w + 1024);
  int*      bucketCur   = (int*)(w + 2048);
  int*      rowptr      = (int*)(w + 4096);                   // 400 KB
  int*      ebuf        = (int*)(w + 512ull * 1024);          // 6.4 MB
  ushort_t* W1bt        = (ushort_t*)(w + 7ull * 1024 * 1024);       // 128 KB
  ushort_t* W2bt        = (ushort_t*)(w + 7ull * 1024 * 1024 + 256 * 1024);  // 64 KB
  ushort_t* axb         = (ushort_t*)(w + 8ull * 1024 * 1024);       // 51.2 MB (ends 59.2)
  ushort_t* h           = (ushort_t*)(w + 60ull * 1024 * 1024);      // 51.2 MB (ends 111.2)
  unsigned int* pairs   = (unsigned int*)(w + 60ull * 1024 * 1024);  // 6.4 MB, aliases h
  unsigned int* xq      = (unsigned int*)(w + 112ull * 1024 * 1024); // 12.8 MB fp8 x
  unsigned int* p8      = (unsigned int*)(w + 125ull * 1024 * 1024); // 6.4 MB fp8 P
  ushort_t*     qb      = (ushort_t*)(w + 132ull * 1024 * 1024);     // 12.8 MB bf16 Q

  zero_int_kernel<<<1, 256, 0, stream>>>(bucketCount, NBKT);
  bin_count_kernel<<<NBIN, 256, 0, stream>>>(dst, bucketCount);
  scan_buckets_kernel<<<1, 64, 0, stream>>>(bucketCount, bucketBase, bucketCur, rowptr);
  bin_scatter_kernel<<<NBIN, 256, 0, stream>>>(src, dst, bucketCur, pairs);
  bucket_csr_kernel<<<NBKT, 256, 0, stream>>>(pairs, bucketBase, rowptr, ebuf);

  const int CVT_TOTAL = CVT_X_WORK + 65536 + 32768;
  cvt_all_kernel<<<(CVT_TOTAL + 255) / 256, 256, 0, stream>>>(
      x, W1l, W1r, W2l, W2r, axb, xq, W1bt, W2bt);

  agg_mean1_kernel<<<(8 * N_NODES + 255) / 256, 256, 0, stream>>>(
      rowptr, ebuf, (const uint4*)xq, axb);

  gemm_bf16_kernel<0><<<dim3((N_NODES + 127) / 128, 2), 256, 0, stream>>>(
      axb, W1bt, b1, h, nullptr, nullptr, N_NODES, 256);
  gemm_bf16_kernel<1><<<dim3((N_NODES + 127) / 128, 1), 256, 0, stream>>>(
      h, W2bt, nullptr, nullptr, (unsigned char*)p8, qb, N_NODES, 128);

  final_kernel<<<(2 * N_NODES + 255) / 256, 256, 0, stream>>>(
      rowptr, ebuf, (const uint4*)p8, qb, b2, out);
}

// Round 13
// 186.862 us; speedup vs baseline: 6.6994x; 1.0486x over previous
//
#include <hip/hip_runtime.h>

#define N_NODES 100000
#define N_EDGES 1600000
#define GK 256      // K dim of both GEMMs
#define NBKT 196    // buckets of 512 nodes: (100000+511)>>9
#define NBIN 128    // blocks for bin count/scatter
#define EPB (N_EDGES / NBIN)  // 12500 edges per bin block

typedef __attribute__((ext_vector_type(8))) short bf16x8;
typedef __attribute__((ext_vector_type(4))) float f32x4;
typedef __attribute__((ext_vector_type(2))) float f32x2;
typedef unsigned short ushort_t;

__device__ __forceinline__ float bf2f(unsigned int bits16) {
  union { unsigned int i; float f; } v; v.i = bits16 << 16; return v.f;
}
__device__ __forceinline__ unsigned short f2bf(float f) {
  union { float f; unsigned int i; } v; v.f = f;
  unsigned int u = v.i;
  unsigned int r = (u + 0x7fffu + ((u >> 16) & 1u)) >> 16;  // RNE
  return (unsigned short)r;
}
__device__ __forceinline__ unsigned pkbf(f32x2 a) {
  return (unsigned)f2bf(a[0]) | ((unsigned)f2bf(a[1]) << 16);
}
__device__ __forceinline__ void gload16(const void* g, void* l) {
  __builtin_amdgcn_global_load_lds(
      (const __attribute__((address_space(1))) void*)g,
      (__attribute__((address_space(3))) void*)l, 16, 0, 0);
}

// accumulate one u32 (4 fp8) into acc[b], acc[b+1]  (static indices only)
#define ACC_U32(u, b) \
  acc[b] += __builtin_amdgcn_cvt_pk_f32_fp8((u), false); \
  acc[(b) + 1] += __builtin_amdgcn_cvt_pk_f32_fp8((u), true);
#define ACC_U4(U, b) \
  ACC_U32((U).x, (b)) ACC_U32((U).y, (b) + 2) ACC_U32((U).z, (b) + 4) ACC_U32((U).w, (b) + 6)

// ---------------- fused CSR-count (partial hist, atomic-free global) + cvt ----
// blocks 0..NBIN-1: per-block LDS histogram of dst buckets -> partialHist[bkt][blk]
// blocks NBIN.. : convert x -> bf16 axb / fp8 xq, W1/W2 -> transposed bf16
#define CVT_X_WORK (N_NODES * 32)
#define CVT_TOTAL (CVT_X_WORK + 65536 + 32768)
__global__ void count_cvt_kernel(const int* __restrict__ dst, int* __restrict__ partialHist,
                                 const float* __restrict__ x,
                                 const float* __restrict__ W1l, const float* __restrict__ W1r,
                                 const float* __restrict__ W2l, const float* __restrict__ W2r,
                                 ushort_t* __restrict__ axb, unsigned int* __restrict__ xq,
                                 ushort_t* __restrict__ W1bt, ushort_t* __restrict__ W2bt) {
  __shared__ int hist[NBKT];
  int tid = threadIdx.x;
  if (blockIdx.x < NBIN) {
    for (int i = tid; i < NBKT; i += 256) hist[i] = 0;
    __syncthreads();
    const int4* d4 = (const int4*)(dst + blockIdx.x * EPB);
    for (int i = tid; i < EPB / 4; i += 256) {
      int4 v = d4[i];
      atomicAdd(&hist[v.x >> 9], 1); atomicAdd(&hist[v.y >> 9], 1);
      atomicAdd(&hist[v.z >> 9], 1); atomicAdd(&hist[v.w >> 9], 1);
    }
    __syncthreads();
    for (int i = tid; i < NBKT; i += 256) partialHist[i * NBIN + blockIdx.x] = hist[i];
  } else {
    int idx = (blockIdx.x - NBIN) * 256 + tid;
    if (idx < CVT_X_WORK) {
      int n = idx >> 5, j = (idx & 31) << 2;
      float4 v = *(const float4*)(x + (size_t)n * 128 + j);
      ushort4 o;
      o.x = f2bf(v.x); o.y = f2bf(v.y); o.z = f2bf(v.z); o.w = f2bf(v.w);
      *(ushort4*)(axb + (size_t)n * 256 + 128 + j) = o;
      unsigned int q = __builtin_amdgcn_cvt_pk_fp8_f32(v.x, v.y, 0, false);
      q = __builtin_amdgcn_cvt_pk_fp8_f32(v.z, v.w, q, true);
      xq[(size_t)n * 32 + (j >> 2)] = q;
    } else if (idx < CVT_X_WORK + 65536) {
      int t = idx - CVT_X_WORK;
      int n = t >> 8, k = t & 255;
      float v = (k < 128) ? W1l[(size_t)k * 256 + n] : W1r[(size_t)(k - 128) * 256 + n];
      W1bt[t] = f2bf(v);
    } else if (idx < CVT_TOTAL) {
      int t = idx - CVT_X_WORK - 65536;
      int n = t >> 8, k = t & 255;
      float v = (n < 64) ? W2l[(size_t)k * 64 + n] : W2r[(size_t)k * 64 + (n - 64)];
      W2bt[t] = f2bf(v);
    }
  }
}

// sum partials + exclusive scan -> base/cursor (one 256-thread block)
__global__ void scan_buckets_kernel(const int* __restrict__ ph, int* __restrict__ base,
                                    int* __restrict__ cursor, int* __restrict__ rowptr) {
  __shared__ int wsum[4];
  int t = threadIdx.x;
  int v = 0;
  if (t < NBKT) {
    const int* row = ph + t * NBIN;
    for (int b = 0; b < NBIN; ++b) v += row[b];
  }
  int lane = t & 63, wave = t >> 6;
  int s = v;
#pragma unroll
  for (int o = 1; o < 64; o <<= 1) { int u = __shfl_up(s, o); if (lane >= o) s += u; }
  if (lane == 63) wsum[wave] = s;
  __syncthreads();
  if (t == 0) { int c = 0; for (int k = 0; k < 4; ++k) { int u = wsum[k]; wsum[k] = c; c += u; } }
  __syncthreads();
  int excl = s - v + wsum[wave];
  if (t < NBKT) { base[t] = excl; cursor[t] = excl; }
  if (t == 0) { base[NBKT] = N_EDGES; rowptr[N_NODES] = N_EDGES; }
}

// pack = (dst_local<<17) | src
__global__ void bin_scatter_kernel(const int* __restrict__ src, const int* __restrict__ dst,
                                   int* __restrict__ cursor, unsigned int* __restrict__ pairs) {
  __shared__ int hist[NBKT];
  __shared__ int curs[NBKT];
  int tid = threadIdx.x;
  for (int i = tid; i < NBKT; i += 256) hist[i] = 0;
  __syncthreads();
  const int4* d4 = (const int4*)(dst + blockIdx.x * EPB);
  const int4* s4 = (const int4*)(src + blockIdx.x * EPB);
  for (int i = tid; i < EPB / 4; i += 256) {
    int4 v = d4[i];
    atomicAdd(&hist[v.x >> 9], 1); atomicAdd(&hist[v.y >> 9], 1);
    atomicAdd(&hist[v.z >> 9], 1); atomicAdd(&hist[v.w >> 9], 1);
  }
  __syncthreads();
  for (int i = tid; i < NBKT; i += 256) curs[i] = atomicAdd(&cursor[i], hist[i]);
  __syncthreads();
  for (int i = tid; i < EPB / 4; i += 256) {
    int4 v = d4[i];
    int4 u = s4[i];
    int p;
    p = atomicAdd(&curs[v.x >> 9], 1); pairs[p] = ((unsigned)(v.x & 511) << 17) | (unsigned)u.x;
    p = atomicAdd(&curs[v.y >> 9], 1); pairs[p] = ((unsigned)(v.y & 511) << 17) | (unsigned)u.y;
    p = atomicAdd(&curs[v.z >> 9], 1); pairs[p] = ((unsigned)(v.z & 511) << 17) | (unsigned)u.z;
    p = atomicAdd(&curs[v.w >> 9], 1); pairs[p] = ((unsigned)(v.w & 511) << 17) | (unsigned)u.w;
  }
}

__launch_bounds__(256)
__global__ void bucket_csr_kernel(const unsigned int* __restrict__ pairs,
                                  const int* __restrict__ base,
                                  int* __restrict__ rowptr, int* __restrict__ ebuf) {
  __shared__ int hist[512];
  __shared__ int curs[512];
  __shared__ int wsum[4];
  int b = blockIdx.x;
  int tid = threadIdx.x;
  int n0 = b << 9;
  int nn = N_NODES - n0; if (nn > 512) nn = 512;
  int lo = base[b], hi = base[b + 1];
  hist[tid] = 0; hist[tid + 256] = 0;
  __syncthreads();
  for (int i = lo + tid; i < hi; i += 256)
    atomicAdd(&hist[pairs[i] >> 17], 1);
  __syncthreads();
  int h0 = hist[2 * tid], h1 = hist[2 * tid + 1];
  int ps = h0 + h1;
  int lane = tid & 63, wave = tid >> 6;
  int s = ps;
#pragma unroll
  for (int o = 1; o < 64; o <<= 1) { int t = __shfl_up(s, o); if (lane >= o) s += t; }
  if (lane == 63) wsum[wave] = s;
  __syncthreads();
  if (tid == 0) { int c = 0; for (int k = 0; k < 4; ++k) { int t = wsum[k]; wsum[k] = c; c += t; } }
  __syncthreads();
  int base0 = lo + (s - ps) + wsum[wave];
  curs[2 * tid] = base0;
  curs[2 * tid + 1] = base0 + h0;
  if (2 * tid < nn)     rowptr[n0 + 2 * tid] = base0;
  if (2 * tid + 1 < nn) rowptr[n0 + 2 * tid + 1] = base0 + h0;
  __syncthreads();
  for (int i = lo + tid; i < hi; i += 256) {
    unsigned int p = pairs[i];
    int pos = atomicAdd(&curs[p >> 17], 1);
    ebuf[pos] = (int)(p & 0x1FFFF);
  }
}

// ---------------- layer-1 mean aggregation: 8 lanes per node, 8-edge unroll ---
__launch_bounds__(256)
__global__ void agg_mean1_kernel(const int* __restrict__ rowptr, const int* __restrict__ ebuf,
                                 const uint4* __restrict__ xq4, ushort_t* __restrict__ axb) {
  int t = blockIdx.x * 256 + threadIdx.x;
  int node = t >> 3, q = t & 7;
  bool valid = node < N_NODES;
  int anode = valid ? node : 0;
  int beg = rowptr[anode], end = rowptr[anode + 1];
  if (!valid) end = beg;
  f32x2 acc[8];
#pragma unroll
  for (int i = 0; i < 8; ++i) acc[i] = (f32x2){0.f, 0.f};
  int e = beg;
  for (; e + 8 <= end; e += 8) {
    int s0 = ebuf[e], s1 = ebuf[e + 1], s2 = ebuf[e + 2], s3 = ebuf[e + 3];
    int s4 = ebuf[e + 4], s5 = ebuf[e + 5], s6 = ebuf[e + 6], s7 = ebuf[e + 7];
    uint4 a = xq4[(unsigned)(s0 * 8 + q)];
    uint4 b = xq4[(unsigned)(s1 * 8 + q)];
    uint4 c = xq4[(unsigned)(s2 * 8 + q)];
    uint4 d = xq4[(unsigned)(s3 * 8 + q)];
    uint4 f = xq4[(unsigned)(s4 * 8 + q)];
    uint4 g = xq4[(unsigned)(s5 * 8 + q)];
    uint4 h2 = xq4[(unsigned)(s6 * 8 + q)];
    uint4 k = xq4[(unsigned)(s7 * 8 + q)];
    ACC_U4(a, 0) ACC_U4(b, 0) ACC_U4(c, 0) ACC_U4(d, 0)
    ACC_U4(f, 0) ACC_U4(g, 0) ACC_U4(h2, 0) ACC_U4(k, 0)
  }
  for (; e < end; ++e) {
    int s = ebuf[e];
    uint4 a = xq4[(unsigned)(s * 8 + q)];
    ACC_U4(a, 0)
  }
  if (!valid) return;
  float inv = (end > beg) ? 1.0f / (float)(end - beg) : 0.0f;
  f32x2 inv2 = {inv, inv};
#pragma unroll
  for (int i = 0; i < 8; ++i) acc[i] *= inv2;
  uint4* orow = (uint4*)(axb + (size_t)node * 256 + q * 16);
  uint4 o0, o1;
  o0.x = pkbf(acc[0]); o0.y = pkbf(acc[1]); o0.z = pkbf(acc[2]); o0.w = pkbf(acc[3]);
  o1.x = pkbf(acc[4]); o1.y = pkbf(acc[5]); o1.z = pkbf(acc[6]); o1.w = pkbf(acc[7]);
  orow[0] = o0;
  orow[1] = o1;
}

// ---------------- bf16 MFMA GEMM (K=256 fixed) ----------------
// MODE 0: C = relu(A@Bt^T + bias) bf16.  MODE 1 (layer2, NC=128):
//   cols 0..63 (wn==0) -> P8 fp8 [N][64];  cols 64..127 (wn==1) -> QB bf16 [N][64]
template<int MODE>
__launch_bounds__(256)
__global__ void gemm_bf16_kernel(const ushort_t* __restrict__ A, const ushort_t* __restrict__ Bt,
                                 const float* __restrict__ bias, ushort_t* __restrict__ C,
                                 unsigned char* __restrict__ P8, ushort_t* __restrict__ QB,
                                 int M, int NC) {
  __shared__ ushort_t ldsA[128 * 64];  // 16 KB
  __shared__ ushort_t ldsB[128 * 64];  // 16 KB
  const int tid = threadIdx.x;
  const int lane = tid & 63;
  const int wm = (tid >> 6) & 1, wn = tid >> 7;
  const int rowBase = blockIdx.x * 128;
  const int colBase = blockIdx.y * 128;
  f32x4 acc[4][4];
#pragma unroll
  for (int i = 0; i < 4; ++i)
#pragma unroll
    for (int j = 0; j < 4; ++j) acc[i][j] = (f32x4){0.f, 0.f, 0.f, 0.f};

  for (int k0 = 0; k0 < GK; k0 += 64) {
#pragma unroll
    for (int i = 0; i < 4; ++i) {
      int s = tid + i * 256;          // 16B slot id
      int row = s >> 3, off16 = s & 7;
      int k16 = off16 ^ (row & 7);    // inverse-swizzled global source
      int ga = rowBase + row; if (ga > M - 1) ga = M - 1;
      gload16(A + (size_t)ga * GK + k0 + k16 * 8, &ldsA[s * 8]);
      gload16(Bt + (size_t)(colBase + row) * GK + k0 + k16 * 8, &ldsB[s * 8]);
    }
    __syncthreads();
#pragma unroll
    for (int kc = 0; kc < 2; ++kc) {
      bf16x8 af[4], bfr[4];
#pragma unroll
      for (int i = 0; i < 4; ++i) {
        int rA = wm * 64 + i * 16 + (lane & 15);
        int oA = (kc * 4 + (lane >> 4)) ^ (rA & 7);   // swizzled read
        af[i] = *(const bf16x8*)&ldsA[rA * 64 + oA * 8];
        int rB = wn * 64 + i * 16 + (lane & 15);
        int oB = (kc * 4 + (lane >> 4)) ^ (rB & 7);
        bfr[i] = *(const bf16x8*)&ldsB[rB * 64 + oB * 8];
      }
#pragma unroll
      for (int mi = 0; mi < 4; ++mi)
#pragma unroll
        for (int ni = 0; ni < 4; ++ni)
          acc[mi][ni] = __builtin_amdgcn_mfma_f32_16x16x32_bf16(af[mi], bfr[ni], acc[mi][ni], 0, 0, 0);
    }
    __syncthreads();
  }
#pragma unroll
  for (int mi = 0; mi < 4; ++mi) {
#pragma unroll
    for (int r = 0; r < 4; ++r) {
      int grow = rowBase + wm * 64 + mi * 16 + (lane >> 4) * 4 + r;
      if (grow >= M) continue;
#pragma unroll
      for (int ni = 0; ni < 4; ++ni) {
        float v = acc[mi][ni][r];
        if (MODE == 0) {
          int gcol = colBase + wn * 64 + ni * 16 + (lane & 15);
          C[(size_t)grow * NC + gcol] = f2bf(fmaxf(v + bias[gcol], 0.f));
        } else {
          int c = ni * 16 + (lane & 15);  // 0..63 within half
          if (wn == 0) {
            unsigned int u = __builtin_amdgcn_cvt_pk_fp8_f32(v, v, 0, false);
            P8[(size_t)grow * 64 + c] = (unsigned char)(u & 0xff);
          } else {
            QB[(size_t)grow * 64 + c] = f2bf(v);
          }
        }
      }
    }
  }
}

// ---------------- final: 4 lanes per node, class-partitioned ----------------
// lane q = t&3 owns classes q*16..q*16+15 (8 f32x2 acc, 1 uint4 per edge);
// softmax combine = 2 shfl_xor levels; 4-edge unroll = 4 loads in flight.
__launch_bounds__(256)
__global__ void final_kernel(const int* __restrict__ rowptr, const int* __restrict__ ebuf,
                             const uint4* __restrict__ p84, const ushort_t* __restrict__ qb,
                             const float* __restrict__ b2, float* __restrict__ out) {
  int t = blockIdx.x * 256 + threadIdx.x;
  int node = t >> 2, q = t & 3;
  bool valid = node < N_NODES;
  int anode = valid ? node : 0;
  int beg = rowptr[anode], end = rowptr[anode + 1];
  if (!valid) end = beg;
  f32x2 acc[8];
#pragma unroll
  for (int i = 0; i < 8; ++i) acc[i] = (f32x2){0.f, 0.f};
  int e = beg;
  for (; e + 4 <= end; e += 4) {
    int s0 = ebuf[e], s1 = ebuf[e + 1], s2 = ebuf[e + 2], s3 = ebuf[e + 3];
    uint4 a = p84[(unsigned)(s0 * 4 + q)];
    uint4 b = p84[(unsigned)(s1 * 4 + q)];
    uint4 c = p84[(unsigned)(s2 * 4 + q)];
    uint4 d = p84[(unsigned)(s3 * 4 + q)];
    ACC_U4(a, 0) ACC_U4(b, 0) ACC_U4(c, 0) ACC_U4(d, 0)
  }
  for (; e < end; ++e) {
    int s = ebuf[e];
    uint4 a = p84[(unsigned)(s * 4 + q)];
    ACC_U4(a, 0)
  }
  float inv = (end > beg) ? 1.0f / (float)(end - beg) : 0.0f;
  f32x2 inv2 = {inv, inv};
#pragma unroll
  for (int i = 0; i < 8; ++i) acc[i] *= inv2;
  // + b2 + Q for own 16 classes
  const uint4* qrow = (const uint4*)(qb + (size_t)anode * 64 + q * 16);
  const float* bb = b2 + q * 16;
#pragma unroll
  for (int k = 0; k < 2; ++k) {
    uint4 qv = qrow[k];
    acc[4 * k + 0][0] += bb[8 * k + 0] + bf2f(qv.x & 0xffff);
    acc[4 * k + 0][1] += bb[8 * k + 1] + bf2f(qv.x >> 16);
    acc[4 * k + 1][0] += bb[8 * k + 2] + bf2f(qv.y & 0xffff);
    acc[4 * k + 1][1] += bb[8 * k + 3] + bf2f(qv.y >> 16);
    acc[4 * k + 2][0] += bb[8 * k + 4] + bf2f(qv.z & 0xffff);
    acc[4 * k + 2][1] += bb[8 * k + 5] + bf2f(qv.z >> 16);
    acc[4 * k + 3][0] += bb[8 * k + 6] + bf2f(qv.w & 0xffff);
    acc[4 * k + 3][1] += bb[8 * k + 7] + bf2f(qv.w >> 16);
  }
  // local max/sum over 16, then 2 shfl_xor levels within the node's 4 lanes
  float mx[8];
#pragma unroll
  for (int i = 0; i < 8; ++i) mx[i] = fmaxf(acc[i][0], acc[i][1]);
#pragma unroll
  for (int s = 4; s >= 1; s >>= 1)
#pragma unroll
    for (int j = 0; j < 4; ++j)
      if (j < s) mx[j] = fmaxf(mx[j], mx[j + s]);
  float m = mx[0];
  m = fmaxf(m, __shfl_xor(m, 1));
  m = fmaxf(m, __shfl_xor(m, 2));
  float sm[8];
#pragma unroll
  for (int i = 0; i < 8; ++i)
    sm[i] = __expf(acc[i][0] - m) + __expf(acc[i][1] - m);
#pragma unroll
  for (int s = 4; s >= 1; s >>= 1)
#pragma unroll
    for (int j = 0; j < 4; ++j)
      if (j < s) sm[j] += sm[j + s];
  float ssum = sm[0];
  ssum += __shfl_xor(ssum, 1);
  ssum += __shfl_xor(ssum, 2);
  if (!valid) return;
  float ls = m + __logf(ssum);
  f32x2 ls2 = {ls, ls};
  float4* orow = (float4*)(out + (size_t)node * 64 + q * 16);
#pragma unroll
  for (int i = 0; i < 4; ++i) {
    f32x2 a = acc[2 * i] - ls2;
    f32x2 b = acc[2 * i + 1] - ls2;
    float4 o = {a[0], a[1], b[0], b[1]};
    orow[i] = o;
  }
}

// ---------------- launch ----------------

extern "C" void kernel_launch(void* const* d_in, const int* in_sizes, int n_in,
                              void* d_out, int out_size, void* d_ws, size_t ws_size,
                              hipStream_t stream) {
  const float* x   = (const float*)d_in[0];
  const int*   ei  = (const int*)d_in[1];
  const float* W1l = (const float*)d_in[2];
  const float* b1  = (const float*)d_in[3];
  const float* W1r = (const float*)d_in[4];
  const float* W2l = (const float*)d_in[5];
  const float* b2  = (const float*)d_in[6];
  const float* W2r = (const float*)d_in[7];
  float* out = (float*)d_out;
  const int* src = ei;
  const int* dst = ei + N_EDGES;

  char* w = (char*)d_ws;
  int*      bucketBase  = (int*)(w);                          // 788 B
  int*      bucketCur   = (int*)(w + 1024);                   // 784 B
  int*      partialHist = (int*)(w + 2048);                   // 100.4 KB [NBKT][NBIN]
  int*      rowptr      = (int*)(w + 128ull * 1024);          // 400 KB
  int*      ebuf        = (int*)(w + 1024ull * 1024);         // 6.4 MB (ends 7.4)
  ushort_t* W1bt        = (ushort_t*)(w + 8ull * 1024 * 1024);       // 128 KB
  ushort_t* W2bt        = (ushort_t*)(w + 8ull * 1024 * 1024 + 256 * 1024);  // 64 KB
  ushort_t* axb         = (ushort_t*)(w + 9ull * 1024 * 1024);       // 51.2 MB (ends 60.2)
  ushort_t* h           = (ushort_t*)(w + 61ull * 1024 * 1024);      // 51.2 MB (ends 112.2)
  unsigned int* pairs   = (unsigned int*)(w + 61ull * 1024 * 1024);  // 6.4 MB, aliases h
  unsigned int* xq      = (unsigned int*)(w + 113ull * 1024 * 1024); // 12.8 MB fp8 x
  unsigned int* p8      = (unsigned int*)(w + 126ull * 1024 * 1024); // 6.4 MB fp8 P
  ushort_t*     qb      = (ushort_t*)(w + 133ull * 1024 * 1024);     // 12.8 MB bf16 Q

  const int CVT_BLOCKS = (CVT_TOTAL + 255) / 256;
  count_cvt_kernel<<<NBIN + CVT_BLOCKS, 256, 0, stream>>>(
      dst, partialHist, x, W1l, W1r, W2l, W2r, axb, xq, W1bt, W2bt);
  scan_buckets_kernel<<<1, 256, 0, stream>>>(partialHist, bucketBase, bucketCur, rowptr);
  bin_scatter_kernel<<<NBIN, 256, 0, stream>>>(src, dst, bucketCur, pairs);
  bucket_csr_kernel<<<NBKT, 256, 0, stream>>>(pairs, bucketBase, rowptr, ebuf);

  agg_mean1_kernel<<<(8 * N_NODES + 255) / 256, 256, 0, stream>>>(
      rowptr, ebuf, (const uint4*)xq, axb);

  gemm_bf16_kernel<0><<<dim3((N_NODES + 127) / 128, 2), 256, 0, stream>>>(
      axb, W1bt, b1, h, nullptr, nullptr, N_NODES, 256);
  gemm_bf16_kernel<1><<<dim3((N_NODES + 127) / 128, 1), 256, 0, stream>>>(
      h, W2bt, nullptr, nullptr, (unsigned char*)p8, qb, N_NODES, 128);

  final_kernel<<<(4 * N_NODES + 255) / 256, 256, 0, stream>>>(
      rowptr, ebuf, (const uint4*)p8, qb, b2, out);
}